// Round 16
// baseline (485.066 us; speedup 1.0000x reference)
//
#include <hip/hip_runtime.h>
#include <math.h>

#define BB 8
#define CC 512
#define TT 2048
#define ICC 256
#define EPSV 1e-5f
#define SC2048 2048.0f
#define INV2048 4.8828125e-4f

typedef _Float16 f16;
typedef __attribute__((ext_vector_type(8))) _Float16 f16x8;
typedef __attribute__((ext_vector_type(4))) float f32x4;

#define MFMA(a, b, c) __builtin_amdgcn_mfma_f32_16x16x32_f16(a, b, c, 0, 0, 0)

__device__ __forceinline__ int swz(int byte, int row) {
  return byte ^ ((row & 7) << 4);
}

// global -> LDS direct (16B/lane). LDS dest = wave-uniform base + lane*16.
__device__ __forceinline__ void ld_lds16(const void* g, void* l) {
  __builtin_amdgcn_global_load_lds(
      (const __attribute__((address_space(1))) unsigned int*)g,
      (__attribute__((address_space(3))) unsigned int*)l, 16, 0, 0);
}

// inverse of slot-swizzle o = s ^ ((s>>2)&7)  (row = slot>>2 layouts)
__device__ __forceinline__ int inv_swz_r2(int o) {
  return o ^ (((o >> 2) & 6) | (((o >> 2) ^ (o >> 4)) & 1));
}
// inverse of slot-swizzle o = s ^ ((s>>5)&7)  (row = slot>>5; involution)
__device__ __forceinline__ int inv_swz_r5(int o) { return o ^ ((o >> 5) & 7); }

// ---------------------------------------------------------------------------
// P0: x[b][c][t] f32 -> xT hi / scaled-lo f16 [b][t][c]
// ---------------------------------------------------------------------------
__global__ __launch_bounds__(256) void split_transpose_x(
    const float* __restrict__ x, f16* __restrict__ xh, f16* __restrict__ xl) {
  __shared__ float tile[32][33];
  const int tx = threadIdx.x, ty = threadIdx.y;
  const int t0 = blockIdx.x * 32, c0 = blockIdx.y * 32, b = blockIdx.z;
#pragma unroll
  for (int k = 0; k < 4; ++k)
    tile[ty + 8 * k][tx] = x[((size_t)b * CC + c0 + ty + 8 * k) * TT + t0 + tx];
  __syncthreads();
#pragma unroll
  for (int k = 0; k < 4; ++k) {
    float v = tile[tx][ty + 8 * k];
    size_t o = ((size_t)b * TT + t0 + ty + 8 * k) * CC + c0 + tx;
    f16 h = (f16)v;
    xh[o] = h;
    xl[o] = (f16)((v - (float)h) * SC2048);
  }
}

__global__ void split_w(const float* __restrict__ src, f16* __restrict__ h,
                        f16* __restrict__ lo, int n) {
  int i = blockIdx.x * 256 + threadIdx.x;
  if (i < n) {
    float v = src[i];
    f16 a = (f16)v;
    h[i] = a;
    lo[i] = (f16)((v - (float)a) * SC2048);
  }
}

// ---------------------------------------------------------------------------
// NT GEMM v3 (r16): 128x128 tile (r13 traffic), 512 threads = 8 waves of
// 64x32 output -> acc 64 AGPR, ~165 total regs, waves_per_eu(2,2) pinned
// (the r12/r13-verified no-spill 2-waves/SIMD recipe).
// grid (N/128, M/128, batch). wave w: m0=(w>>2)*64, n0=(w&3)*32.
// ---------------------------------------------------------------------------
template <int M, int N, int K, bool BIAS_N, bool F32OUT>
__global__ __launch_bounds__(512)
    __attribute__((amdgpu_waves_per_eu(2, 2))) void gemm_nt(
        const f16* __restrict__ Ah, const f16* __restrict__ Al, long strideA,
        const f16* __restrict__ Bh, const f16* __restrict__ Bl, long strideB,
        const float* __restrict__ bias, f16* __restrict__ Oh,
        f16* __restrict__ Ol, float* __restrict__ Of, long strideO,
        double* __restrict__ osum, double* __restrict__ osumsq) {
  __shared__ f16 sAh[4096], sAl[4096];  // A tile [128][32] swizzled
  __shared__ f16 sBh[4096], sBl[4096];  // B tile [128][32] swizzled
  __shared__ float sOut[F32OUT ? 1 : 32 * 132];
  const int tid = threadIdx.x;
  const int w = tid >> 6, l = tid & 63;
  const int bn = blockIdx.x * 128, bm = blockIdx.y * 128;
  const size_t baseA = (size_t)blockIdx.z * strideA;
  const size_t baseB = (size_t)blockIdx.z * strideB;
  const size_t baseO = (size_t)blockIdx.z * strideO;
  const int m0 = (w >> 2) * 64, n0 = (w & 3) * 32;
  char* cAh = (char*)sAh;
  char* cAl = (char*)sAl;
  char* cBh = (char*)sBh;
  char* cBl = (char*)sBl;

  f32x4 acc[4][2], accL[4][2];
#pragma unroll
  for (int i = 0; i < 4; ++i)
#pragma unroll
    for (int j = 0; j < 2; ++j) {
      acc[i][j] = (f32x4){0.f, 0.f, 0.f, 0.f};
      accL[i][j] = (f32x4){0.f, 0.f, 0.f, 0.f};
    }

  for (int kb = 0; kb < K; kb += 32) {
    __syncthreads();
    // A and B tiles: 512 slots each, one gload_lds per lane per tile
    {
      int base = w * 64;
      int s = inv_swz_r2(base + l);
      int row = s >> 2, ks = s & 3;
      size_t ga = baseA + (size_t)(bm + row) * K + kb + ks * 8;
      size_t gb = baseB + (size_t)(bn + row) * K + kb + ks * 8;
      ld_lds16(Ah + ga, cAh + base * 16);
      ld_lds16(Al + ga, cAl + base * 16);
      ld_lds16(Bh + gb, cBh + base * 16);
      ld_lds16(Bl + gb, cBl + base * 16);
    }
    __syncthreads();
    f16x8 ah[4], al[4];
#pragma unroll
    for (int mf = 0; mf < 4; ++mf) {
      int row = m0 + mf * 16 + (l & 15);
      int byte = swz(row * 64 + ((l >> 4) << 4), row);
      ah[mf] = *(const f16x8*)(cAh + byte);
      al[mf] = *(const f16x8*)(cAl + byte);
    }
#pragma unroll
    for (int nf = 0; nf < 2; ++nf) {
      int row = n0 + nf * 16 + (l & 15);
      int byte = swz(row * 64 + ((l >> 4) << 4), row);
      f16x8 bh = *(const f16x8*)(cBh + byte);
      f16x8 bl = *(const f16x8*)(cBl + byte);
#pragma unroll
      for (int mf = 0; mf < 4; ++mf)
        acc[mf][nf] = MFMA(ah[mf], bh, acc[mf][nf]);
#pragma unroll
      for (int mf = 0; mf < 4; ++mf)
        accL[mf][nf] = MFMA(al[mf], bh, accL[mf][nf]);
#pragma unroll
      for (int mf = 0; mf < 4; ++mf)
        accL[mf][nf] = MFMA(ah[mf], bl, accL[mf][nf]);
    }
  }

  if (F32OUT) {
#pragma unroll
    for (int mf = 0; mf < 4; ++mf)
#pragma unroll
      for (int r = 0; r < 4; ++r) {
        int mrow = bm + m0 + mf * 16 + ((l >> 4) << 2) + r;
        float bv = bias[mrow];
        double s = 0.0, q = 0.0;
#pragma unroll
        for (int nf = 0; nf < 2; ++nf) {
          float v = acc[mf][nf][r] + accL[mf][nf][r] * INV2048 + bv;
          Of[baseO + (size_t)mrow * N + bn + n0 + nf * 16 + (l & 15)] = v;
          s += (double)v;
          q += (double)v * (double)v;
        }
#pragma unroll
        for (int sh = 8; sh >= 1; sh >>= 1) {
          s += __shfl_xor(s, sh);
          q += __shfl_xor(q, sh);
        }
        if ((l & 15) == 0) {
          atomicAdd(&osum[mrow], s);
          atomicAdd(&osumsq[mrow], q);
        }
      }
  } else {
    // f16 epilogue: 4 chunks of 32 rows x 128 cols via LDS transpose
    for (int c = 0; c < 4; ++c) {
      __syncthreads();
      if ((w >> 2) == (c >> 1)) {
#pragma unroll
        for (int mf2 = 0; mf2 < 2; ++mf2) {
          int mf = (c & 1) * 2 + mf2;
          int rl = mf2 * 16 + ((l >> 4) << 2);
#pragma unroll
          for (int nf = 0; nf < 2; ++nf)
#pragma unroll
            for (int r = 0; r < 4; ++r)
              sOut[(rl + r) * 132 + n0 + nf * 16 + (l & 15)] =
                  acc[mf][nf][r] + accL[mf][nf][r] * INV2048;
        }
      }
      __syncthreads();
      int row = tid >> 4, cc0 = (tid & 15) * 8;
      size_t gm = bm + c * 32 + row;
      size_t ob = baseO + gm * (size_t)N + bn + cc0;
      f16 hv[8], lv[8];
#pragma unroll
      for (int e = 0; e < 8; ++e) {
        float v = sOut[row * 132 + cc0 + e];
        v += BIAS_N ? bias[bn + cc0 + e] : bias[gm];
        f16 h = (f16)v;
        hv[e] = h;
        lv[e] = (f16)((v - (float)h) * SC2048);
      }
      *(f16x8*)&Oh[ob] = *(f16x8*)hv;
      *(f16x8*)&Ol[ob] = *(f16x8*)lv;
    }
  }
}

// ---------------------------------------------------------------------------
// Fused flash attention (r13 exact, verified 286us): 8-wave block, K-split QK
// via sS exchange, 2 waves/SIMD pinned with waves_per_eu(2,2).
// ---------------------------------------------------------------------------
__global__ __launch_bounds__(512)
    __attribute__((amdgpu_waves_per_eu(2, 2))) void attn_mfma(
        const f16* __restrict__ th_h, const f16* __restrict__ th_l,
        const f16* __restrict__ ph_h, const f16* __restrict__ ph_l,
        const f16* __restrict__ g_h, const f16* __restrict__ g_l,
        f16* __restrict__ y_h, f16* __restrict__ y_l) {
  __shared__ f16 sPhiH[8192], sPhiL[8192];  // phi [32 j][256 c] swizzled
  __shared__ f16 sGH[8192], sGL[8192];      // g   [256 c][32 j] swizzled
  __shared__ float sS[2][64][33];           // combined partial S per K-half
  __shared__ f16 sP[2048], sPl[2048];       // P hi / scaled-lo [64][32]
  __shared__ float sSc[64], sL[64];
  const int tid = threadIdx.x, w = tid >> 6, l = tid & 63;
  const int b = blockIdx.x & 7;
  const int i0 = (blockIdx.x >> 3) * 64;
  const int gq = w >> 2;        // K-half for QK
  const int rw = (w & 3) * 16;  // QK row base

  const size_t tbase =
      ((size_t)b * TT + i0 + rw + (l & 15)) * 256 + gq * 128 + ((l >> 4) << 3);
  f16x8 qh[4], ql[4];
#pragma unroll
  for (int kf = 0; kf < 4; ++kf) {
    qh[kf] = *(const f16x8*)(th_h + tbase + kf * 32);
    ql[kf] = *(const f16x8*)(th_l + tbase + kf * 32);
  }
  f32x4 yacc[4][2], yaccL[4][2];
#pragma unroll
  for (int i = 0; i < 4; ++i)
#pragma unroll
    for (int j = 0; j < 2; ++j) {
      yacc[i][j] = (f32x4){0.f, 0.f, 0.f, 0.f};
      yaccL[i][j] = (f32x4){0.f, 0.f, 0.f, 0.f};
    }
  float mrow[4], lrow[4];
#pragma unroll
  for (int r = 0; r < 4; ++r) {
    mrow[r] = -3e38f;
    lrow[r] = 0.f;
  }

  for (int jc = 0; jc < 64; ++jc) {
    const int j0 = jc * 32;
#pragma unroll
    for (int rep = 0; rep < 2; ++rep) {
      int base = w * 64 + rep * 512;
      int s = inv_swz_r5(base + l);
      int row = s >> 5, kq = s & 31;
      size_t ga = ((size_t)b * TT + j0 + row) * 256 + kq * 8;
      ld_lds16(ph_h + ga, (char*)sPhiH + base * 16);
      ld_lds16(ph_l + ga, (char*)sPhiL + base * 16);
    }
#pragma unroll
    for (int rep = 0; rep < 2; ++rep) {
      int base = w * 64 + rep * 512;
      int s = inv_swz_r2(base + l);
      int row = s >> 2, kq = s & 3;
      size_t ga = ((size_t)b * 256 + row) * TT + j0 + kq * 8;
      ld_lds16(g_h + ga, (char*)sGH + base * 16);
      ld_lds16(g_l + ga, (char*)sGL + base * 16);
    }
    __syncthreads();  // A: tiles staged
    f32x4 s4[2] = {(f32x4){0.f, 0.f, 0.f, 0.f}, (f32x4){0.f, 0.f, 0.f, 0.f}};
    f32x4 s4L[2] = {(f32x4){0.f, 0.f, 0.f, 0.f}, (f32x4){0.f, 0.f, 0.f, 0.f}};
#pragma unroll
    for (int kf = 0; kf < 4; ++kf) {
#pragma unroll
      for (int jf = 0; jf < 2; ++jf) {
        int prow = jf * 16 + (l & 15);
        int byte =
            swz(prow * 512 + gq * 256 + kf * 64 + ((l >> 4) << 4), prow);
        f16x8 bh = *(const f16x8*)((char*)sPhiH + byte);
        f16x8 bl = *(const f16x8*)((char*)sPhiL + byte);
        s4[jf] = MFMA(qh[kf], bh, s4[jf]);
        s4L[jf] = MFMA(ql[kf], bh, s4L[jf]);
        s4L[jf] = MFMA(qh[kf], bl, s4L[jf]);
      }
    }
#pragma unroll
    for (int jf = 0; jf < 2; ++jf)
#pragma unroll
      for (int r = 0; r < 4; ++r) {
        int row = rw + ((l >> 4) << 2) + r;
        sS[gq][row][jf * 16 + (l & 15)] = s4[jf][r] + s4L[jf][r] * INV2048;
      }
    __syncthreads();  // B: S complete
    {
      int jcol = l & 31;
#pragma unroll
      for (int ry = 0; ry < 4; ++ry) {
        int row = w * 8 + (l >> 5) * 4 + ry;
        float sv = sS[0][row][jcol] + sS[1][row][jcol];
        float mx = sv;
#pragma unroll
        for (int sh = 16; sh >= 1; sh >>= 1) mx = fmaxf(mx, __shfl_xor(mx, sh));
        float mn = fmaxf(mrow[ry], mx);
        float sc = __expf(mrow[ry] - mn);
        mrow[ry] = mn;
        float p = __expf(sv - mn);
        float ls = p;
#pragma unroll
        for (int sh = 16; sh >= 1; sh >>= 1) ls += __shfl_xor(ls, sh);
        lrow[ry] = lrow[ry] * sc + ls;
        f16 h = (f16)p;
        *(f16*)((char*)sP + swz(row * 64 + jcol * 2, row)) = h;
        *(f16*)((char*)sPl + swz(row * 64 + jcol * 2, row)) =
            (f16)((p - (float)h) * SC2048);
        if (jcol == 0) sSc[row] = sc;
      }
    }
    __syncthreads();  // C: P + sSc published
#pragma unroll
    for (int mf = 0; mf < 4; ++mf)
#pragma unroll
      for (int r = 0; r < 4; ++r) {
        float s0 = sSc[mf * 16 + ((l >> 4) << 2) + r];
#pragma unroll
        for (int cf = 0; cf < 2; ++cf) {
          yacc[mf][cf][r] *= s0;
          yaccL[mf][cf][r] *= s0;
        }
      }
#pragma unroll
    for (int mf = 0; mf < 4; ++mf) {
      int prow = mf * 16 + (l & 15);
      int pb = swz(prow * 64 + ((l >> 4) << 4), prow);
      f16x8 pa = *(const f16x8*)((char*)sP + pb);
      f16x8 paL = *(const f16x8*)((char*)sPl + pb);
#pragma unroll
      for (int cf = 0; cf < 2; ++cf) {
        int crow = w * 32 + cf * 16 + (l & 15);
        int gb2 = swz(crow * 64 + ((l >> 4) << 4), crow);
        f16x8 gh = *(const f16x8*)((char*)sGH + gb2);
        f16x8 gl = *(const f16x8*)((char*)sGL + gb2);
        yacc[mf][cf] = MFMA(pa, gh, yacc[mf][cf]);
        yaccL[mf][cf] = MFMA(paL, gh, yaccL[mf][cf]);
        yaccL[mf][cf] = MFMA(pa, gl, yaccL[mf][cf]);
      }
    }
    __syncthreads();  // D: P/g reads done before next staging
  }

  if ((l & 31) == 0) {
#pragma unroll
    for (int ry = 0; ry < 4; ++ry) sL[w * 8 + (l >> 5) * 4 + ry] = lrow[ry];
  }
  __syncthreads();
  float* sOutF = (float*)sPhiH;
  for (int c2 = 0; c2 < 4; ++c2) {
#pragma unroll
    for (int r = 0; r < 4; ++r) {
      int row = c2 * 16 + ((l >> 4) << 2) + r;
      float linv = 1.f / sL[row];
      int rl = row - c2 * 16;
#pragma unroll
      for (int cf = 0; cf < 2; ++cf)
        sOutF[rl * 264 + w * 32 + cf * 16 + (l & 15)] =
            (yacc[c2][cf][r] + yaccL[c2][cf][r] * INV2048) * linv;
    }
    __syncthreads();
    int row = tid >> 5, cc0 = (tid & 31) * 8;
    size_t ob = ((size_t)b * TT + i0 + c2 * 16 + row) * 256 + cc0;
    f16 hv[8], lv[8];
#pragma unroll
    for (int e = 0; e < 8; ++e) {
      float v = sOutF[row * 264 + cc0 + e];
      f16 h = (f16)v;
      hv[e] = h;
      lv[e] = (f16)((v - (float)h) * SC2048);
    }
    *(f16x8*)&y_h[ob] = *(f16x8*)hv;
    *(f16x8*)&y_l[ob] = *(f16x8*)lv;
    __syncthreads();
  }
}

// ---------------------------------------------------------------------------
__global__ void zero_stats(double* s) { s[threadIdx.x] = 0.0; }

__global__ void bn_stats(const double* __restrict__ osum,
                         const double* __restrict__ osumsq,
                         float* __restrict__ mean, float* __restrict__ rstd) {
  int o = threadIdx.x;
  if (o < CC) {
    const double inv = 1.0 / (double)(BB * TT);
    double mu = osum[o] * inv;
    double var = osumsq[o] * inv - mu * mu;
    mean[o] = (float)mu;
    rstd[o] = (float)(1.0 / sqrt(var + (double)EPSV));
  }
}

__global__ __launch_bounds__(256) void bn_apply(
    float* __restrict__ out, const float* __restrict__ x,
    const float* __restrict__ mean, const float* __restrict__ rstd,
    const float* __restrict__ gamma, const float* __restrict__ beta) {
  const size_t n4 = (size_t)BB * CC * TT / 4;
  for (size_t idx = (size_t)blockIdx.x * blockDim.x + threadIdx.x; idx < n4;
       idx += (size_t)gridDim.x * blockDim.x) {
    size_t e = idx * 4;
    int o = (int)((e / TT) % CC);
    float4 wv = ((const float4*)out)[idx];
    float4 xv = ((const float4*)x)[idx];
    float mu = mean[o], rs = rstd[o], ga = gamma[o], be = beta[o];
    float4 r;
    r.x = fmaxf((wv.x - mu) * rs * ga + be, 0.f) + xv.x;
    r.y = fmaxf((wv.y - mu) * rs * ga + be, 0.f) + xv.y;
    r.z = fmaxf((wv.z - mu) * rs * ga + be, 0.f) + xv.z;
    r.w = fmaxf((wv.w - mu) * rs * ga + be, 0.f) + xv.w;
    ((float4*)out)[idx] = r;
  }
}

// ===========================================================================
// Fallback fp32 path (round-3, known-good) — used if ws too small.
// ===========================================================================
template <int M, int K, bool STATS>
__global__ __launch_bounds__(256) void gemm_proj(
    const float* __restrict__ W, const float* __restrict__ bias,
    const float* __restrict__ X, float* __restrict__ Out,
    double* __restrict__ osum, double* __restrict__ osumsq) {
  __shared__ float Ws[16][65];
  __shared__ float Xs[16][65];
  const int bt = blockIdx.x * 64, bm = blockIdx.y * 64, b = blockIdx.z;
  const int tid = threadIdx.x, tx = tid & 15, ty = tid >> 4;
  const float* Xb = X + (size_t)b * K * TT;
  float acc[4][4] = {};
  for (int kb = 0; kb < K; kb += 16) {
#pragma unroll
    for (int r = 0; r < 4; ++r) {
      int idx = tid + r * 256;
      int m = idx >> 4, k = idx & 15;
      Ws[k][m] = W[(size_t)(bm + m) * K + kb + k];
      int kx = idx >> 6, t = idx & 63;
      Xs[kx][t] = Xb[(size_t)(kb + kx) * TT + bt + t];
    }
    __syncthreads();
#pragma unroll
    for (int k = 0; k < 16; ++k) {
      float a[4], bv[4];
#pragma unroll
      for (int i = 0; i < 4; ++i) a[i] = Ws[k][ty * 4 + i];
#pragma unroll
      for (int j = 0; j < 4; ++j) bv[j] = Xs[k][tx * 4 + j];
#pragma unroll
      for (int i = 0; i < 4; ++i)
#pragma unroll
        for (int j = 0; j < 4; ++j) acc[i][j] += a[i] * bv[j];
    }
    __syncthreads();
  }
#pragma unroll
  for (int i = 0; i < 4; ++i) {
    int m = bm + ty * 4 + i;
    float bv = bias[m];
    double rs = 0.0, rq = 0.0;
#pragma unroll
    for (int j = 0; j < 4; ++j) {
      float v = acc[i][j] + bv;
      Out[((size_t)b * M + m) * TT + bt + tx * 4 + j] = v;
      if (STATS) {
        rs += (double)v;
        rq += (double)v * (double)v;
      }
    }
    if (STATS) {
#pragma unroll
      for (int s = 8; s >= 1; s >>= 1) {
        rs += __shfl_xor(rs, s, 16);
        rq += __shfl_xor(rq, s, 16);
      }
      if (tx == 0) {
        atomicAdd(&osum[m], rs);
        atomicAdd(&osumsq[m], rq);
      }
    }
  }
}

__global__ __launch_bounds__(256) void attn_flash(
    const float* __restrict__ th, const float* __restrict__ ph,
    const float* __restrict__ gx, float* __restrict__ y) {
  __shared__ float As[16][65];
  __shared__ float Bs[16][65];
  __shared__ float Ps[64][65];
  __shared__ float Gs[64][65];
  __shared__ float mScale[64];
  __shared__ float lArr[64];
  const int i0 = blockIdx.x * 64, b = blockIdx.y;
  const int tid = threadIdx.x, tx = tid & 15, ty = tid >> 4;
  const float* thb = th + (size_t)b * ICC * TT;
  const float* phb = ph + (size_t)b * ICC * TT;
  const float* gb = gx + (size_t)b * ICC * TT;
  float m[4], l[4];
#pragma unroll
  for (int i = 0; i < 4; ++i) {
    m[i] = -1e30f;
    l[i] = 0.f;
  }
  float acc[4][4][4] = {};
  for (int j0 = 0; j0 < TT; j0 += 64) {
    float S[4][4] = {};
    for (int cb = 0; cb < ICC; cb += 16) {
#pragma unroll
      for (int r = 0; r < 4; ++r) {
        int idx = tid + r * 256;
        int k = idx >> 6, col = idx & 63;
        As[k][col] = thb[(size_t)(cb + k) * TT + i0 + col];
        Bs[k][col] = phb[(size_t)(cb + k) * TT + j0 + col];
      }
      __syncthreads();
#pragma unroll
      for (int k = 0; k < 16; ++k) {
        float a[4], bv[4];
#pragma unroll
        for (int i = 0; i < 4; ++i) a[i] = As[k][ty * 4 + i];
#pragma unroll
        for (int j = 0; j < 4; ++j) bv[j] = Bs[k][tx * 4 + j];
#pragma unroll
        for (int i = 0; i < 4; ++i)
#pragma unroll
          for (int j = 0; j < 4; ++j) S[i][j] += a[i] * bv[j];
      }
      __syncthreads();
    }
    float sc[4];
#pragma unroll
    for (int i = 0; i < 4; ++i) {
      float mc = S[i][0];
#pragma unroll
      for (int j = 1; j < 4; ++j) mc = fmaxf(mc, S[i][j]);
#pragma unroll
      for (int s = 8; s >= 1; s >>= 1) mc = fmaxf(mc, __shfl_xor(mc, s, 16));
      float mn = fmaxf(m[i], mc);
      sc[i] = __expf(m[i] - mn);
      float lsum = 0.f;
#pragma unroll
      for (int j = 0; j < 4; ++j) {
        float p = __expf(S[i][j] - mn);
        S[i][j] = p;
        lsum += p;
      }
#pragma unroll
      for (int s = 8; s >= 1; s >>= 1) lsum += __shfl_xor(lsum, s, 16);
      l[i] = l[i] * sc[i] + lsum;
      m[i] = mn;
#pragma unroll
      for (int j = 0; j < 4; ++j) Ps[ty * 4 + i][tx * 4 + j] = S[i][j];
    }
    if (tx == 0) {
#pragma unroll
      for (int i = 0; i < 4; ++i) mScale[ty * 4 + i] = sc[i];
    }
    __syncthreads();
#pragma unroll
    for (int cq = 0; cq < 4; ++cq) {
#pragma unroll
      for (int r = 0; r < 16; ++r) {
        int idx = tid + r * 256;
        int cpr = idx >> 6, j = idx & 63;
        Gs[cpr][j] = gb[(size_t)(cq * 64 + cpr) * TT + j0 + j];
      }
      __syncthreads();
      float scj[4];
#pragma unroll
      for (int jq = 0; jq < 4; ++jq) scj[jq] = mScale[tx * 4 + jq];
#pragma unroll
      for (int ci = 0; ci < 4; ++ci)
#pragma unroll
        for (int jq = 0; jq < 4; ++jq) acc[cq][ci][jq] *= scj[jq];
      for (int j = 0; j < 64; ++j) {
        float a[4], p[4];
#pragma unroll
        for (int ci = 0; ci < 4; ++ci) a[ci] = Gs[ty * 4 + ci][j];
#pragma unroll
        for (int jq = 0; jq < 4; ++jq) p[jq] = Ps[tx * 4 + jq][j];
#pragma unroll
        for (int ci = 0; ci < 4; ++ci)
#pragma unroll
          for (int jq = 0; jq < 4; ++jq) acc[cq][ci][jq] += a[ci] * p[jq];
      }
      __syncthreads();
    }
  }
  if (tx == 0) {
#pragma unroll
    for (int i = 0; i < 4; ++i) lArr[ty * 4 + i] = l[i];
  }
  __syncthreads();
  float linv[4];
#pragma unroll
  for (int jq = 0; jq < 4; ++jq) linv[jq] = 1.f / lArr[tx * 4 + jq];
#pragma unroll
  for (int cq = 0; cq < 4; ++cq)
#pragma unroll
    for (int ci = 0; ci < 4; ++ci)
#pragma unroll
      for (int jq = 0; jq < 4; ++jq)
        y[((size_t)b * ICC + cq * 64 + ty * 4 + ci) * TT + i0 + tx * 4 + jq] =
            acc[cq][ci][jq] * linv[jq];
}

// ---------------------------------------------------------------------------
extern "C" void kernel_launch(void* const* d_in, const int* in_sizes, int n_in,
                              void* d_out, int out_size, void* d_ws,
                              size_t ws_size, hipStream_t stream) {
  const float* x = (const float*)d_in[0];
  const float* g_w = (const float*)d_in[1];
  const float* g_b = (const float*)d_in[2];
  const float* th_w = (const float*)d_in[3];
  const float* th_b = (const float*)d_in[4];
  const float* ph_w = (const float*)d_in[5];
  const float* ph_b = (const float*)d_in[6];
  const float* W_w = (const float*)d_in[7];
  const float* W_b = (const float*)d_in[8];
  const float* gamma = (const float*)d_in[9];
  const float* beta = (const float*)d_in[10];
  float* out = (float*)d_out;
  dim3 blk(256);

  const size_t NP = (size_t)BB * TT * ICC;  // 4,194,304
  const size_t NW = 131072;                 // 256*512
  const size_t need = (8 * NP + 8 * NW) * sizeof(f16) + 8192 + 4096;

  if (ws_size >= need) {
    // ---------------- fast MFMA path ----------------
    f16* p = (f16*)d_ws;
    f16 *thH = p, *thL = thH + NP, *phH = thL + NP, *phL = phH + NP;
    f16 *gH = phL + NP, *gL = gH + NP, *yH = gL + NP, *yL = yH + NP;
    f16* wp = yL + NP;
    f16 *gwH = wp, *gwL = gwH + NW, *twH = gwL + NW, *twL = twH + NW;
    f16 *pwH = twL + NW, *pwL = pwH + NW, *wwH = pwL + NW, *wwL = wwH + NW;
    double* statd = (double*)(wwL + NW);
    float* meanb = (float*)(statd + 1024);
    float* rstdb = meanb + 512;
    f16* xTh = (f16*)d_out;  // xT hi/lo lives in d_out (dead before W-conv)
    f16* xTl = xTh + (size_t)BB * TT * CC;

    split_transpose_x<<<dim3(TT / 32, CC / 32, BB), dim3(32, 8), 0, stream>>>(
        x, xTh, xTl);
    split_w<<<512, 256, 0, stream>>>(g_w, gwH, gwL, (int)NW);
    split_w<<<512, 256, 0, stream>>>(th_w, twH, twL, (int)NW);
    split_w<<<512, 256, 0, stream>>>(ph_w, pwH, pwL, (int)NW);
    split_w<<<512, 256, 0, stream>>>(W_w, wwH, wwL, (int)NW);
    zero_stats<<<1, 1024, 0, stream>>>(statd);

    // theta/phi: D[t][ic] = xT * W^T   (M=T, N=IC, K=C, bias on N)
    gemm_nt<TT, ICC, CC, true, false><<<dim3(2, 16, BB), dim3(512), 0,
                                        stream>>>(
        xTh, xTl, (long)TT * CC, twH, twL, 0, th_b, thH, thL, nullptr,
        (long)TT * ICC, nullptr, nullptr);
    gemm_nt<TT, ICC, CC, true, false><<<dim3(2, 16, BB), dim3(512), 0,
                                        stream>>>(
        xTh, xTl, (long)TT * CC, pwH, pwL, 0, ph_b, phH, phL, nullptr,
        (long)TT * ICC, nullptr, nullptr);
    // g: D[ic][t] = Wg * xT^T   (M=IC, N=T, K=C, bias on M)
    gemm_nt<ICC, TT, CC, false, false><<<dim3(16, 2, BB), dim3(512), 0,
                                         stream>>>(
        gwH, gwL, 0, xTh, xTl, (long)TT * CC, g_b, gH, gL, nullptr,
        (long)ICC * TT, nullptr, nullptr);
    // attention -> y f16 hi/lo directly (r13 exact)
    attn_mfma<<<256, dim3(512), 0, stream>>>(thH, thL, phH, phL, gH, gL, yH,
                                             yL);
    // W conv: D[o][t] -> d_out + BN stats  (M=C, N=T, K=IC, bias on M)
    gemm_nt<CC, TT, ICC, false, true><<<dim3(16, 4, BB), dim3(512), 0,
                                        stream>>>(
        wwH, wwL, 0, yH, yL, (long)TT * ICC, W_b, nullptr, nullptr, out,
        (long)CC * TT, statd, statd + CC);
    bn_stats<<<1, 512, 0, stream>>>(statd, statd + CC, meanb, rstdb);
    bn_apply<<<2048, 256, 0, stream>>>(out, x, meanb, rstdb, gamma, beta);
  } else {
    // ---------------- fallback fp32 path ----------------
    float* ws = (float*)d_ws;
    const size_t np = (size_t)BB * ICC * TT;
    float* thb = ws;
    float* phb = ws + np;
    float* gbuf = ws + 2 * np;
    float* yb = thb;
    double* statd = (double*)(ws + 3 * np);
    float* meanb = (float*)(statd + 1024);
    float* rstdb = meanb + 512;
    gemm_proj<ICC, CC, false><<<dim3(TT / 64, ICC / 64, BB), blk, 0, stream>>>(
        th_w, th_b, x, thb, nullptr, nullptr);
    gemm_proj<ICC, CC, false><<<dim3(TT / 64, ICC / 64, BB), blk, 0, stream>>>(
        ph_w, ph_b, x, phb, nullptr, nullptr);
    gemm_proj<ICC, CC, false><<<dim3(TT / 64, ICC / 64, BB), blk, 0, stream>>>(
        g_w, g_b, x, gbuf, nullptr, nullptr);
    attn_flash<<<dim3(TT / 64, BB), blk, 0, stream>>>(thb, phb, gbuf, yb);
    zero_stats<<<1, 1024, 0, stream>>>(statd);
    gemm_proj<CC, ICC, true><<<dim3(TT / 64, CC / 64, BB), blk, 0, stream>>>(
        W_w, W_b, yb, out, statd, statd + CC);
    bn_stats<<<1, 512, 0, stream>>>(statd, statd + CC, meanb, rstdb);
    bn_apply<<<2048, 256, 0, stream>>>(out, x, meanb, rstdb, gamma, beta);
  }
}

// Round 17
// 466.681 us; speedup vs baseline: 1.0394x; 1.0394x over previous
//
#include <hip/hip_runtime.h>
#include <math.h>

#define BB 8
#define CC 512
#define TT 2048
#define ICC 256
#define EPSV 1e-5f
#define SC2048 2048.0f
#define INV2048 4.8828125e-4f

typedef _Float16 f16;
typedef __attribute__((ext_vector_type(8))) _Float16 f16x8;
typedef __attribute__((ext_vector_type(4))) float f32x4;

#define MFMA(a, b, c) __builtin_amdgcn_mfma_f32_16x16x32_f16(a, b, c, 0, 0, 0)

__device__ __forceinline__ int swz(int byte, int row) {
  return byte ^ ((row & 7) << 4);
}

// global -> LDS direct (16B/lane). LDS dest = wave-uniform base + lane*16.
__device__ __forceinline__ void ld_lds16(const void* g, void* l) {
  __builtin_amdgcn_global_load_lds(
      (const __attribute__((address_space(1))) unsigned int*)g,
      (__attribute__((address_space(3))) unsigned int*)l, 16, 0, 0);
}

// inverse of slot-swizzle o = s ^ ((s>>2)&7)  (row = slot>>2 layouts)
__device__ __forceinline__ int inv_swz_r2(int o) {
  return o ^ (((o >> 2) & 6) | (((o >> 2) ^ (o >> 4)) & 1));
}
// inverse of slot-swizzle o = s ^ ((s>>5)&7)  (row = slot>>5; involution)
__device__ __forceinline__ int inv_swz_r5(int o) { return o ^ ((o >> 5) & 7); }

// ---------------------------------------------------------------------------
// P0: x[b][c][t] f32 -> xT hi / scaled-lo f16 [b][t][c]
// ---------------------------------------------------------------------------
__global__ __launch_bounds__(256) void split_transpose_x(
    const float* __restrict__ x, f16* __restrict__ xh, f16* __restrict__ xl) {
  __shared__ float tile[32][33];
  const int tx = threadIdx.x, ty = threadIdx.y;
  const int t0 = blockIdx.x * 32, c0 = blockIdx.y * 32, b = blockIdx.z;
#pragma unroll
  for (int k = 0; k < 4; ++k)
    tile[ty + 8 * k][tx] = x[((size_t)b * CC + c0 + ty + 8 * k) * TT + t0 + tx];
  __syncthreads();
#pragma unroll
  for (int k = 0; k < 4; ++k) {
    float v = tile[tx][ty + 8 * k];
    size_t o = ((size_t)b * TT + t0 + ty + 8 * k) * CC + c0 + tx;
    f16 h = (f16)v;
    xh[o] = h;
    xl[o] = (f16)((v - (float)h) * SC2048);
  }
}

__global__ void split_w(const float* __restrict__ src, f16* __restrict__ h,
                        f16* __restrict__ lo, int n) {
  int i = blockIdx.x * 256 + threadIdx.x;
  if (i < n) {
    float v = src[i];
    f16 a = (f16)v;
    h[i] = a;
    lo[i] = (f16)((v - (float)a) * SC2048);
  }
}

// ---------------------------------------------------------------------------
// NT GEMM (r13 exact, best verified): D = A*B^T + bias, split-f16,
// gload_lds staging, 128x128 tile, 256 threads.
// ---------------------------------------------------------------------------
template <int M, int N, int K, bool BIAS_N, bool F32OUT>
__global__ __launch_bounds__(256) void gemm_nt(
    const f16* __restrict__ Ah, const f16* __restrict__ Al, long strideA,
    const f16* __restrict__ Bh, const f16* __restrict__ Bl, long strideB,
    const float* __restrict__ bias, f16* __restrict__ Oh, f16* __restrict__ Ol,
    float* __restrict__ Of, long strideO, double* __restrict__ osum,
    double* __restrict__ osumsq) {
  __shared__ f16 sAh[4096], sAl[4096], sBh[4096], sBl[4096];
  __shared__ float sOut[F32OUT ? 1 : 32 * 132];
  const int tid = threadIdx.x;
  const int w = tid >> 6, l = tid & 63;
  const int bn = blockIdx.x * 128, bm = blockIdx.y * 128;
  const size_t baseA = (size_t)blockIdx.z * strideA;
  const size_t baseB = (size_t)blockIdx.z * strideB;
  const size_t baseO = (size_t)blockIdx.z * strideO;
  const int m0 = (w >> 1) * 64, n0 = (w & 1) * 64;
  char* cAh = (char*)sAh;
  char* cAl = (char*)sAl;
  char* cBh = (char*)sBh;
  char* cBl = (char*)sBl;

  f32x4 acc[4][4], accL[4][4];
#pragma unroll
  for (int i = 0; i < 4; ++i)
#pragma unroll
    for (int j = 0; j < 4; ++j) {
      acc[i][j] = (f32x4){0.f, 0.f, 0.f, 0.f};
      accL[i][j] = (f32x4){0.f, 0.f, 0.f, 0.f};
    }

  for (int kb = 0; kb < K; kb += 32) {
    __syncthreads();
#pragma unroll
    for (int rep = 0; rep < 2; ++rep) {
      int base = w * 64 + rep * 256;
      int s = inv_swz_r2(base + l);
      int row = s >> 2, ks = s & 3;
      size_t ga = baseA + (size_t)(bm + row) * K + kb + ks * 8;
      size_t gb = baseB + (size_t)(bn + row) * K + kb + ks * 8;
      ld_lds16(Ah + ga, cAh + base * 16);
      ld_lds16(Al + ga, cAl + base * 16);
      ld_lds16(Bh + gb, cBh + base * 16);
      ld_lds16(Bl + gb, cBl + base * 16);
    }
    __syncthreads();
    f16x8 ah[4], al[4];
#pragma unroll
    for (int mf = 0; mf < 4; ++mf) {
      int row = m0 + mf * 16 + (l & 15);
      int byte = swz(row * 64 + ((l >> 4) << 4), row);
      ah[mf] = *(const f16x8*)(cAh + byte);
      al[mf] = *(const f16x8*)(cAl + byte);
    }
#pragma unroll
    for (int nf = 0; nf < 4; ++nf) {
      int row = n0 + nf * 16 + (l & 15);
      int byte = swz(row * 64 + ((l >> 4) << 4), row);
      f16x8 bh = *(const f16x8*)(cBh + byte);
      f16x8 bl = *(const f16x8*)(cBl + byte);
#pragma unroll
      for (int mf = 0; mf < 4; ++mf)
        acc[mf][nf] = MFMA(ah[mf], bh, acc[mf][nf]);
#pragma unroll
      for (int mf = 0; mf < 4; ++mf)
        accL[mf][nf] = MFMA(al[mf], bh, accL[mf][nf]);
#pragma unroll
      for (int mf = 0; mf < 4; ++mf)
        accL[mf][nf] = MFMA(ah[mf], bl, accL[mf][nf]);
    }
  }

  if (F32OUT) {
#pragma unroll
    for (int mf = 0; mf < 4; ++mf)
#pragma unroll
      for (int r = 0; r < 4; ++r) {
        int mrow = bm + m0 + mf * 16 + ((l >> 4) << 2) + r;
        float bv = bias[mrow];
        double s = 0.0, q = 0.0;
#pragma unroll
        for (int nf = 0; nf < 4; ++nf) {
          float v = acc[mf][nf][r] + accL[mf][nf][r] * INV2048 + bv;
          Of[baseO + (size_t)mrow * N + bn + n0 + nf * 16 + (l & 15)] = v;
          s += (double)v;
          q += (double)v * (double)v;
        }
#pragma unroll
        for (int sh = 8; sh >= 1; sh >>= 1) {
          s += __shfl_xor(s, sh);
          q += __shfl_xor(q, sh);
        }
        if ((l & 15) == 0) {
          atomicAdd(&osum[mrow], s);
          atomicAdd(&osumsq[mrow], q);
        }
      }
  } else {
    for (int c = 0; c < 4; ++c) {
      __syncthreads();
      if ((w >> 1) == (c >> 1)) {
#pragma unroll
        for (int mf2 = 0; mf2 < 2; ++mf2) {
          int mf = (c & 1) * 2 + mf2;
          int rl = m0 - c * 32 + mf * 16 + ((l >> 4) << 2);
#pragma unroll
          for (int nf = 0; nf < 4; ++nf)
#pragma unroll
            for (int r = 0; r < 4; ++r)
              sOut[(rl + r) * 132 + n0 + nf * 16 + (l & 15)] =
                  acc[mf][nf][r] + accL[mf][nf][r] * INV2048;
        }
      }
      __syncthreads();
      int row = tid >> 3, cc0 = (tid & 7) * 16;
      size_t gm = bm + c * 32 + row;
      size_t ob = baseO + gm * (size_t)N + bn + cc0;
      f16 hv[16], lv[16];
#pragma unroll
      for (int e = 0; e < 16; ++e) {
        float v = sOut[row * 132 + cc0 + e];
        v += BIAS_N ? bias[bn + cc0 + e] : bias[gm];
        f16 h = (f16)v;
        hv[e] = h;
        lv[e] = (f16)((v - (float)h) * SC2048);
      }
      *(f16x8*)&Oh[ob] = *(f16x8*)hv;
      *(f16x8*)&Oh[ob + 8] = *(f16x8*)(hv + 8);
      *(f16x8*)&Ol[ob] = *(f16x8*)lv;
      *(f16x8*)&Ol[ob + 8] = *(f16x8*)(lv + 8);
    }
  }
}

// ---------------------------------------------------------------------------
// Fused flash attention (r13 + sS pad 33->34 to kill the 4-way bank conflict
// on the QK->sS writes; row groups now land +8 banks apart = <=2-way = free).
// ---------------------------------------------------------------------------
__global__ __launch_bounds__(512)
    __attribute__((amdgpu_waves_per_eu(2, 2))) void attn_mfma(
        const f16* __restrict__ th_h, const f16* __restrict__ th_l,
        const f16* __restrict__ ph_h, const f16* __restrict__ ph_l,
        const f16* __restrict__ g_h, const f16* __restrict__ g_l,
        f16* __restrict__ y_h, f16* __restrict__ y_l) {
  __shared__ f16 sPhiH[8192], sPhiL[8192];  // phi [32 j][256 c] swizzled
  __shared__ f16 sGH[8192], sGL[8192];      // g   [256 c][32 j] swizzled
  __shared__ float sS[2][64][34];           // partial S per K-half (pad 34)
  __shared__ f16 sP[2048], sPl[2048];       // P hi / scaled-lo [64][32]
  __shared__ float sSc[64], sL[64];
  const int tid = threadIdx.x, w = tid >> 6, l = tid & 63;
  const int b = blockIdx.x & 7;
  const int i0 = (blockIdx.x >> 3) * 64;
  const int gq = w >> 2;        // K-half for QK
  const int rw = (w & 3) * 16;  // QK row base

  const size_t tbase =
      ((size_t)b * TT + i0 + rw + (l & 15)) * 256 + gq * 128 + ((l >> 4) << 3);
  f16x8 qh[4], ql[4];
#pragma unroll
  for (int kf = 0; kf < 4; ++kf) {
    qh[kf] = *(const f16x8*)(th_h + tbase + kf * 32);
    ql[kf] = *(const f16x8*)(th_l + tbase + kf * 32);
  }
  f32x4 yacc[4][2], yaccL[4][2];
#pragma unroll
  for (int i = 0; i < 4; ++i)
#pragma unroll
    for (int j = 0; j < 2; ++j) {
      yacc[i][j] = (f32x4){0.f, 0.f, 0.f, 0.f};
      yaccL[i][j] = (f32x4){0.f, 0.f, 0.f, 0.f};
    }
  float mrow[4], lrow[4];
#pragma unroll
  for (int r = 0; r < 4; ++r) {
    mrow[r] = -3e38f;
    lrow[r] = 0.f;
  }

  for (int jc = 0; jc < 64; ++jc) {
    const int j0 = jc * 32;
#pragma unroll
    for (int rep = 0; rep < 2; ++rep) {
      int base = w * 64 + rep * 512;
      int s = inv_swz_r5(base + l);
      int row = s >> 5, kq = s & 31;
      size_t ga = ((size_t)b * TT + j0 + row) * 256 + kq * 8;
      ld_lds16(ph_h + ga, (char*)sPhiH + base * 16);
      ld_lds16(ph_l + ga, (char*)sPhiL + base * 16);
    }
#pragma unroll
    for (int rep = 0; rep < 2; ++rep) {
      int base = w * 64 + rep * 512;
      int s = inv_swz_r2(base + l);
      int row = s >> 2, kq = s & 3;
      size_t ga = ((size_t)b * 256 + row) * TT + j0 + kq * 8;
      ld_lds16(g_h + ga, (char*)sGH + base * 16);
      ld_lds16(g_l + ga, (char*)sGL + base * 16);
    }
    __syncthreads();  // A: tiles staged
    f32x4 s4[2] = {(f32x4){0.f, 0.f, 0.f, 0.f}, (f32x4){0.f, 0.f, 0.f, 0.f}};
    f32x4 s4L[2] = {(f32x4){0.f, 0.f, 0.f, 0.f}, (f32x4){0.f, 0.f, 0.f, 0.f}};
#pragma unroll
    for (int kf = 0; kf < 4; ++kf) {
#pragma unroll
      for (int jf = 0; jf < 2; ++jf) {
        int prow = jf * 16 + (l & 15);
        int byte =
            swz(prow * 512 + gq * 256 + kf * 64 + ((l >> 4) << 4), prow);
        f16x8 bh = *(const f16x8*)((char*)sPhiH + byte);
        f16x8 bl = *(const f16x8*)((char*)sPhiL + byte);
        s4[jf] = MFMA(qh[kf], bh, s4[jf]);
        s4L[jf] = MFMA(ql[kf], bh, s4L[jf]);
        s4L[jf] = MFMA(qh[kf], bl, s4L[jf]);
      }
    }
#pragma unroll
    for (int jf = 0; jf < 2; ++jf)
#pragma unroll
      for (int r = 0; r < 4; ++r) {
        int row = rw + ((l >> 4) << 2) + r;
        sS[gq][row][jf * 16 + (l & 15)] = s4[jf][r] + s4L[jf][r] * INV2048;
      }
    __syncthreads();  // B: S complete
    {
      int jcol = l & 31;
#pragma unroll
      for (int ry = 0; ry < 4; ++ry) {
        int row = w * 8 + (l >> 5) * 4 + ry;
        float sv = sS[0][row][jcol] + sS[1][row][jcol];
        float mx = sv;
#pragma unroll
        for (int sh = 16; sh >= 1; sh >>= 1) mx = fmaxf(mx, __shfl_xor(mx, sh));
        float mn = fmaxf(mrow[ry], mx);
        float sc = __expf(mrow[ry] - mn);
        mrow[ry] = mn;
        float p = __expf(sv - mn);
        float ls = p;
#pragma unroll
        for (int sh = 16; sh >= 1; sh >>= 1) ls += __shfl_xor(ls, sh);
        lrow[ry] = lrow[ry] * sc + ls;
        f16 h = (f16)p;
        *(f16*)((char*)sP + swz(row * 64 + jcol * 2, row)) = h;
        *(f16*)((char*)sPl + swz(row * 64 + jcol * 2, row)) =
            (f16)((p - (float)h) * SC2048);
        if (jcol == 0) sSc[row] = sc;
      }
    }
    __syncthreads();  // C: P + sSc published
#pragma unroll
    for (int mf = 0; mf < 4; ++mf)
#pragma unroll
      for (int r = 0; r < 4; ++r) {
        float s0 = sSc[mf * 16 + ((l >> 4) << 2) + r];
#pragma unroll
        for (int cf = 0; cf < 2; ++cf) {
          yacc[mf][cf][r] *= s0;
          yaccL[mf][cf][r] *= s0;
        }
      }
#pragma unroll
    for (int mf = 0; mf < 4; ++mf) {
      int prow = mf * 16 + (l & 15);
      int pb = swz(prow * 64 + ((l >> 4) << 4), prow);
      f16x8 pa = *(const f16x8*)((char*)sP + pb);
      f16x8 paL = *(const f16x8*)((char*)sPl + pb);
#pragma unroll
      for (int cf = 0; cf < 2; ++cf) {
        int crow = w * 32 + cf * 16 + (l & 15);
        int gb2 = swz(crow * 64 + ((l >> 4) << 4), crow);
        f16x8 gh = *(const f16x8*)((char*)sGH + gb2);
        f16x8 gl = *(const f16x8*)((char*)sGL + gb2);
        yacc[mf][cf] = MFMA(pa, gh, yacc[mf][cf]);
        yaccL[mf][cf] = MFMA(paL, gh, yaccL[mf][cf]);
        yaccL[mf][cf] = MFMA(pa, gl, yaccL[mf][cf]);
      }
    }
    __syncthreads();  // D: P/g reads done before next staging
  }

  if ((l & 31) == 0) {
#pragma unroll
    for (int ry = 0; ry < 4; ++ry) sL[w * 8 + (l >> 5) * 4 + ry] = lrow[ry];
  }
  __syncthreads();
  float* sOutF = (float*)sPhiH;
  for (int c2 = 0; c2 < 4; ++c2) {
#pragma unroll
    for (int r = 0; r < 4; ++r) {
      int row = c2 * 16 + ((l >> 4) << 2) + r;
      float linv = 1.f / sL[row];
      int rl = row - c2 * 16;
#pragma unroll
      for (int cf = 0; cf < 2; ++cf)
        sOutF[rl * 264 + w * 32 + cf * 16 + (l & 15)] =
            (yacc[c2][cf][r] + yaccL[c2][cf][r] * INV2048) * linv;
    }
    __syncthreads();
    int row = tid >> 5, cc0 = (tid & 31) * 8;
    size_t ob = ((size_t)b * TT + i0 + c2 * 16 + row) * 256 + cc0;
    f16 hv[8], lv[8];
#pragma unroll
    for (int e = 0; e < 8; ++e) {
      float v = sOutF[row * 264 + cc0 + e];
      f16 h = (f16)v;
      hv[e] = h;
      lv[e] = (f16)((v - (float)h) * SC2048);
    }
    *(f16x8*)&y_h[ob] = *(f16x8*)hv;
    *(f16x8*)&y_l[ob] = *(f16x8*)lv;
    __syncthreads();
  }
}

// ---------------------------------------------------------------------------
__global__ void zero_stats(double* s) { s[threadIdx.x] = 0.0; }

__global__ void bn_stats(const double* __restrict__ osum,
                         const double* __restrict__ osumsq,
                         float* __restrict__ mean, float* __restrict__ rstd) {
  int o = threadIdx.x;
  if (o < CC) {
    const double inv = 1.0 / (double)(BB * TT);
    double mu = osum[o] * inv;
    double var = osumsq[o] * inv - mu * mu;
    mean[o] = (float)mu;
    rstd[o] = (float)(1.0 / sqrt(var + (double)EPSV));
  }
}

__global__ __launch_bounds__(256) void bn_apply(
    float* __restrict__ out, const float* __restrict__ x,
    const float* __restrict__ mean, const float* __restrict__ rstd,
    const float* __restrict__ gamma, const float* __restrict__ beta) {
  const size_t n4 = (size_t)BB * CC * TT / 4;
  for (size_t idx = (size_t)blockIdx.x * blockDim.x + threadIdx.x; idx < n4;
       idx += (size_t)gridDim.x * blockDim.x) {
    size_t e = idx * 4;
    int o = (int)((e / TT) % CC);
    float4 wv = ((const float4*)out)[idx];
    float4 xv = ((const float4*)x)[idx];
    float mu = mean[o], rs = rstd[o], ga = gamma[o], be = beta[o];
    float4 r;
    r.x = fmaxf((wv.x - mu) * rs * ga + be, 0.f) + xv.x;
    r.y = fmaxf((wv.y - mu) * rs * ga + be, 0.f) + xv.y;
    r.z = fmaxf((wv.z - mu) * rs * ga + be, 0.f) + xv.z;
    r.w = fmaxf((wv.w - mu) * rs * ga + be, 0.f) + xv.w;
    ((float4*)out)[idx] = r;
  }
}

// ===========================================================================
// Fallback fp32 path (round-3, known-good) — used if ws too small.
// ===========================================================================
template <int M, int K, bool STATS>
__global__ __launch_bounds__(256) void gemm_proj(
    const float* __restrict__ W, const float* __restrict__ bias,
    const float* __restrict__ X, float* __restrict__ Out,
    double* __restrict__ osum, double* __restrict__ osumsq) {
  __shared__ float Ws[16][65];
  __shared__ float Xs[16][65];
  const int bt = blockIdx.x * 64, bm = blockIdx.y * 64, b = blockIdx.z;
  const int tid = threadIdx.x, tx = tid & 15, ty = tid >> 4;
  const float* Xb = X + (size_t)b * K * TT;
  float acc[4][4] = {};
  for (int kb = 0; kb < K; kb += 16) {
#pragma unroll
    for (int r = 0; r < 4; ++r) {
      int idx = tid + r * 256;
      int m = idx >> 4, k = idx & 15;
      Ws[k][m] = W[(size_t)(bm + m) * K + kb + k];
      int kx = idx >> 6, t = idx & 63;
      Xs[kx][t] = Xb[(size_t)(kb + kx) * TT + bt + t];
    }
    __syncthreads();
#pragma unroll
    for (int k = 0; k < 16; ++k) {
      float a[4], bv[4];
#pragma unroll
      for (int i = 0; i < 4; ++i) a[i] = Ws[k][ty * 4 + i];
#pragma unroll
      for (int j = 0; j < 4; ++j) bv[j] = Xs[k][tx * 4 + j];
#pragma unroll
      for (int i = 0; i < 4; ++i)
#pragma unroll
        for (int j = 0; j < 4; ++j) acc[i][j] += a[i] * bv[j];
    }
    __syncthreads();
  }
#pragma unroll
  for (int i = 0; i < 4; ++i) {
    int m = bm + ty * 4 + i;
    float bv = bias[m];
    double rs = 0.0, rq = 0.0;
#pragma unroll
    for (int j = 0; j < 4; ++j) {
      float v = acc[i][j] + bv;
      Out[((size_t)b * M + m) * TT + bt + tx * 4 + j] = v;
      if (STATS) {
        rs += (double)v;
        rq += (double)v * (double)v;
      }
    }
    if (STATS) {
#pragma unroll
      for (int s = 8; s >= 1; s >>= 1) {
        rs += __shfl_xor(rs, s, 16);
        rq += __shfl_xor(rq, s, 16);
      }
      if (tx == 0) {
        atomicAdd(&osum[m], rs);
        atomicAdd(&osumsq[m], rq);
      }
    }
  }
}

__global__ __launch_bounds__(256) void attn_flash(
    const float* __restrict__ th, const float* __restrict__ ph,
    const float* __restrict__ gx, float* __restrict__ y) {
  __shared__ float As[16][65];
  __shared__ float Bs[16][65];
  __shared__ float Ps[64][65];
  __shared__ float Gs[64][65];
  __shared__ float mScale[64];
  __shared__ float lArr[64];
  const int i0 = blockIdx.x * 64, b = blockIdx.y;
  const int tid = threadIdx.x, tx = tid & 15, ty = tid >> 4;
  const float* thb = th + (size_t)b * ICC * TT;
  const float* phb = ph + (size_t)b * ICC * TT;
  const float* gb = gx + (size_t)b * ICC * TT;
  float m[4], l[4];
#pragma unroll
  for (int i = 0; i < 4; ++i) {
    m[i] = -1e30f;
    l[i] = 0.f;
  }
  float acc[4][4][4] = {};
  for (int j0 = 0; j0 < TT; j0 += 64) {
    float S[4][4] = {};
    for (int cb = 0; cb < ICC; cb += 16) {
#pragma unroll
      for (int r = 0; r < 4; ++r) {
        int idx = tid + r * 256;
        int k = idx >> 6, col = idx & 63;
        As[k][col] = thb[(size_t)(cb + k) * TT + i0 + col];
        Bs[k][col] = phb[(size_t)(cb + k) * TT + j0 + col];
      }
      __syncthreads();
#pragma unroll
      for (int k = 0; k < 16; ++k) {
        float a[4], bv[4];
#pragma unroll
        for (int i = 0; i < 4; ++i) a[i] = As[k][ty * 4 + i];
#pragma unroll
        for (int j = 0; j < 4; ++j) bv[j] = Bs[k][tx * 4 + j];
#pragma unroll
        for (int i = 0; i < 4; ++i)
#pragma unroll
          for (int j = 0; j < 4; ++j) S[i][j] += a[i] * bv[j];
      }
      __syncthreads();
    }
    float sc[4];
#pragma unroll
    for (int i = 0; i < 4; ++i) {
      float mc = S[i][0];
#pragma unroll
      for (int j = 1; j < 4; ++j) mc = fmaxf(mc, S[i][j]);
#pragma unroll
      for (int s = 8; s >= 1; s >>= 1) mc = fmaxf(mc, __shfl_xor(mc, s, 16));
      float mn = fmaxf(m[i], mc);
      sc[i] = __expf(m[i] - mn);
      float lsum = 0.f;
#pragma unroll
      for (int j = 0; j < 4; ++j) {
        float p = __expf(S[i][j] - mn);
        S[i][j] = p;
        lsum += p;
      }
#pragma unroll
      for (int s = 8; s >= 1; s >>= 1) lsum += __shfl_xor(lsum, s, 16);
      l[i] = l[i] * sc[i] + lsum;
      m[i] = mn;
#pragma unroll
      for (int j = 0; j < 4; ++j) Ps[ty * 4 + i][tx * 4 + j] = S[i][j];
    }
    if (tx == 0) {
#pragma unroll
      for (int i = 0; i < 4; ++i) mScale[ty * 4 + i] = sc[i];
    }
    __syncthreads();
#pragma unroll
    for (int cq = 0; cq < 4; ++cq) {
#pragma unroll
      for (int r = 0; r < 16; ++r) {
        int idx = tid + r * 256;
        int cpr = idx >> 6, j = idx & 63;
        Gs[cpr][j] = gb[(size_t)(cq * 64 + cpr) * TT + j0 + j];
      }
      __syncthreads();
      float scj[4];
#pragma unroll
      for (int jq = 0; jq < 4; ++jq) scj[jq] = mScale[tx * 4 + jq];
#pragma unroll
      for (int ci = 0; ci < 4; ++ci)
#pragma unroll
        for (int jq = 0; jq < 4; ++jq) acc[cq][ci][jq] *= scj[jq];
      for (int j = 0; j < 64; ++j) {
        float a[4], p[4];
#pragma unroll
        for (int ci = 0; ci < 4; ++ci) a[ci] = Gs[ty * 4 + ci][j];
#pragma unroll
        for (int jq = 0; jq < 4; ++jq) p[jq] = Ps[tx * 4 + jq][j];
#pragma unroll
        for (int ci = 0; ci < 4; ++ci)
#pragma unroll
          for (int jq = 0; jq < 4; ++jq) acc[cq][ci][jq] += a[ci] * p[jq];
      }
      __syncthreads();
    }
  }
  if (tx == 0) {
#pragma unroll
    for (int i = 0; i < 4; ++i) lArr[ty * 4 + i] = l[i];
  }
  __syncthreads();
  float linv[4];
#pragma unroll
  for (int jq = 0; jq < 4; ++jq) linv[jq] = 1.f / lArr[tx * 4 + jq];
#pragma unroll
  for (int cq = 0; cq < 4; ++cq)
#pragma unroll
    for (int ci = 0; ci < 4; ++ci)
#pragma unroll
      for (int jq = 0; jq < 4; ++jq)
        y[((size_t)b * ICC + cq * 64 + ty * 4 + ci) * TT + i0 + tx * 4 + jq] =
            acc[cq][ci][jq] * linv[jq];
}

// ---------------------------------------------------------------------------
extern "C" void kernel_launch(void* const* d_in, const int* in_sizes, int n_in,
                              void* d_out, int out_size, void* d_ws,
                              size_t ws_size, hipStream_t stream) {
  const float* x = (const float*)d_in[0];
  const float* g_w = (const float*)d_in[1];
  const float* g_b = (const float*)d_in[2];
  const float* th_w = (const float*)d_in[3];
  const float* th_b = (const float*)d_in[4];
  const float* ph_w = (const float*)d_in[5];
  const float* ph_b = (const float*)d_in[6];
  const float* W_w = (const float*)d_in[7];
  const float* W_b = (const float*)d_in[8];
  const float* gamma = (const float*)d_in[9];
  const float* beta = (const float*)d_in[10];
  float* out = (float*)d_out;
  dim3 blk(256);

  const size_t NP = (size_t)BB * TT * ICC;  // 4,194,304
  const size_t NW = 131072;                 // 256*512
  const size_t need = (8 * NP + 8 * NW) * sizeof(f16) + 8192 + 4096;

  if (ws_size >= need) {
    // ---------------- fast MFMA path ----------------
    f16* p = (f16*)d_ws;
    f16 *thH = p, *thL = thH + NP, *phH = thL + NP, *phL = phH + NP;
    f16 *gH = phL + NP, *gL = gH + NP, *yH = gL + NP, *yL = yH + NP;
    f16* wp = yL + NP;
    f16 *gwH = wp, *gwL = gwH + NW, *twH = gwL + NW, *twL = twH + NW;
    f16 *pwH = twL + NW, *pwL = pwH + NW, *wwH = pwL + NW, *wwL = wwH + NW;
    double* statd = (double*)(wwL + NW);
    float* meanb = (float*)(statd + 1024);
    float* rstdb = meanb + 512;
    f16* xTh = (f16*)d_out;  // xT hi/lo lives in d_out (dead before W-conv)
    f16* xTl = xTh + (size_t)BB * TT * CC;

    split_transpose_x<<<dim3(TT / 32, CC / 32, BB), dim3(32, 8), 0, stream>>>(
        x, xTh, xTl);
    split_w<<<512, 256, 0, stream>>>(g_w, gwH, gwL, (int)NW);
    split_w<<<512, 256, 0, stream>>>(th_w, twH, twL, (int)NW);
    split_w<<<512, 256, 0, stream>>>(ph_w, pwH, pwL, (int)NW);
    split_w<<<512, 256, 0, stream>>>(W_w, wwH, wwL, (int)NW);
    zero_stats<<<1, 1024, 0, stream>>>(statd);

    // theta/phi: D[t][ic] = xT * W^T   (M=T, N=IC, K=C, bias on N)
    gemm_nt<TT, ICC, CC, true, false><<<dim3(2, 16, BB), blk, 0, stream>>>(
        xTh, xTl, (long)TT * CC, twH, twL, 0, th_b, thH, thL, nullptr,
        (long)TT * ICC, nullptr, nullptr);
    gemm_nt<TT, ICC, CC, true, false><<<dim3(2, 16, BB), blk, 0, stream>>>(
        xTh, xTl, (long)TT * CC, pwH, pwL, 0, ph_b, phH, phL, nullptr,
        (long)TT * ICC, nullptr, nullptr);
    // g: D[ic][t] = Wg * xT^T   (M=IC, N=T, K=C, bias on M)
    gemm_nt<ICC, TT, CC, false, false><<<dim3(16, 2, BB), blk, 0, stream>>>(
        gwH, gwL, 0, xTh, xTl, (long)TT * CC, g_b, gH, gL, nullptr,
        (long)ICC * TT, nullptr, nullptr);
    // attention -> y f16 hi/lo directly
    attn_mfma<<<256, dim3(512), 0, stream>>>(thH, thL, phH, phL, gH, gL, yH,
                                             yL);
    // W conv: D[o][t] -> d_out + BN stats  (M=C, N=T, K=IC, bias on M)
    gemm_nt<CC, TT, ICC, false, true><<<dim3(16, 4, BB), blk, 0, stream>>>(
        wwH, wwL, 0, yH, yL, (long)TT * ICC, W_b, nullptr, nullptr, out,
        (long)CC * TT, statd, statd + CC);
    bn_stats<<<1, 512, 0, stream>>>(statd, statd + CC, meanb, rstdb);
    bn_apply<<<2048, 256, 0, stream>>>(out, x, meanb, rstdb, gamma, beta);
  } else {
    // ---------------- fallback fp32 path ----------------
    float* ws = (float*)d_ws;
    const size_t np = (size_t)BB * ICC * TT;
    float* thb = ws;
    float* phb = ws + np;
    float* gbuf = ws + 2 * np;
    float* yb = thb;
    double* statd = (double*)(ws + 3 * np);
    float* meanb = (float*)(statd + 1024);
    float* rstdb = meanb + 512;
    gemm_proj<ICC, CC, false><<<dim3(TT / 64, ICC / 64, BB), blk, 0, stream>>>(
        th_w, th_b, x, thb, nullptr, nullptr);
    gemm_proj<ICC, CC, false><<<dim3(TT / 64, ICC / 64, BB), blk, 0, stream>>>(
        ph_w, ph_b, x, phb, nullptr, nullptr);
    gemm_proj<ICC, CC, false><<<dim3(TT / 64, ICC / 64, BB), blk, 0, stream>>>(
        g_w, g_b, x, gbuf, nullptr, nullptr);
    attn_flash<<<dim3(TT / 64, BB), blk, 0, stream>>>(thb, phb, gbuf, yb);
    zero_stats<<<1, 1024, 0, stream>>>(statd);
    gemm_proj<CC, ICC, true><<<dim3(TT / 64, CC / 64, BB), blk, 0, stream>>>(
        W_w, W_b, yb, out, statd, statd + CC);
    bn_stats<<<1, 512, 0, stream>>>(statd, statd + CC, meanb, rstdb);
    bn_apply<<<2048, 256, 0, stream>>>(out, x, meanb, rstdb, gamma, beta);
  }
}

// Round 18
// 424.325 us; speedup vs baseline: 1.1431x; 1.0998x over previous
//
#include <hip/hip_runtime.h>
#include <math.h>

#define BB 8
#define CC 512
#define TT 2048
#define ICC 256
#define EPSV 1e-5f
#define SC2048 2048.0f
#define INV2048 4.8828125e-4f

typedef _Float16 f16;
typedef __attribute__((ext_vector_type(8))) _Float16 f16x8;
typedef __attribute__((ext_vector_type(4))) float f32x4;

#define MFMA(a, b, c) __builtin_amdgcn_mfma_f32_16x16x32_f16(a, b, c, 0, 0, 0)

__device__ __forceinline__ int swz(int byte, int row) {
  return byte ^ ((row & 7) << 4);
}

// global -> LDS direct (16B/lane). LDS dest = wave-uniform base + lane*16.
__device__ __forceinline__ void ld_lds16(const void* g, void* l) {
  __builtin_amdgcn_global_load_lds(
      (const __attribute__((address_space(1))) unsigned int*)g,
      (__attribute__((address_space(3))) unsigned int*)l, 16, 0, 0);
}

// inverse of slot-swizzle o = s ^ ((s>>2)&7)  (row = slot>>2 layouts)
__device__ __forceinline__ int inv_swz_r2(int o) {
  return o ^ (((o >> 2) & 6) | (((o >> 2) ^ (o >> 4)) & 1));
}
// inverse of slot-swizzle o = s ^ ((s>>5)&7)  (row = slot>>5; involution)
__device__ __forceinline__ int inv_swz_r5(int o) { return o ^ ((o >> 5) & 7); }

// ---------------------------------------------------------------------------
// P0: x[b][c][t] f32 -> xT hi / scaled-lo f16 [b][t][c]
// ---------------------------------------------------------------------------
__global__ __launch_bounds__(256) void split_transpose_x(
    const float* __restrict__ x, f16* __restrict__ xh, f16* __restrict__ xl) {
  __shared__ float tile[32][33];
  const int tx = threadIdx.x, ty = threadIdx.y;
  const int t0 = blockIdx.x * 32, c0 = blockIdx.y * 32, b = blockIdx.z;
#pragma unroll
  for (int k = 0; k < 4; ++k)
    tile[ty + 8 * k][tx] = x[((size_t)b * CC + c0 + ty + 8 * k) * TT + t0 + tx];
  __syncthreads();
#pragma unroll
  for (int k = 0; k < 4; ++k) {
    float v = tile[tx][ty + 8 * k];
    size_t o = ((size_t)b * TT + t0 + ty + 8 * k) * CC + c0 + tx;
    f16 h = (f16)v;
    xh[o] = h;
    xl[o] = (f16)((v - (float)h) * SC2048);
  }
}

__global__ void split_w(const float* __restrict__ src, f16* __restrict__ h,
                        f16* __restrict__ lo, int n) {
  int i = blockIdx.x * 256 + threadIdx.x;
  if (i < n) {
    float v = src[i];
    f16 a = (f16)v;
    h[i] = a;
    lo[i] = (f16)((v - (float)a) * SC2048);
  }
}

// ---------------------------------------------------------------------------
// NT GEMM (r13 exact, best verified): D = A*B^T + bias, split-f16,
// gload_lds staging, 128x128 tile, 256 threads.
// ---------------------------------------------------------------------------
template <int M, int N, int K, bool BIAS_N, bool F32OUT>
__global__ __launch_bounds__(256) void gemm_nt(
    const f16* __restrict__ Ah, const f16* __restrict__ Al, long strideA,
    const f16* __restrict__ Bh, const f16* __restrict__ Bl, long strideB,
    const float* __restrict__ bias, f16* __restrict__ Oh, f16* __restrict__ Ol,
    float* __restrict__ Of, long strideO, double* __restrict__ osum,
    double* __restrict__ osumsq) {
  __shared__ f16 sAh[4096], sAl[4096], sBh[4096], sBl[4096];
  __shared__ float sOut[F32OUT ? 1 : 32 * 132];
  const int tid = threadIdx.x;
  const int w = tid >> 6, l = tid & 63;
  const int bn = blockIdx.x * 128, bm = blockIdx.y * 128;
  const size_t baseA = (size_t)blockIdx.z * strideA;
  const size_t baseB = (size_t)blockIdx.z * strideB;
  const size_t baseO = (size_t)blockIdx.z * strideO;
  const int m0 = (w >> 1) * 64, n0 = (w & 1) * 64;
  char* cAh = (char*)sAh;
  char* cAl = (char*)sAl;
  char* cBh = (char*)sBh;
  char* cBl = (char*)sBl;

  f32x4 acc[4][4], accL[4][4];
#pragma unroll
  for (int i = 0; i < 4; ++i)
#pragma unroll
    for (int j = 0; j < 4; ++j) {
      acc[i][j] = (f32x4){0.f, 0.f, 0.f, 0.f};
      accL[i][j] = (f32x4){0.f, 0.f, 0.f, 0.f};
    }

  for (int kb = 0; kb < K; kb += 32) {
    __syncthreads();
#pragma unroll
    for (int rep = 0; rep < 2; ++rep) {
      int base = w * 64 + rep * 256;
      int s = inv_swz_r2(base + l);
      int row = s >> 2, ks = s & 3;
      size_t ga = baseA + (size_t)(bm + row) * K + kb + ks * 8;
      size_t gb = baseB + (size_t)(bn + row) * K + kb + ks * 8;
      ld_lds16(Ah + ga, cAh + base * 16);
      ld_lds16(Al + ga, cAl + base * 16);
      ld_lds16(Bh + gb, cBh + base * 16);
      ld_lds16(Bl + gb, cBl + base * 16);
    }
    __syncthreads();
    f16x8 ah[4], al[4];
#pragma unroll
    for (int mf = 0; mf < 4; ++mf) {
      int row = m0 + mf * 16 + (l & 15);
      int byte = swz(row * 64 + ((l >> 4) << 4), row);
      ah[mf] = *(const f16x8*)(cAh + byte);
      al[mf] = *(const f16x8*)(cAl + byte);
    }
#pragma unroll
    for (int nf = 0; nf < 4; ++nf) {
      int row = n0 + nf * 16 + (l & 15);
      int byte = swz(row * 64 + ((l >> 4) << 4), row);
      f16x8 bh = *(const f16x8*)(cBh + byte);
      f16x8 bl = *(const f16x8*)(cBl + byte);
#pragma unroll
      for (int mf = 0; mf < 4; ++mf)
        acc[mf][nf] = MFMA(ah[mf], bh, acc[mf][nf]);
#pragma unroll
      for (int mf = 0; mf < 4; ++mf)
        accL[mf][nf] = MFMA(al[mf], bh, accL[mf][nf]);
#pragma unroll
      for (int mf = 0; mf < 4; ++mf)
        accL[mf][nf] = MFMA(ah[mf], bl, accL[mf][nf]);
    }
  }

  if (F32OUT) {
#pragma unroll
    for (int mf = 0; mf < 4; ++mf)
#pragma unroll
      for (int r = 0; r < 4; ++r) {
        int mrow = bm + m0 + mf * 16 + ((l >> 4) << 2) + r;
        float bv = bias[mrow];
        double s = 0.0, q = 0.0;
#pragma unroll
        for (int nf = 0; nf < 4; ++nf) {
          float v = acc[mf][nf][r] + accL[mf][nf][r] * INV2048 + bv;
          Of[baseO + (size_t)mrow * N + bn + n0 + nf * 16 + (l & 15)] = v;
          s += (double)v;
          q += (double)v * (double)v;
        }
#pragma unroll
        for (int sh = 8; sh >= 1; sh >>= 1) {
          s += __shfl_xor(s, sh);
          q += __shfl_xor(q, sh);
        }
        if ((l & 15) == 0) {
          atomicAdd(&osum[mrow], s);
          atomicAdd(&osumsq[mrow], q);
        }
      }
  } else {
    for (int c = 0; c < 4; ++c) {
      __syncthreads();
      if ((w >> 1) == (c >> 1)) {
#pragma unroll
        for (int mf2 = 0; mf2 < 2; ++mf2) {
          int mf = (c & 1) * 2 + mf2;
          int rl = m0 - c * 32 + mf * 16 + ((l >> 4) << 2);
#pragma unroll
          for (int nf = 0; nf < 4; ++nf)
#pragma unroll
            for (int r = 0; r < 4; ++r)
              sOut[(rl + r) * 132 + n0 + nf * 16 + (l & 15)] =
                  acc[mf][nf][r] + accL[mf][nf][r] * INV2048;
        }
      }
      __syncthreads();
      int row = tid >> 3, cc0 = (tid & 7) * 16;
      size_t gm = bm + c * 32 + row;
      size_t ob = baseO + gm * (size_t)N + bn + cc0;
      f16 hv[16], lv[16];
#pragma unroll
      for (int e = 0; e < 16; ++e) {
        float v = sOut[row * 132 + cc0 + e];
        v += BIAS_N ? bias[bn + cc0 + e] : bias[gm];
        f16 h = (f16)v;
        hv[e] = h;
        lv[e] = (f16)((v - (float)h) * SC2048);
      }
      *(f16x8*)&Oh[ob] = *(f16x8*)hv;
      *(f16x8*)&Oh[ob + 8] = *(f16x8*)(hv + 8);
      *(f16x8*)&Ol[ob] = *(f16x8*)lv;
      *(f16x8*)&Ol[ob + 8] = *(f16x8*)(lv + 8);
    }
  }
}

// ---------------------------------------------------------------------------
// Fused flash attention v7 (r18): j-split QK (r14 verified math, no sS) +
// double-buffered phi/g staging (r7 pattern) + 256-reg budget (r13 recipe).
//  - wave w: QK rows (w&3)*16..+16, j-half gj=w>>2, full K=256 in-wave
//    (qh[8]+ql[8] resident; fits the waves_per_eu(2,2) 256-reg budget).
//  - stage(jc+1) issued at loop top, drains at barrier B (hidden under QK).
//  - 3 barriers/chunk (was 4); no sS f32 round-trip.
// ---------------------------------------------------------------------------
__global__ __launch_bounds__(512)
    __attribute__((amdgpu_waves_per_eu(2, 2))) void attn_mfma(
        const f16* __restrict__ th_h, const f16* __restrict__ th_l,
        const f16* __restrict__ ph_h, const f16* __restrict__ ph_l,
        const f16* __restrict__ g_h, const f16* __restrict__ g_l,
        f16* __restrict__ y_h, f16* __restrict__ y_l) {
  __shared__ f16 sPhiH[2][8192], sPhiL[2][8192];  // phi [buf][32 j][256 c]
  __shared__ f16 sGH[2][8192], sGL[2][8192];      // g   [buf][256 c][32 j]
  __shared__ f16 sP[2048], sPl[2048];             // P hi / scaled-lo [64][32]
  __shared__ float sPm[2][64], sPs[2][64];        // per-row partial max/sum
  __shared__ float sSc[64], sL[64];
  const int tid = threadIdx.x, w = tid >> 6, l = tid & 63;
  const int b = blockIdx.x & 7;
  const int i0 = (blockIdx.x >> 3) * 64;
  const int gj = w >> 2;        // j-half this wave computes in QK
  const int rw = (w & 3) * 16;  // QK row base

  auto stagePhi = [&](int j0, int buf) {
#pragma unroll
    for (int rep = 0; rep < 2; ++rep) {
      int base = w * 64 + rep * 512;
      int s = inv_swz_r5(base + l);
      int row = s >> 5, kq = s & 31;
      size_t ga = ((size_t)b * TT + j0 + row) * 256 + kq * 8;
      ld_lds16(ph_h + ga, (char*)&sPhiH[buf][0] + base * 16);
      ld_lds16(ph_l + ga, (char*)&sPhiL[buf][0] + base * 16);
    }
  };
  auto stageG = [&](int j0, int buf) {
#pragma unroll
    for (int rep = 0; rep < 2; ++rep) {
      int base = w * 64 + rep * 512;
      int s = inv_swz_r2(base + l);
      int row = s >> 2, kq = s & 3;
      size_t ga = ((size_t)b * 256 + row) * TT + j0 + kq * 8;
      ld_lds16(g_h + ga, (char*)&sGH[buf][0] + base * 16);
      ld_lds16(g_l + ga, (char*)&sGL[buf][0] + base * 16);
    }
  };

  // theta fragments resident (full K: 8 hi + 8 lo = 64 VGPR)
  const size_t tbase =
      ((size_t)b * TT + i0 + rw + (l & 15)) * 256 + ((l >> 4) << 3);
  f16x8 qh[8], ql[8];
#pragma unroll
  for (int kf = 0; kf < 8; ++kf) {
    qh[kf] = *(const f16x8*)(th_h + tbase + kf * 32);
    ql[kf] = *(const f16x8*)(th_l + tbase + kf * 32);
  }
  f32x4 yacc[4][2], yaccL[4][2];
#pragma unroll
  for (int i = 0; i < 4; ++i)
#pragma unroll
    for (int j = 0; j < 2; ++j) {
      yacc[i][j] = (f32x4){0.f, 0.f, 0.f, 0.f};
      yaccL[i][j] = (f32x4){0.f, 0.f, 0.f, 0.f};
    }
  float mrow[4], lrow[4];  // rows rw + (l>>4)*4 + r (dup in paired wave)
#pragma unroll
  for (int r = 0; r < 4; ++r) {
    mrow[r] = -3e38f;
    lrow[r] = 0.f;
  }

  // prologue: stage chunk 0 into buf 0
  stagePhi(0, 0);
  stageG(0, 0);
  __syncthreads();

  for (int jc = 0; jc < 64; ++jc) {
    const int cur = jc & 1, nxt = cur ^ 1;
    // ---- issue next-chunk staging (drains at barrier B, hidden under QK)
    if (jc < 63) {
      stagePhi((jc + 1) * 32, nxt);
      stageG((jc + 1) * 32, nxt);
    }
    // ---- QK^T: full K=256, this wave's 16 rows x 16 j (half gj)
    f32x4 s4 = (f32x4){0.f, 0.f, 0.f, 0.f};
    f32x4 s4L = (f32x4){0.f, 0.f, 0.f, 0.f};
    {
      int prow = gj * 16 + (l & 15);
#pragma unroll
      for (int kf = 0; kf < 8; ++kf) {
        int byte = swz(prow * 512 + kf * 64 + ((l >> 4) << 4), prow);
        f16x8 bh = *(const f16x8*)((char*)&sPhiH[cur][0] + byte);
        f16x8 bl = *(const f16x8*)((char*)&sPhiL[cur][0] + byte);
        s4 = MFMA(qh[kf], bh, s4);
        s4L = MFMA(ql[kf], bh, s4L);
        s4L = MFMA(qh[kf], bl, s4L);
      }
    }
    float sv[4], pm[4];
#pragma unroll
    for (int r = 0; r < 4; ++r) {
      sv[r] = s4[r] + s4L[r] * INV2048;
      float mx = sv[r];
#pragma unroll
      for (int sh = 8; sh >= 1; sh >>= 1) mx = fmaxf(mx, __shfl_xor(mx, sh));
      pm[r] = mx;  // row max over this wave's 16 j
    }
    if ((l & 15) == 0) {
#pragma unroll
      for (int r = 0; r < 4; ++r) sPm[gj][rw + ((l >> 4) << 2) + r] = pm[r];
    }
    __syncthreads();  // B: partial maxima visible; staged loads drained
    float scr[4];
#pragma unroll
    for (int r = 0; r < 4; ++r) {
      int row = rw + ((l >> 4) << 2) + r;
      float mx = fmaxf(sPm[0][row], sPm[1][row]);
      float mn = fmaxf(mrow[r], mx);
      scr[r] = __expf(mrow[r] - mn);
      mrow[r] = mn;
      float p = __expf(sv[r] - mn);
      float ls = p;
#pragma unroll
      for (int sh = 8; sh >= 1; sh >>= 1) ls += __shfl_xor(ls, sh);
      int jj = gj * 16 + (l & 15);
      f16 h = (f16)p;
      *(f16*)((char*)sP + swz(row * 64 + jj * 2, row)) = h;
      *(f16*)((char*)sPl + swz(row * 64 + jj * 2, row)) =
          (f16)((p - (float)h) * SC2048);
      if ((l & 15) == 0) {
        sPs[gj][row] = ls;
        if (gj == 0) sSc[row] = scr[r];
      }
    }
    __syncthreads();  // C: P + partial sums + sSc published
    // ---- l update (paired waves compute identical values)
#pragma unroll
    for (int r = 0; r < 4; ++r) {
      int row = rw + ((l >> 4) << 2) + r;
      lrow[r] = lrow[r] * scr[r] + (sPs[0][row] + sPs[1][row]);
    }
    // ---- rescale accumulators (rows span all 64 -> via sSc)
#pragma unroll
    for (int mf = 0; mf < 4; ++mf)
#pragma unroll
      for (int r = 0; r < 4; ++r) {
        float s0 = sSc[mf * 16 + ((l >> 4) << 2) + r];
#pragma unroll
        for (int cf = 0; cf < 2; ++cf) {
          yacc[mf][cf][r] *= s0;
          yaccL[mf][cf][r] *= s0;
        }
      }
    // ---- PV: A=P (all 64 rows), B=g[cur] (wave's 32 channels), 3-pass
#pragma unroll
    for (int mf = 0; mf < 4; ++mf) {
      int prow = mf * 16 + (l & 15);
      int pb = swz(prow * 64 + ((l >> 4) << 4), prow);
      f16x8 pa = *(const f16x8*)((char*)sP + pb);
      f16x8 paL = *(const f16x8*)((char*)sPl + pb);
#pragma unroll
      for (int cf = 0; cf < 2; ++cf) {
        int crow = w * 32 + cf * 16 + (l & 15);
        int gb2 = swz(crow * 64 + ((l >> 4) << 4), crow);
        f16x8 gh = *(const f16x8*)((char*)&sGH[cur][0] + gb2);
        f16x8 gl = *(const f16x8*)((char*)&sGL[cur][0] + gb2);
        yacc[mf][cf] = MFMA(pa, gh, yacc[mf][cf]);
        yaccL[mf][cf] = MFMA(paL, gh, yaccL[mf][cf]);
        yaccL[mf][cf] = MFMA(pa, gl, yaccL[mf][cf]);
      }
    }
    __syncthreads();  // D: P/g reads done before next softmax/staging reuse
  }

  // ---- publish final l per row (gj==0 waves own rows rw..rw+16)
  if (gj == 0 && (l & 15) == 0) {
#pragma unroll
    for (int r = 0; r < 4; ++r) sL[rw + ((l >> 4) << 2) + r] = lrow[r];
  }
  __syncthreads();
  // ---- epilogue: normalized y via f32 LDS transpose, 4 chunks of 16 rows
  float* sOutF = (float*)&sPhiH[0][0];  // 32KB scratch (phi dead)
  for (int c2 = 0; c2 < 4; ++c2) {
#pragma unroll
    for (int r = 0; r < 4; ++r) {
      int row = c2 * 16 + ((l >> 4) << 2) + r;
      float linv = 1.f / sL[row];
      int rl = row - c2 * 16;
#pragma unroll
      for (int cf = 0; cf < 2; ++cf)
        sOutF[rl * 264 + w * 32 + cf * 16 + (l & 15)] =
            (yacc[c2][cf][r] + yaccL[c2][cf][r] * INV2048) * linv;
    }
    __syncthreads();
    int row = tid >> 5, cc0 = (tid & 31) * 8;
    size_t ob = ((size_t)b * TT + i0 + c2 * 16 + row) * 256 + cc0;
    f16 hv[8], lv[8];
#pragma unroll
    for (int e = 0; e < 8; ++e) {
      float v = sOutF[row * 264 + cc0 + e];
      f16 h = (f16)v;
      hv[e] = h;
      lv[e] = (f16)((v - (float)h) * SC2048);
    }
    *(f16x8*)&y_h[ob] = *(f16x8*)hv;
    *(f16x8*)&y_l[ob] = *(f16x8*)lv;
    __syncthreads();
  }
}

// ---------------------------------------------------------------------------
__global__ void zero_stats(double* s) { s[threadIdx.x] = 0.0; }

__global__ void bn_stats(const double* __restrict__ osum,
                         const double* __restrict__ osumsq,
                         float* __restrict__ mean, float* __restrict__ rstd) {
  int o = threadIdx.x;
  if (o < CC) {
    const double inv = 1.0 / (double)(BB * TT);
    double mu = osum[o] * inv;
    double var = osumsq[o] * inv - mu * mu;
    mean[o] = (float)mu;
    rstd[o] = (float)(1.0 / sqrt(var + (double)EPSV));
  }
}

__global__ __launch_bounds__(256) void bn_apply(
    float* __restrict__ out, const float* __restrict__ x,
    const float* __restrict__ mean, const float* __restrict__ rstd,
    const float* __restrict__ gamma, const float* __restrict__ beta) {
  const size_t n4 = (size_t)BB * CC * TT / 4;
  for (size_t idx = (size_t)blockIdx.x * blockDim.x + threadIdx.x; idx < n4;
       idx += (size_t)gridDim.x * blockDim.x) {
    size_t e = idx * 4;
    int o = (int)((e / TT) % CC);
    float4 wv = ((const float4*)out)[idx];
    float4 xv = ((const float4*)x)[idx];
    float mu = mean[o], rs = rstd[o], ga = gamma[o], be = beta[o];
    float4 r;
    r.x = fmaxf((wv.x - mu) * rs * ga + be, 0.f) + xv.x;
    r.y = fmaxf((wv.y - mu) * rs * ga + be, 0.f) + xv.y;
    r.z = fmaxf((wv.z - mu) * rs * ga + be, 0.f) + xv.z;
    r.w = fmaxf((wv.w - mu) * rs * ga + be, 0.f) + xv.w;
    ((float4*)out)[idx] = r;
  }
}

// ===========================================================================
// Fallback fp32 path (round-3, known-good) — used if ws too small.
// ===========================================================================
template <int M, int K, bool STATS>
__global__ __launch_bounds__(256) void gemm_proj(
    const float* __restrict__ W, const float* __restrict__ bias,
    const float* __restrict__ X, float* __restrict__ Out,
    double* __restrict__ osum, double* __restrict__ osumsq) {
  __shared__ float Ws[16][65];
  __shared__ float Xs[16][65];
  const int bt = blockIdx.x * 64, bm = blockIdx.y * 64, b = blockIdx.z;
  const int tid = threadIdx.x, tx = tid & 15, ty = tid >> 4;
  const float* Xb = X + (size_t)b * K * TT;
  float acc[4][4] = {};
  for (int kb = 0; kb < K; kb += 16) {
#pragma unroll
    for (int r = 0; r < 4; ++r) {
      int idx = tid + r * 256;
      int m = idx >> 4, k = idx & 15;
      Ws[k][m] = W[(size_t)(bm + m) * K + kb + k];
      int kx = idx >> 6, t = idx & 63;
      Xs[kx][t] = Xb[(size_t)(kb + kx) * TT + bt + t];
    }
    __syncthreads();
#pragma unroll
    for (int k = 0; k < 16; ++k) {
      float a[4], bv[4];
#pragma unroll
      for (int i = 0; i < 4; ++i) a[i] = Ws[k][ty * 4 + i];
#pragma unroll
      for (int j = 0; j < 4; ++j) bv[j] = Xs[k][tx * 4 + j];
#pragma unroll
      for (int i = 0; i < 4; ++i)
#pragma unroll
        for (int j = 0; j < 4; ++j) acc[i][j] += a[i] * bv[j];
    }
    __syncthreads();
  }
#pragma unroll
  for (int i = 0; i < 4; ++i) {
    int m = bm + ty * 4 + i;
    float bv = bias[m];
    double rs = 0.0, rq = 0.0;
#pragma unroll
    for (int j = 0; j < 4; ++j) {
      float v = acc[i][j] + bv;
      Out[((size_t)b * M + m) * TT + bt + tx * 4 + j] = v;
      if (STATS) {
        rs += (double)v;
        rq += (double)v * (double)v;
      }
    }
    if (STATS) {
#pragma unroll
      for (int s = 8; s >= 1; s >>= 1) {
        rs += __shfl_xor(rs, s, 16);
        rq += __shfl_xor(rq, s, 16);
      }
      if (tx == 0) {
        atomicAdd(&osum[m], rs);
        atomicAdd(&osumsq[m], rq);
      }
    }
  }
}

__global__ __launch_bounds__(256) void attn_flash(
    const float* __restrict__ th, const float* __restrict__ ph,
    const float* __restrict__ gx, float* __restrict__ y) {
  __shared__ float As[16][65];
  __shared__ float Bs[16][65];
  __shared__ float Ps[64][65];
  __shared__ float Gs[64][65];
  __shared__ float mScale[64];
  __shared__ float lArr[64];
  const int i0 = blockIdx.x * 64, b = blockIdx.y;
  const int tid = threadIdx.x, tx = tid & 15, ty = tid >> 4;
  const float* thb = th + (size_t)b * ICC * TT;
  const float* phb = ph + (size_t)b * ICC * TT;
  const float* gb = gx + (size_t)b * ICC * TT;
  float m[4], l[4];
#pragma unroll
  for (int i = 0; i < 4; ++i) {
    m[i] = -1e30f;
    l[i] = 0.f;
  }
  float acc[4][4][4] = {};
  for (int j0 = 0; j0 < TT; j0 += 64) {
    float S[4][4] = {};
    for (int cb = 0; cb < ICC; cb += 16) {
#pragma unroll
      for (int r = 0; r < 4; ++r) {
        int idx = tid + r * 256;
        int k = idx >> 6, col = idx & 63;
        As[k][col] = thb[(size_t)(cb + k) * TT + i0 + col];
        Bs[k][col] = phb[(size_t)(cb + k) * TT + j0 + col];
      }
      __syncthreads();
#pragma unroll
      for (int k = 0; k < 16; ++k) {
        float a[4], bv[4];
#pragma unroll
        for (int i = 0; i < 4; ++i) a[i] = As[k][ty * 4 + i];
#pragma unroll
        for (int j = 0; j < 4; ++j) bv[j] = Bs[k][tx * 4 + j];
#pragma unroll
        for (int i = 0; i < 4; ++i)
#pragma unroll
          for (int j = 0; j < 4; ++j) S[i][j] += a[i] * bv[j];
      }
      __syncthreads();
    }
    float sc[4];
#pragma unroll
    for (int i = 0; i < 4; ++i) {
      float mc = S[i][0];
#pragma unroll
      for (int j = 1; j < 4; ++j) mc = fmaxf(mc, S[i][j]);
#pragma unroll
      for (int s = 8; s >= 1; s >>= 1) mc = fmaxf(mc, __shfl_xor(mc, s, 16));
      float mn = fmaxf(m[i], mc);
      sc[i] = __expf(m[i] - mn);
      float lsum = 0.f;
#pragma unroll
      for (int j = 0; j < 4; ++j) {
        float p = __expf(S[i][j] - mn);
        S[i][j] = p;
        lsum += p;
      }
#pragma unroll
      for (int s = 8; s >= 1; s >>= 1) lsum += __shfl_xor(lsum, s, 16);
      l[i] = l[i] * sc[i] + lsum;
      m[i] = mn;
#pragma unroll
      for (int j = 0; j < 4; ++j) Ps[ty * 4 + i][tx * 4 + j] = S[i][j];
    }
    if (tx == 0) {
#pragma unroll
      for (int i = 0; i < 4; ++i) mScale[ty * 4 + i] = sc[i];
    }
    __syncthreads();
#pragma unroll
    for (int cq = 0; cq < 4; ++cq) {
#pragma unroll
      for (int r = 0; r < 16; ++r) {
        int idx = tid + r * 256;
        int cpr = idx >> 6, j = idx & 63;
        Gs[cpr][j] = gb[(size_t)(cq * 64 + cpr) * TT + j0 + j];
      }
      __syncthreads();
      float scj[4];
#pragma unroll
      for (int jq = 0; jq < 4; ++jq) scj[jq] = mScale[tx * 4 + jq];
#pragma unroll
      for (int ci = 0; ci < 4; ++ci)
#pragma unroll
        for (int jq = 0; jq < 4; ++jq) acc[cq][ci][jq] *= scj[jq];
      for (int j = 0; j < 64; ++j) {
        float a[4], p[4];
#pragma unroll
        for (int ci = 0; ci < 4; ++ci) a[ci] = Gs[ty * 4 + ci][j];
#pragma unroll
        for (int jq = 0; jq < 4; ++jq) p[jq] = Ps[tx * 4 + jq][j];
#pragma unroll
        for (int ci = 0; ci < 4; ++ci)
#pragma unroll
          for (int jq = 0; jq < 4; ++jq) acc[cq][ci][jq] += a[ci] * p[jq];
      }
      __syncthreads();
    }
  }
  if (tx == 0) {
#pragma unroll
    for (int i = 0; i < 4; ++i) lArr[ty * 4 + i] = l[i];
  }
  __syncthreads();
  float linv[4];
#pragma unroll
  for (int jq = 0; jq < 4; ++jq) linv[jq] = 1.f / lArr[tx * 4 + jq];
#pragma unroll
  for (int cq = 0; cq < 4; ++cq)
#pragma unroll
    for (int ci = 0; ci < 4; ++ci)
#pragma unroll
      for (int jq = 0; jq < 4; ++jq)
        y[((size_t)b * ICC + cq * 64 + ty * 4 + ci) * TT + i0 + tx * 4 + jq] =
            acc[cq][ci][jq] * linv[jq];
}

// ---------------------------------------------------------------------------
extern "C" void kernel_launch(void* const* d_in, const int* in_sizes, int n_in,
                              void* d_out, int out_size, void* d_ws,
                              size_t ws_size, hipStream_t stream) {
  const float* x = (const float*)d_in[0];
  const float* g_w = (const float*)d_in[1];
  const float* g_b = (const float*)d_in[2];
  const float* th_w = (const float*)d_in[3];
  const float* th_b = (const float*)d_in[4];
  const float* ph_w = (const float*)d_in[5];
  const float* ph_b = (const float*)d_in[6];
  const float* W_w = (const float*)d_in[7];
  const float* W_b = (const float*)d_in[8];
  const float* gamma = (const float*)d_in[9];
  const float* beta = (const float*)d_in[10];
  float* out = (float*)d_out;
  dim3 blk(256);

  const size_t NP = (size_t)BB * TT * ICC;  // 4,194,304
  const size_t NW = 131072;                 // 256*512
  const size_t need = (8 * NP + 8 * NW) * sizeof(f16) + 8192 + 4096;

  if (ws_size >= need) {
    // ---------------- fast MFMA path ----------------
    f16* p = (f16*)d_ws;
    f16 *thH = p, *thL = thH + NP, *phH = thL + NP, *phL = phH + NP;
    f16 *gH = phL + NP, *gL = gH + NP, *yH = gL + NP, *yL = yH + NP;
    f16* wp = yL + NP;
    f16 *gwH = wp, *gwL = gwH + NW, *twH = gwL + NW, *twL = twH + NW;
    f16 *pwH = twL + NW, *pwL = pwH + NW, *wwH = pwL + NW, *wwL = wwH + NW;
    double* statd = (double*)(wwL + NW);
    float* meanb = (float*)(statd + 1024);
    float* rstdb = meanb + 512;
    f16* xTh = (f16*)d_out;  // xT hi/lo lives in d_out (dead before W-conv)
    f16* xTl = xTh + (size_t)BB * TT * CC;

    split_transpose_x<<<dim3(TT / 32, CC / 32, BB), dim3(32, 8), 0, stream>>>(
        x, xTh, xTl);
    split_w<<<512, 256, 0, stream>>>(g_w, gwH, gwL, (int)NW);
    split_w<<<512, 256, 0, stream>>>(th_w, twH, twL, (int)NW);
    split_w<<<512, 256, 0, stream>>>(ph_w, pwH, pwL, (int)NW);
    split_w<<<512, 256, 0, stream>>>(W_w, wwH, wwL, (int)NW);
    zero_stats<<<1, 1024, 0, stream>>>(statd);

    // theta/phi: D[t][ic] = xT * W^T   (M=T, N=IC, K=C, bias on N)
    gemm_nt<TT, ICC, CC, true, false><<<dim3(2, 16, BB), blk, 0, stream>>>(
        xTh, xTl, (long)TT * CC, twH, twL, 0, th_b, thH, thL, nullptr,
        (long)TT * ICC, nullptr, nullptr);
    gemm_nt<TT, ICC, CC, true, false><<<dim3(2, 16, BB), blk, 0, stream>>>(
        xTh, xTl, (long)TT * CC, pwH, pwL, 0, ph_b, phH, phL, nullptr,
        (long)TT * ICC, nullptr, nullptr);
    // g: D[ic][t] = Wg * xT^T   (M=IC, N=T, K=C, bias on M)
    gemm_nt<ICC, TT, CC, false, false><<<dim3(16, 2, BB), blk, 0, stream>>>(
        gwH, gwL, 0, xTh, xTl, (long)TT * CC, g_b, gH, gL, nullptr,
        (long)ICC * TT, nullptr, nullptr);
    // attention -> y f16 hi/lo directly
    attn_mfma<<<256, dim3(512), 0, stream>>>(thH, thL, phH, phL, gH, gL, yH,
                                             yL);
    // W conv: D[o][t] -> d_out + BN stats  (M=C, N=T, K=IC, bias on M)
    gemm_nt<CC, TT, ICC, false, true><<<dim3(16, 4, BB), blk, 0, stream>>>(
        wwH, wwL, 0, yH, yL, (long)TT * ICC, W_b, nullptr, nullptr, out,
        (long)CC * TT, statd, statd + CC);
    bn_stats<<<1, 512, 0, stream>>>(statd, statd + CC, meanb, rstdb);
    bn_apply<<<2048, 256, 0, stream>>>(out, x, meanb, rstdb, gamma, beta);
  } else {
    // ---------------- fallback fp32 path ----------------
    float* ws = (float*)d_ws;
    const size_t np = (size_t)BB * ICC * TT;
    float* thb = ws;
    float* phb = ws + np;
    float* gbuf = ws + 2 * np;
    float* yb = thb;
    double* statd = (double*)(ws + 3 * np);
    float* meanb = (float*)(statd + 1024);
    float* rstdb = meanb + 512;
    gemm_proj<ICC, CC, false><<<dim3(TT / 64, ICC / 64, BB), blk, 0, stream>>>(
        th_w, th_b, x, thb, nullptr, nullptr);
    gemm_proj<ICC, CC, false><<<dim3(TT / 64, ICC / 64, BB), blk, 0, stream>>>(
        ph_w, ph_b, x, phb, nullptr, nullptr);
    gemm_proj<ICC, CC, false><<<dim3(TT / 64, ICC / 64, BB), blk, 0, stream>>>(
        g_w, g_b, x, gbuf, nullptr, nullptr);
    attn_flash<<<dim3(TT / 64, BB), blk, 0, stream>>>(thb, phb, gbuf, yb);
    zero_stats<<<1, 1024, 0, stream>>>(statd);
    gemm_proj<CC, ICC, true><<<dim3(TT / 64, CC / 64, BB), blk, 0, stream>>>(
        W_w, W_b, yb, out, statd, statd + CC);
    bn_stats<<<1, 512, 0, stream>>>(statd, statd + CC, meanb, rstdb);
    bn_apply<<<2048, 256, 0, stream>>>(out, x, meanb, rstdb, gamma, beta);
  }
}

// Round 19
// 424.271 us; speedup vs baseline: 1.1433x; 1.0001x over previous
//
#include <hip/hip_runtime.h>
#include <math.h>

#define BB 8
#define CC 512
#define TT 2048
#define ICC 256
#define EPSV 1e-5f
#define SC2048 2048.0f
#define INV2048 4.8828125e-4f

typedef _Float16 f16;
typedef __attribute__((ext_vector_type(8))) _Float16 f16x8;
typedef __attribute__((ext_vector_type(4))) float f32x4;

#define MFMA(a, b, c) __builtin_amdgcn_mfma_f32_16x16x32_f16(a, b, c, 0, 0, 0)

__device__ __forceinline__ int swz(int byte, int row) {
  return byte ^ ((row & 7) << 4);
}

// global -> LDS direct (16B/lane). LDS dest = wave-uniform base + lane*16.
__device__ __forceinline__ void ld_lds16(const void* g, void* l) {
  __builtin_amdgcn_global_load_lds(
      (const __attribute__((address_space(1))) unsigned int*)g,
      (__attribute__((address_space(3))) unsigned int*)l, 16, 0, 0);
}

// inverse of slot-swizzle o = s ^ ((s>>2)&7)  (row = slot>>2 layouts)
__device__ __forceinline__ int inv_swz_r2(int o) {
  return o ^ (((o >> 2) & 6) | (((o >> 2) ^ (o >> 4)) & 1));
}
// inverse of slot-swizzle o = s ^ ((s>>5)&7)  (row = slot>>5; involution)
__device__ __forceinline__ int inv_swz_r5(int o) { return o ^ ((o >> 5) & 7); }

// ---------------------------------------------------------------------------
// P0: x[b][c][t] f32 -> xT hi / scaled-lo f16 [b][t][c]
// ---------------------------------------------------------------------------
__global__ __launch_bounds__(256) void split_transpose_x(
    const float* __restrict__ x, f16* __restrict__ xh, f16* __restrict__ xl) {
  __shared__ float tile[32][33];
  const int tx = threadIdx.x, ty = threadIdx.y;
  const int t0 = blockIdx.x * 32, c0 = blockIdx.y * 32, b = blockIdx.z;
#pragma unroll
  for (int k = 0; k < 4; ++k)
    tile[ty + 8 * k][tx] = x[((size_t)b * CC + c0 + ty + 8 * k) * TT + t0 + tx];
  __syncthreads();
#pragma unroll
  for (int k = 0; k < 4; ++k) {
    float v = tile[tx][ty + 8 * k];
    size_t o = ((size_t)b * TT + t0 + ty + 8 * k) * CC + c0 + tx;
    f16 h = (f16)v;
    xh[o] = h;
    xl[o] = (f16)((v - (float)h) * SC2048);
  }
}

__global__ void split_w(const float* __restrict__ src, f16* __restrict__ h,
                        f16* __restrict__ lo, int n) {
  int i = blockIdx.x * 256 + threadIdx.x;
  if (i < n) {
    float v = src[i];
    f16 a = (f16)v;
    h[i] = a;
    lo[i] = (f16)((v - (float)a) * SC2048);
  }
}

// ---------------------------------------------------------------------------
// NT GEMM v4 (r19): r16's verified 8-wave 64x32-per-wave mapping + r18's
// double-buffered gload_lds staging with ONE barrier per K-step (the barrier
// both drains the prefetch and protects the just-read buffer).
// 512 threads, waves_per_eu(2,2), 64 KB LDS (f16 epilogue aliases tiles).
// grid (N/128, M/128, batch). wave w: m0=(w>>2)*64, n0=(w&3)*32.
// ---------------------------------------------------------------------------
template <int M, int N, int K, bool BIAS_N, bool F32OUT>
__global__ __launch_bounds__(512)
    __attribute__((amdgpu_waves_per_eu(2, 2))) void gemm_nt(
        const f16* __restrict__ Ah, const f16* __restrict__ Al, long strideA,
        const f16* __restrict__ Bh, const f16* __restrict__ Bl, long strideB,
        const float* __restrict__ bias, f16* __restrict__ Oh,
        f16* __restrict__ Ol, float* __restrict__ Of, long strideO,
        double* __restrict__ osum, double* __restrict__ osumsq) {
  __shared__ f16 sBuf[2][4][4096];  // [buf][Ah,Al,Bh,Bl][128 rows x 32 k]
  const int tid = threadIdx.x;
  const int w = tid >> 6, l = tid & 63;
  const int bn = blockIdx.x * 128, bm = blockIdx.y * 128;
  const size_t baseA = (size_t)blockIdx.z * strideA;
  const size_t baseB = (size_t)blockIdx.z * strideB;
  const size_t baseO = (size_t)blockIdx.z * strideO;
  const int m0 = (w >> 2) * 64, n0 = (w & 3) * 32;

  auto stage = [&](int kb, int buf) {
    int base = w * 64;
    int s = inv_swz_r2(base + l);
    int row = s >> 2, ks = s & 3;
    size_t ga = baseA + (size_t)(bm + row) * K + kb + ks * 8;
    size_t gb = baseB + (size_t)(bn + row) * K + kb + ks * 8;
    ld_lds16(Ah + ga, (char*)&sBuf[buf][0][0] + base * 16);
    ld_lds16(Al + ga, (char*)&sBuf[buf][1][0] + base * 16);
    ld_lds16(Bh + gb, (char*)&sBuf[buf][2][0] + base * 16);
    ld_lds16(Bl + gb, (char*)&sBuf[buf][3][0] + base * 16);
  };

  f32x4 acc[4][2], accL[4][2];
#pragma unroll
  for (int i = 0; i < 4; ++i)
#pragma unroll
    for (int j = 0; j < 2; ++j) {
      acc[i][j] = (f32x4){0.f, 0.f, 0.f, 0.f};
      accL[i][j] = (f32x4){0.f, 0.f, 0.f, 0.f};
    }

  stage(0, 0);
  __syncthreads();
  const int nsteps = K / 32;
  for (int st = 0; st < nsteps; ++st) {
    const int cur = st & 1, nxt = cur ^ 1;
    if (st + 1 < nsteps) stage((st + 1) * 32, nxt);
    char* cAh = (char*)&sBuf[cur][0][0];
    char* cAl = (char*)&sBuf[cur][1][0];
    char* cBh = (char*)&sBuf[cur][2][0];
    char* cBl = (char*)&sBuf[cur][3][0];
    f16x8 ah[4], al[4];
#pragma unroll
    for (int mf = 0; mf < 4; ++mf) {
      int row = m0 + mf * 16 + (l & 15);
      int byte = swz(row * 64 + ((l >> 4) << 4), row);
      ah[mf] = *(const f16x8*)(cAh + byte);
      al[mf] = *(const f16x8*)(cAl + byte);
    }
#pragma unroll
    for (int nf = 0; nf < 2; ++nf) {
      int row = n0 + nf * 16 + (l & 15);
      int byte = swz(row * 64 + ((l >> 4) << 4), row);
      f16x8 bh = *(const f16x8*)(cBh + byte);
      f16x8 bl = *(const f16x8*)(cBl + byte);
#pragma unroll
      for (int mf = 0; mf < 4; ++mf)
        acc[mf][nf] = MFMA(ah[mf], bh, acc[mf][nf]);
#pragma unroll
      for (int mf = 0; mf < 4; ++mf)
        accL[mf][nf] = MFMA(al[mf], bh, accL[mf][nf]);
#pragma unroll
      for (int mf = 0; mf < 4; ++mf)
        accL[mf][nf] = MFMA(ah[mf], bl, accL[mf][nf]);
    }
    __syncthreads();  // drains stage(st+1); protects cur before re-staging
  }

  if (F32OUT) {
#pragma unroll
    for (int mf = 0; mf < 4; ++mf)
#pragma unroll
      for (int r = 0; r < 4; ++r) {
        int mrow = bm + m0 + mf * 16 + ((l >> 4) << 2) + r;
        float bv = bias[mrow];
        double s = 0.0, q = 0.0;
#pragma unroll
        for (int nf = 0; nf < 2; ++nf) {
          float v = acc[mf][nf][r] + accL[mf][nf][r] * INV2048 + bv;
          Of[baseO + (size_t)mrow * N + bn + n0 + nf * 16 + (l & 15)] = v;
          s += (double)v;
          q += (double)v * (double)v;
        }
#pragma unroll
        for (int sh = 8; sh >= 1; sh >>= 1) {
          s += __shfl_xor(s, sh);
          q += __shfl_xor(q, sh);
        }
        if ((l & 15) == 0) {
          atomicAdd(&osum[mrow], s);
          atomicAdd(&osumsq[mrow], q);
        }
      }
  } else {
    // f16 epilogue: 4 chunks of 32 rows x 128 cols; sOut aliases dead tiles
    float* sOut = (float*)&sBuf[0][0][0];  // needs 16.9 KB of the 64 KB
    for (int c = 0; c < 4; ++c) {
      __syncthreads();
      if ((w >> 2) == (c >> 1)) {
#pragma unroll
        for (int mf2 = 0; mf2 < 2; ++mf2) {
          int mf = (c & 1) * 2 + mf2;
          int rl = mf2 * 16 + ((l >> 4) << 2);
#pragma unroll
          for (int nf = 0; nf < 2; ++nf)
#pragma unroll
            for (int r = 0; r < 4; ++r)
              sOut[(rl + r) * 132 + n0 + nf * 16 + (l & 15)] =
                  acc[mf][nf][r] + accL[mf][nf][r] * INV2048;
        }
      }
      __syncthreads();
      int row = tid >> 4, cc0 = (tid & 15) * 8;
      size_t gm = bm + c * 32 + row;
      size_t ob = baseO + gm * (size_t)N + bn + cc0;
      f16 hv[8], lv[8];
#pragma unroll
      for (int e = 0; e < 8; ++e) {
        float v = sOut[row * 132 + cc0 + e];
        v += BIAS_N ? bias[bn + cc0 + e] : bias[gm];
        f16 h = (f16)v;
        hv[e] = h;
        lv[e] = (f16)((v - (float)h) * SC2048);
      }
      *(f16x8*)&Oh[ob] = *(f16x8*)hv;
      *(f16x8*)&Ol[ob] = *(f16x8*)lv;
    }
  }
}

// ---------------------------------------------------------------------------
// Fused flash attention (r18 exact, verified 245us): j-split QK, dbuf staging,
// 3 barriers/chunk, waves_per_eu(2,2).
// ---------------------------------------------------------------------------
__global__ __launch_bounds__(512)
    __attribute__((amdgpu_waves_per_eu(2, 2))) void attn_mfma(
        const f16* __restrict__ th_h, const f16* __restrict__ th_l,
        const f16* __restrict__ ph_h, const f16* __restrict__ ph_l,
        const f16* __restrict__ g_h, const f16* __restrict__ g_l,
        f16* __restrict__ y_h, f16* __restrict__ y_l) {
  __shared__ f16 sPhiH[2][8192], sPhiL[2][8192];  // phi [buf][32 j][256 c]
  __shared__ f16 sGH[2][8192], sGL[2][8192];      // g   [buf][256 c][32 j]
  __shared__ f16 sP[2048], sPl[2048];             // P hi / scaled-lo [64][32]
  __shared__ float sPm[2][64], sPs[2][64];        // per-row partial max/sum
  __shared__ float sSc[64], sL[64];
  const int tid = threadIdx.x, w = tid >> 6, l = tid & 63;
  const int b = blockIdx.x & 7;
  const int i0 = (blockIdx.x >> 3) * 64;
  const int gj = w >> 2;        // j-half this wave computes in QK
  const int rw = (w & 3) * 16;  // QK row base

  auto stagePhi = [&](int j0, int buf) {
#pragma unroll
    for (int rep = 0; rep < 2; ++rep) {
      int base = w * 64 + rep * 512;
      int s = inv_swz_r5(base + l);
      int row = s >> 5, kq = s & 31;
      size_t ga = ((size_t)b * TT + j0 + row) * 256 + kq * 8;
      ld_lds16(ph_h + ga, (char*)&sPhiH[buf][0] + base * 16);
      ld_lds16(ph_l + ga, (char*)&sPhiL[buf][0] + base * 16);
    }
  };
  auto stageG = [&](int j0, int buf) {
#pragma unroll
    for (int rep = 0; rep < 2; ++rep) {
      int base = w * 64 + rep * 512;
      int s = inv_swz_r2(base + l);
      int row = s >> 2, kq = s & 3;
      size_t ga = ((size_t)b * 256 + row) * TT + j0 + kq * 8;
      ld_lds16(g_h + ga, (char*)&sGH[buf][0] + base * 16);
      ld_lds16(g_l + ga, (char*)&sGL[buf][0] + base * 16);
    }
  };

  const size_t tbase =
      ((size_t)b * TT + i0 + rw + (l & 15)) * 256 + ((l >> 4) << 3);
  f16x8 qh[8], ql[8];
#pragma unroll
  for (int kf = 0; kf < 8; ++kf) {
    qh[kf] = *(const f16x8*)(th_h + tbase + kf * 32);
    ql[kf] = *(const f16x8*)(th_l + tbase + kf * 32);
  }
  f32x4 yacc[4][2], yaccL[4][2];
#pragma unroll
  for (int i = 0; i < 4; ++i)
#pragma unroll
    for (int j = 0; j < 2; ++j) {
      yacc[i][j] = (f32x4){0.f, 0.f, 0.f, 0.f};
      yaccL[i][j] = (f32x4){0.f, 0.f, 0.f, 0.f};
    }
  float mrow[4], lrow[4];
#pragma unroll
  for (int r = 0; r < 4; ++r) {
    mrow[r] = -3e38f;
    lrow[r] = 0.f;
  }

  stagePhi(0, 0);
  stageG(0, 0);
  __syncthreads();

  for (int jc = 0; jc < 64; ++jc) {
    const int cur = jc & 1, nxt = cur ^ 1;
    if (jc < 63) {
      stagePhi((jc + 1) * 32, nxt);
      stageG((jc + 1) * 32, nxt);
    }
    f32x4 s4 = (f32x4){0.f, 0.f, 0.f, 0.f};
    f32x4 s4L = (f32x4){0.f, 0.f, 0.f, 0.f};
    {
      int prow = gj * 16 + (l & 15);
#pragma unroll
      for (int kf = 0; kf < 8; ++kf) {
        int byte = swz(prow * 512 + kf * 64 + ((l >> 4) << 4), prow);
        f16x8 bh = *(const f16x8*)((char*)&sPhiH[cur][0] + byte);
        f16x8 bl = *(const f16x8*)((char*)&sPhiL[cur][0] + byte);
        s4 = MFMA(qh[kf], bh, s4);
        s4L = MFMA(ql[kf], bh, s4L);
        s4L = MFMA(qh[kf], bl, s4L);
      }
    }
    float sv[4], pm[4];
#pragma unroll
    for (int r = 0; r < 4; ++r) {
      sv[r] = s4[r] + s4L[r] * INV2048;
      float mx = sv[r];
#pragma unroll
      for (int sh = 8; sh >= 1; sh >>= 1) mx = fmaxf(mx, __shfl_xor(mx, sh));
      pm[r] = mx;
    }
    if ((l & 15) == 0) {
#pragma unroll
      for (int r = 0; r < 4; ++r) sPm[gj][rw + ((l >> 4) << 2) + r] = pm[r];
    }
    __syncthreads();  // B: partial maxima visible; staged loads drained
    float scr[4];
#pragma unroll
    for (int r = 0; r < 4; ++r) {
      int row = rw + ((l >> 4) << 2) + r;
      float mx = fmaxf(sPm[0][row], sPm[1][row]);
      float mn = fmaxf(mrow[r], mx);
      scr[r] = __expf(mrow[r] - mn);
      mrow[r] = mn;
      float p = __expf(sv[r] - mn);
      float ls = p;
#pragma unroll
      for (int sh = 8; sh >= 1; sh >>= 1) ls += __shfl_xor(ls, sh);
      int jj = gj * 16 + (l & 15);
      f16 h = (f16)p;
      *(f16*)((char*)sP + swz(row * 64 + jj * 2, row)) = h;
      *(f16*)((char*)sPl + swz(row * 64 + jj * 2, row)) =
          (f16)((p - (float)h) * SC2048);
      if ((l & 15) == 0) {
        sPs[gj][row] = ls;
        if (gj == 0) sSc[row] = scr[r];
      }
    }
    __syncthreads();  // C: P + partial sums + sSc published
#pragma unroll
    for (int r = 0; r < 4; ++r) {
      int row = rw + ((l >> 4) << 2) + r;
      lrow[r] = lrow[r] * scr[r] + (sPs[0][row] + sPs[1][row]);
    }
#pragma unroll
    for (int mf = 0; mf < 4; ++mf)
#pragma unroll
      for (int r = 0; r < 4; ++r) {
        float s0 = sSc[mf * 16 + ((l >> 4) << 2) + r];
#pragma unroll
        for (int cf = 0; cf < 2; ++cf) {
          yacc[mf][cf][r] *= s0;
          yaccL[mf][cf][r] *= s0;
        }
      }
#pragma unroll
    for (int mf = 0; mf < 4; ++mf) {
      int prow = mf * 16 + (l & 15);
      int pb = swz(prow * 64 + ((l >> 4) << 4), prow);
      f16x8 pa = *(const f16x8*)((char*)sP + pb);
      f16x8 paL = *(const f16x8*)((char*)sPl + pb);
#pragma unroll
      for (int cf = 0; cf < 2; ++cf) {
        int crow = w * 32 + cf * 16 + (l & 15);
        int gb2 = swz(crow * 64 + ((l >> 4) << 4), crow);
        f16x8 gh = *(const f16x8*)((char*)&sGH[cur][0] + gb2);
        f16x8 gl = *(const f16x8*)((char*)&sGL[cur][0] + gb2);
        yacc[mf][cf] = MFMA(pa, gh, yacc[mf][cf]);
        yaccL[mf][cf] = MFMA(paL, gh, yaccL[mf][cf]);
        yaccL[mf][cf] = MFMA(pa, gl, yaccL[mf][cf]);
      }
    }
    __syncthreads();  // D: P/g reads done before next softmax/staging reuse
  }

  if (gj == 0 && (l & 15) == 0) {
#pragma unroll
    for (int r = 0; r < 4; ++r) sL[rw + ((l >> 4) << 2) + r] = lrow[r];
  }
  __syncthreads();
  float* sOutF = (float*)&sPhiH[0][0];
  for (int c2 = 0; c2 < 4; ++c2) {
#pragma unroll
    for (int r = 0; r < 4; ++r) {
      int row = c2 * 16 + ((l >> 4) << 2) + r;
      float linv = 1.f / sL[row];
      int rl = row - c2 * 16;
#pragma unroll
      for (int cf = 0; cf < 2; ++cf)
        sOutF[rl * 264 + w * 32 + cf * 16 + (l & 15)] =
            (yacc[c2][cf][r] + yaccL[c2][cf][r] * INV2048) * linv;
    }
    __syncthreads();
    int row = tid >> 5, cc0 = (tid & 31) * 8;
    size_t ob = ((size_t)b * TT + i0 + c2 * 16 + row) * 256 + cc0;
    f16 hv[8], lv[8];
#pragma unroll
    for (int e = 0; e < 8; ++e) {
      float v = sOutF[row * 264 + cc0 + e];
      f16 h = (f16)v;
      hv[e] = h;
      lv[e] = (f16)((v - (float)h) * SC2048);
    }
    *(f16x8*)&y_h[ob] = *(f16x8*)hv;
    *(f16x8*)&y_l[ob] = *(f16x8*)lv;
    __syncthreads();
  }
}

// ---------------------------------------------------------------------------
__global__ void zero_stats(double* s) { s[threadIdx.x] = 0.0; }

__global__ void bn_stats(const double* __restrict__ osum,
                         const double* __restrict__ osumsq,
                         float* __restrict__ mean, float* __restrict__ rstd) {
  int o = threadIdx.x;
  if (o < CC) {
    const double inv = 1.0 / (double)(BB * TT);
    double mu = osum[o] * inv;
    double var = osumsq[o] * inv - mu * mu;
    mean[o] = (float)mu;
    rstd[o] = (float)(1.0 / sqrt(var + (double)EPSV));
  }
}

__global__ __launch_bounds__(256) void bn_apply(
    float* __restrict__ out, const float* __restrict__ x,
    const float* __restrict__ mean, const float* __restrict__ rstd,
    const float* __restrict__ gamma, const float* __restrict__ beta) {
  const size_t n4 = (size_t)BB * CC * TT / 4;
  for (size_t idx = (size_t)blockIdx.x * blockDim.x + threadIdx.x; idx < n4;
       idx += (size_t)gridDim.x * blockDim.x) {
    size_t e = idx * 4;
    int o = (int)((e / TT) % CC);
    float4 wv = ((const float4*)out)[idx];
    float4 xv = ((const float4*)x)[idx];
    float mu = mean[o], rs = rstd[o], ga = gamma[o], be = beta[o];
    float4 r;
    r.x = fmaxf((wv.x - mu) * rs * ga + be, 0.f) + xv.x;
    r.y = fmaxf((wv.y - mu) * rs * ga + be, 0.f) + xv.y;
    r.z = fmaxf((wv.z - mu) * rs * ga + be, 0.f) + xv.z;
    r.w = fmaxf((wv.w - mu) * rs * ga + be, 0.f) + xv.w;
    ((float4*)out)[idx] = r;
  }
}

// ===========================================================================
// Fallback fp32 path (round-3, known-good) — used if ws too small.
// ===========================================================================
template <int M, int K, bool STATS>
__global__ __launch_bounds__(256) void gemm_proj(
    const float* __restrict__ W, const float* __restrict__ bias,
    const float* __restrict__ X, float* __restrict__ Out,
    double* __restrict__ osum, double* __restrict__ osumsq) {
  __shared__ float Ws[16][65];
  __shared__ float Xs[16][65];
  const int bt = blockIdx.x * 64, bm = blockIdx.y * 64, b = blockIdx.z;
  const int tid = threadIdx.x, tx = tid & 15, ty = tid >> 4;
  const float* Xb = X + (size_t)b * K * TT;
  float acc[4][4] = {};
  for (int kb = 0; kb < K; kb += 16) {
#pragma unroll
    for (int r = 0; r < 4; ++r) {
      int idx = tid + r * 256;
      int m = idx >> 4, k = idx & 15;
      Ws[k][m] = W[(size_t)(bm + m) * K + kb + k];
      int kx = idx >> 6, t = idx & 63;
      Xs[kx][t] = Xb[(size_t)(kb + kx) * TT + bt + t];
    }
    __syncthreads();
#pragma unroll
    for (int k = 0; k < 16; ++k) {
      float a[4], bv[4];
#pragma unroll
      for (int i = 0; i < 4; ++i) a[i] = Ws[k][ty * 4 + i];
#pragma unroll
      for (int j = 0; j < 4; ++j) bv[j] = Xs[k][tx * 4 + j];
#pragma unroll
      for (int i = 0; i < 4; ++i)
#pragma unroll
        for (int j = 0; j < 4; ++j) acc[i][j] += a[i] * bv[j];
    }
    __syncthreads();
  }
#pragma unroll
  for (int i = 0; i < 4; ++i) {
    int m = bm + ty * 4 + i;
    float bv = bias[m];
    double rs = 0.0, rq = 0.0;
#pragma unroll
    for (int j = 0; j < 4; ++j) {
      float v = acc[i][j] + bv;
      Out[((size_t)b * M + m) * TT + bt + tx * 4 + j] = v;
      if (STATS) {
        rs += (double)v;
        rq += (double)v * (double)v;
      }
    }
    if (STATS) {
#pragma unroll
      for (int s = 8; s >= 1; s >>= 1) {
        rs += __shfl_xor(rs, s, 16);
        rq += __shfl_xor(rq, s, 16);
      }
      if (tx == 0) {
        atomicAdd(&osum[m], rs);
        atomicAdd(&osumsq[m], rq);
      }
    }
  }
}

__global__ __launch_bounds__(256) void attn_flash(
    const float* __restrict__ th, const float* __restrict__ ph,
    const float* __restrict__ gx, float* __restrict__ y) {
  __shared__ float As[16][65];
  __shared__ float Bs[16][65];
  __shared__ float Ps[64][65];
  __shared__ float Gs[64][65];
  __shared__ float mScale[64];
  __shared__ float lArr[64];
  const int i0 = blockIdx.x * 64, b = blockIdx.y;
  const int tid = threadIdx.x, tx = tid & 15, ty = tid >> 4;
  const float* thb = th + (size_t)b * ICC * TT;
  const float* phb = ph + (size_t)b * ICC * TT;
  const float* gb = gx + (size_t)b * ICC * TT;
  float m[4], l[4];
#pragma unroll
  for (int i = 0; i < 4; ++i) {
    m[i] = -1e30f;
    l[i] = 0.f;
  }
  float acc[4][4][4] = {};
  for (int j0 = 0; j0 < TT; j0 += 64) {
    float S[4][4] = {};
    for (int cb = 0; cb < ICC; cb += 16) {
#pragma unroll
      for (int r = 0; r < 4; ++r) {
        int idx = tid + r * 256;
        int k = idx >> 6, col = idx & 63;
        As[k][col] = thb[(size_t)(cb + k) * TT + i0 + col];
        Bs[k][col] = phb[(size_t)(cb + k) * TT + j0 + col];
      }
      __syncthreads();
#pragma unroll
      for (int k = 0; k < 16; ++k) {
        float a[4], bv[4];
#pragma unroll
        for (int i = 0; i < 4; ++i) a[i] = As[k][ty * 4 + i];
#pragma unroll
        for (int j = 0; j < 4; ++j) bv[j] = Bs[k][tx * 4 + j];
#pragma unroll
        for (int i = 0; i < 4; ++i)
#pragma unroll
          for (int j = 0; j < 4; ++j) S[i][j] += a[i] * bv[j];
      }
      __syncthreads();
    }
    float sc[4];
#pragma unroll
    for (int i = 0; i < 4; ++i) {
      float mc = S[i][0];
#pragma unroll
      for (int j = 1; j < 4; ++j) mc = fmaxf(mc, S[i][j]);
#pragma unroll
      for (int s = 8; s >= 1; s >>= 1) mc = fmaxf(mc, __shfl_xor(mc, s, 16));
      float mn = fmaxf(m[i], mc);
      sc[i] = __expf(m[i] - mn);
      float lsum = 0.f;
#pragma unroll
      for (int j = 0; j < 4; ++j) {
        float p = __expf(S[i][j] - mn);
        S[i][j] = p;
        lsum += p;
      }
#pragma unroll
      for (int s = 8; s >= 1; s >>= 1) lsum += __shfl_xor(lsum, s, 16);
      l[i] = l[i] * sc[i] + lsum;
      m[i] = mn;
#pragma unroll
      for (int j = 0; j < 4; ++j) Ps[ty * 4 + i][tx * 4 + j] = S[i][j];
    }
    if (tx == 0) {
#pragma unroll
      for (int i = 0; i < 4; ++i) mScale[ty * 4 + i] = sc[i];
    }
    __syncthreads();
#pragma unroll
    for (int cq = 0; cq < 4; ++cq) {
#pragma unroll
      for (int r = 0; r < 16; ++r) {
        int idx = tid + r * 256;
        int cpr = idx >> 6, j = idx & 63;
        Gs[cpr][j] = gb[(size_t)(cq * 64 + cpr) * TT + j0 + j];
      }
      __syncthreads();
      float scj[4];
#pragma unroll
      for (int jq = 0; jq < 4; ++jq) scj[jq] = mScale[tx * 4 + jq];
#pragma unroll
      for (int ci = 0; ci < 4; ++ci)
#pragma unroll
        for (int jq = 0; jq < 4; ++jq) acc[cq][ci][jq] *= scj[jq];
      for (int j = 0; j < 64; ++j) {
        float a[4], p[4];
#pragma unroll
        for (int ci = 0; ci < 4; ++ci) a[ci] = Gs[ty * 4 + ci][j];
#pragma unroll
        for (int jq = 0; jq < 4; ++jq) p[jq] = Ps[tx * 4 + jq][j];
#pragma unroll
        for (int ci = 0; ci < 4; ++ci)
#pragma unroll
          for (int jq = 0; jq < 4; ++jq) acc[cq][ci][jq] += a[ci] * p[jq];
      }
      __syncthreads();
    }
  }
  if (tx == 0) {
#pragma unroll
    for (int i = 0; i < 4; ++i) lArr[ty * 4 + i] = l[i];
  }
  __syncthreads();
  float linv[4];
#pragma unroll
  for (int jq = 0; jq < 4; ++jq) linv[jq] = 1.f / lArr[tx * 4 + jq];
#pragma unroll
  for (int cq = 0; cq < 4; ++cq)
#pragma unroll
    for (int ci = 0; ci < 4; ++ci)
#pragma unroll
      for (int jq = 0; jq < 4; ++jq)
        y[((size_t)b * ICC + cq * 64 + ty * 4 + ci) * TT + i0 + tx * 4 + jq] =
            acc[cq][ci][jq] * linv[jq];
}

// ---------------------------------------------------------------------------
extern "C" void kernel_launch(void* const* d_in, const int* in_sizes, int n_in,
                              void* d_out, int out_size, void* d_ws,
                              size_t ws_size, hipStream_t stream) {
  const float* x = (const float*)d_in[0];
  const float* g_w = (const float*)d_in[1];
  const float* g_b = (const float*)d_in[2];
  const float* th_w = (const float*)d_in[3];
  const float* th_b = (const float*)d_in[4];
  const float* ph_w = (const float*)d_in[5];
  const float* ph_b = (const float*)d_in[6];
  const float* W_w = (const float*)d_in[7];
  const float* W_b = (const float*)d_in[8];
  const float* gamma = (const float*)d_in[9];
  const float* beta = (const float*)d_in[10];
  float* out = (float*)d_out;
  dim3 blk(256);

  const size_t NP = (size_t)BB * TT * ICC;  // 4,194,304
  const size_t NW = 131072;                 // 256*512
  const size_t need = (8 * NP + 8 * NW) * sizeof(f16) + 8192 + 4096;

  if (ws_size >= need) {
    // ---------------- fast MFMA path ----------------
    f16* p = (f16*)d_ws;
    f16 *thH = p, *thL = thH + NP, *phH = thL + NP, *phL = phH + NP;
    f16 *gH = phL + NP, *gL = gH + NP, *yH = gL + NP, *yL = yH + NP;
    f16* wp = yL + NP;
    f16 *gwH = wp, *gwL = gwH + NW, *twH = gwL + NW, *twL = twH + NW;
    f16 *pwH = twL + NW, *pwL = pwH + NW, *wwH = pwL + NW, *wwL = wwH + NW;
    double* statd = (double*)(wwL + NW);
    float* meanb = (float*)(statd + 1024);
    float* rstdb = meanb + 512;
    f16* xTh = (f16*)d_out;  // xT hi/lo lives in d_out (dead before W-conv)
    f16* xTl = xTh + (size_t)BB * TT * CC;

    split_transpose_x<<<dim3(TT / 32, CC / 32, BB), dim3(32, 8), 0, stream>>>(
        x, xTh, xTl);
    split_w<<<512, 256, 0, stream>>>(g_w, gwH, gwL, (int)NW);
    split_w<<<512, 256, 0, stream>>>(th_w, twH, twL, (int)NW);
    split_w<<<512, 256, 0, stream>>>(ph_w, pwH, pwL, (int)NW);
    split_w<<<512, 256, 0, stream>>>(W_w, wwH, wwL, (int)NW);
    zero_stats<<<1, 1024, 0, stream>>>(statd);

    // theta/phi: D[t][ic] = xT * W^T   (M=T, N=IC, K=C, bias on N)
    gemm_nt<TT, ICC, CC, true, false><<<dim3(2, 16, BB), dim3(512), 0,
                                        stream>>>(
        xTh, xTl, (long)TT * CC, twH, twL, 0, th_b, thH, thL, nullptr,
        (long)TT * ICC, nullptr, nullptr);
    gemm_nt<TT, ICC, CC, true, false><<<dim3(2, 16, BB), dim3(512), 0,
                                        stream>>>(
        xTh, xTl, (long)TT * CC, pwH, pwL, 0, ph_b, phH, phL, nullptr,
        (long)TT * ICC, nullptr, nullptr);
    // g: D[ic][t] = Wg * xT^T   (M=IC, N=T, K=C, bias on M)
    gemm_nt<ICC, TT, CC, false, false><<<dim3(16, 2, BB), dim3(512), 0,
                                         stream>>>(
        gwH, gwL, 0, xTh, xTl, (long)TT * CC, g_b, gH, gL, nullptr,
        (long)ICC * TT, nullptr, nullptr);
    // attention -> y f16 hi/lo directly (r18 exact)
    attn_mfma<<<256, dim3(512), 0, stream>>>(thH, thL, phH, phL, gH, gL, yH,
                                             yL);
    // W conv: D[o][t] -> d_out + BN stats  (M=C, N=T, K=IC, bias on M)
    gemm_nt<CC, TT, ICC, false, true><<<dim3(16, 4, BB), dim3(512), 0,
                                        stream>>>(
        wwH, wwL, 0, yH, yL, (long)TT * ICC, W_b, nullptr, nullptr, out,
        (long)CC * TT, statd, statd + CC);
    bn_stats<<<1, 512, 0, stream>>>(statd, statd + CC, meanb, rstdb);
    bn_apply<<<2048, 256, 0, stream>>>(out, x, meanb, rstdb, gamma, beta);
  } else {
    // ---------------- fallback fp32 path ----------------
    float* ws = (float*)d_ws;
    const size_t np = (size_t)BB * ICC * TT;
    float* thb = ws;
    float* phb = ws + np;
    float* gbuf = ws + 2 * np;
    float* yb = thb;
    double* statd = (double*)(ws + 3 * np);
    float* meanb = (float*)(statd + 1024);
    float* rstdb = meanb + 512;
    gemm_proj<ICC, CC, false><<<dim3(TT / 64, ICC / 64, BB), blk, 0, stream>>>(
        th_w, th_b, x, thb, nullptr, nullptr);
    gemm_proj<ICC, CC, false><<<dim3(TT / 64, ICC / 64, BB), blk, 0, stream>>>(
        ph_w, ph_b, x, phb, nullptr, nullptr);
    gemm_proj<ICC, CC, false><<<dim3(TT / 64, ICC / 64, BB), blk, 0, stream>>>(
        g_w, g_b, x, gbuf, nullptr, nullptr);
    attn_flash<<<dim3(TT / 64, BB), blk, 0, stream>>>(thb, phb, gbuf, yb);
    zero_stats<<<1, 1024, 0, stream>>>(statd);
    gemm_proj<CC, ICC, true><<<dim3(TT / 64, CC / 64, BB), blk, 0, stream>>>(
        W_w, W_b, yb, out, statd, statd + CC);
    bn_stats<<<1, 512, 0, stream>>>(statd, statd + CC, meanb, rstdb);
    bn_apply<<<2048, 256, 0, stream>>>(out, x, meanb, rstdb, gamma, beta);
  }
}

// Round 21
// 410.140 us; speedup vs baseline: 1.1827x; 1.0345x over previous
//
#include <hip/hip_runtime.h>
#include <math.h>

#define BB 8
#define CC 512
#define TT 2048
#define ICC 256
#define EPSV 1e-5f
#define SC2048 2048.0f
#define INV2048 4.8828125e-4f

typedef _Float16 f16;
typedef __attribute__((ext_vector_type(8))) _Float16 f16x8;
typedef __attribute__((ext_vector_type(4))) float f32x4;

#define MFMA(a, b, c) __builtin_amdgcn_mfma_f32_16x16x32_f16(a, b, c, 0, 0, 0)

__device__ __forceinline__ int swz(int byte, int row) {
  return byte ^ ((row & 7) << 4);
}

// global -> LDS direct (16B/lane). LDS dest = wave-uniform base + lane*16.
__device__ __forceinline__ void ld_lds16(const void* g, void* l) {
  __builtin_amdgcn_global_load_lds(
      (const __attribute__((address_space(1))) unsigned int*)g,
      (__attribute__((address_space(3))) unsigned int*)l, 16, 0, 0);
}

// inverse of slot-swizzle o = s ^ ((s>>2)&7)  (row = slot>>2 layouts)
__device__ __forceinline__ int inv_swz_r2(int o) {
  return o ^ (((o >> 2) & 6) | (((o >> 2) ^ (o >> 4)) & 1));
}
// inverse of slot-swizzle o = s ^ ((s>>5)&7)  (row = slot>>5; involution)
__device__ __forceinline__ int inv_swz_r5(int o) { return o ^ ((o >> 5) & 7); }

// ---------------------------------------------------------------------------
// P0: x[b][c][t] f32 -> xT hi / scaled-lo f16 [b][t][c]
// ---------------------------------------------------------------------------
__global__ __launch_bounds__(256) void split_transpose_x(
    const float* __restrict__ x, f16* __restrict__ xh, f16* __restrict__ xl) {
  __shared__ float tile[32][33];
  const int tx = threadIdx.x, ty = threadIdx.y;
  const int t0 = blockIdx.x * 32, c0 = blockIdx.y * 32, b = blockIdx.z;
#pragma unroll
  for (int k = 0; k < 4; ++k)
    tile[ty + 8 * k][tx] = x[((size_t)b * CC + c0 + ty + 8 * k) * TT + t0 + tx];
  __syncthreads();
#pragma unroll
  for (int k = 0; k < 4; ++k) {
    float v = tile[tx][ty + 8 * k];
    size_t o = ((size_t)b * TT + t0 + ty + 8 * k) * CC + c0 + tx;
    f16 h = (f16)v;
    xh[o] = h;
    xl[o] = (f16)((v - (float)h) * SC2048);
  }
}

// fused: 4x weight split (2048 blocks) + stats zeroing (block 2048).
// BUGFIX (r20->r21): block 2048 has 256 threads; zero ALL 1024 doubles via
// strided loop (r20 zeroed only [0..255] -> stats accumulated across graph
// replays -> re-validation failed).
__global__ void split_w4(const float* __restrict__ s0, f16* __restrict__ h0,
                         f16* __restrict__ l0, const float* __restrict__ s1,
                         f16* __restrict__ h1, f16* __restrict__ l1,
                         const float* __restrict__ s2, f16* __restrict__ h2,
                         f16* __restrict__ l2, const float* __restrict__ s3,
                         f16* __restrict__ h3, f16* __restrict__ l3,
                         double* __restrict__ statd) {
  const int NW = 131072;
  int bx = blockIdx.x;
  if (bx == 2048) {
    for (int k = threadIdx.x; k < 1024; k += 256) statd[k] = 0.0;
    return;
  }
  int i = bx * 256 + threadIdx.x;
  int which = i >> 17;
  int j = i & (NW - 1);
  const float* src = which == 0 ? s0 : which == 1 ? s1 : which == 2 ? s2 : s3;
  f16* h = which == 0 ? h0 : which == 1 ? h1 : which == 2 ? h2 : h3;
  f16* lo = which == 0 ? l0 : which == 1 ? l1 : which == 2 ? l2 : l3;
  float v = src[j];
  f16 a = (f16)v;
  h[j] = a;
  lo[j] = (f16)((v - (float)a) * SC2048);
}

// ---------------------------------------------------------------------------
// GEMM body (r19-verified): D = A*B^T + bias, split-f16, dbuf gload_lds,
// one barrier per K-step. 512 threads = 8 waves of 64x32 output.
// ---------------------------------------------------------------------------
template <int M, int N, int K, bool BIAS_N, bool F32OUT>
__device__ __forceinline__ void gemm_body(
    f16 (*sBuf)[4][4096], const f16* __restrict__ Ah,
    const f16* __restrict__ Al, long strideA, const f16* __restrict__ Bh,
    const f16* __restrict__ Bl, long strideB, const float* __restrict__ bias,
    f16* __restrict__ Oh, f16* __restrict__ Ol, float* __restrict__ Of,
    long strideO, double* __restrict__ osum, double* __restrict__ osumsq,
    int bxx, int byy, int bzz) {
  const int tid = threadIdx.x;
  const int w = tid >> 6, l = tid & 63;
  const int bn = bxx * 128, bm = byy * 128;
  const size_t baseA = (size_t)bzz * strideA;
  const size_t baseB = (size_t)bzz * strideB;
  const size_t baseO = (size_t)bzz * strideO;
  const int m0 = (w >> 2) * 64, n0 = (w & 3) * 32;

  auto stage = [&](int kb, int buf) {
    int base = w * 64;
    int s = inv_swz_r2(base + l);
    int row = s >> 2, ks = s & 3;
    size_t ga = baseA + (size_t)(bm + row) * K + kb + ks * 8;
    size_t gb = baseB + (size_t)(bn + row) * K + kb + ks * 8;
    ld_lds16(Ah + ga, (char*)&sBuf[buf][0][0] + base * 16);
    ld_lds16(Al + ga, (char*)&sBuf[buf][1][0] + base * 16);
    ld_lds16(Bh + gb, (char*)&sBuf[buf][2][0] + base * 16);
    ld_lds16(Bl + gb, (char*)&sBuf[buf][3][0] + base * 16);
  };

  f32x4 acc[4][2], accL[4][2];
#pragma unroll
  for (int i = 0; i < 4; ++i)
#pragma unroll
    for (int j = 0; j < 2; ++j) {
      acc[i][j] = (f32x4){0.f, 0.f, 0.f, 0.f};
      accL[i][j] = (f32x4){0.f, 0.f, 0.f, 0.f};
    }

  stage(0, 0);
  __syncthreads();
  const int nsteps = K / 32;
  for (int st = 0; st < nsteps; ++st) {
    const int cur = st & 1, nxt = cur ^ 1;
    if (st + 1 < nsteps) stage((st + 1) * 32, nxt);
    char* cAh = (char*)&sBuf[cur][0][0];
    char* cAl = (char*)&sBuf[cur][1][0];
    char* cBh = (char*)&sBuf[cur][2][0];
    char* cBl = (char*)&sBuf[cur][3][0];
    f16x8 ah[4], al[4];
#pragma unroll
    for (int mf = 0; mf < 4; ++mf) {
      int row = m0 + mf * 16 + (l & 15);
      int byte = swz(row * 64 + ((l >> 4) << 4), row);
      ah[mf] = *(const f16x8*)(cAh + byte);
      al[mf] = *(const f16x8*)(cAl + byte);
    }
#pragma unroll
    for (int nf = 0; nf < 2; ++nf) {
      int row = n0 + nf * 16 + (l & 15);
      int byte = swz(row * 64 + ((l >> 4) << 4), row);
      f16x8 bh = *(const f16x8*)(cBh + byte);
      f16x8 bl = *(const f16x8*)(cBl + byte);
#pragma unroll
      for (int mf = 0; mf < 4; ++mf)
        acc[mf][nf] = MFMA(ah[mf], bh, acc[mf][nf]);
#pragma unroll
      for (int mf = 0; mf < 4; ++mf)
        accL[mf][nf] = MFMA(al[mf], bh, accL[mf][nf]);
#pragma unroll
      for (int mf = 0; mf < 4; ++mf)
        accL[mf][nf] = MFMA(ah[mf], bl, accL[mf][nf]);
    }
    __syncthreads();
  }

  if (F32OUT) {
#pragma unroll
    for (int mf = 0; mf < 4; ++mf)
#pragma unroll
      for (int r = 0; r < 4; ++r) {
        int mrow = bm + m0 + mf * 16 + ((l >> 4) << 2) + r;
        float bv = bias[mrow];
        double s = 0.0, q = 0.0;
#pragma unroll
        for (int nf = 0; nf < 2; ++nf) {
          float v = acc[mf][nf][r] + accL[mf][nf][r] * INV2048 + bv;
          Of[baseO + (size_t)mrow * N + bn + n0 + nf * 16 + (l & 15)] = v;
          s += (double)v;
          q += (double)v * (double)v;
        }
#pragma unroll
        for (int sh = 8; sh >= 1; sh >>= 1) {
          s += __shfl_xor(s, sh);
          q += __shfl_xor(q, sh);
        }
        if ((l & 15) == 0) {
          atomicAdd(&osum[mrow], s);
          atomicAdd(&osumsq[mrow], q);
        }
      }
  } else {
    float* sOut = (float*)&sBuf[0][0][0];
    for (int c = 0; c < 4; ++c) {
      __syncthreads();
      if ((w >> 2) == (c >> 1)) {
#pragma unroll
        for (int mf2 = 0; mf2 < 2; ++mf2) {
          int mf = (c & 1) * 2 + mf2;
          int rl = mf2 * 16 + ((l >> 4) << 2);
#pragma unroll
          for (int nf = 0; nf < 2; ++nf)
#pragma unroll
            for (int r = 0; r < 4; ++r)
              sOut[(rl + r) * 132 + n0 + nf * 16 + (l & 15)] =
                  acc[mf][nf][r] + accL[mf][nf][r] * INV2048;
        }
      }
      __syncthreads();
      int row = tid >> 4, cc0 = (tid & 15) * 8;
      size_t gm = bm + c * 32 + row;
      size_t ob = baseO + gm * (size_t)N + bn + cc0;
      f16 hv[8], lv[8];
#pragma unroll
      for (int e = 0; e < 8; ++e) {
        float v = sOut[row * 132 + cc0 + e];
        v += BIAS_N ? bias[bn + cc0 + e] : bias[gm];
        f16 h = (f16)v;
        hv[e] = h;
        lv[e] = (f16)((v - (float)h) * SC2048);
      }
      *(f16x8*)&Oh[ob] = *(f16x8*)hv;
      *(f16x8*)&Ol[ob] = *(f16x8*)lv;
    }
  }
}

// standalone GEMM kernel (used for W-conv, F32OUT path)
template <int M, int N, int K, bool BIAS_N, bool F32OUT>
__global__ __launch_bounds__(512)
    __attribute__((amdgpu_waves_per_eu(2, 2))) void gemm_nt(
        const f16* __restrict__ Ah, const f16* __restrict__ Al, long strideA,
        const f16* __restrict__ Bh, const f16* __restrict__ Bl, long strideB,
        const float* __restrict__ bias, f16* __restrict__ Oh,
        f16* __restrict__ Ol, float* __restrict__ Of, long strideO,
        double* __restrict__ osum, double* __restrict__ osumsq) {
  __shared__ f16 sBuf[2][4][4096];
  gemm_body<M, N, K, BIAS_N, F32OUT>(sBuf, Ah, Al, strideA, Bh, Bl, strideB,
                                     bias, Oh, Ol, Of, strideO, osum, osumsq,
                                     blockIdx.x, blockIdx.y, blockIdx.z);
}

// fused theta/phi/g projection: grid 768 = 3 x 256 tiles, tails overlap
__global__ __launch_bounds__(512)
    __attribute__((amdgpu_waves_per_eu(2, 2))) void fused_proj(
        const f16* __restrict__ xTh, const f16* __restrict__ xTl,
        const f16* __restrict__ twH, const f16* __restrict__ twL,
        const float* __restrict__ th_b, f16* __restrict__ thH,
        f16* __restrict__ thL, const f16* __restrict__ pwH,
        const f16* __restrict__ pwL, const float* __restrict__ ph_b,
        f16* __restrict__ phH, f16* __restrict__ phL,
        const f16* __restrict__ gwH, const f16* __restrict__ gwL,
        const float* __restrict__ g_b, f16* __restrict__ gH,
        f16* __restrict__ gL) {
  __shared__ f16 sBuf[2][4][4096];
  int bx = blockIdx.x;
  if (bx < 512) {
    int which = bx >> 8, sub = bx & 255;
    int gx = sub & 1, gy = (sub >> 1) & 15, gz = sub >> 5;
    const f16* wH = which ? pwH : twH;
    const f16* wL = which ? pwL : twL;
    const float* bb = which ? ph_b : th_b;
    f16* oH = which ? phH : thH;
    f16* oL = which ? phL : thL;
    gemm_body<TT, ICC, CC, true, false>(sBuf, xTh, xTl, (long)TT * CC, wH, wL,
                                        0, bb, oH, oL, nullptr,
                                        (long)TT * ICC, nullptr, nullptr, gx,
                                        gy, gz);
  } else {
    int sub = bx - 512;
    int gx = sub & 15, gy = (sub >> 4) & 1, gz = sub >> 5;
    gemm_body<ICC, TT, CC, false, false>(sBuf, gwH, gwL, 0, xTh, xTl,
                                         (long)TT * CC, g_b, gH, gL, nullptr,
                                         (long)ICC * TT, nullptr, nullptr, gx,
                                         gy, gz);
  }
}

// ---------------------------------------------------------------------------
// Fused flash attention (r18 exact, verified 245us): j-split QK, dbuf staging,
// 3 barriers/chunk, waves_per_eu(2,2).
// ---------------------------------------------------------------------------
__global__ __launch_bounds__(512)
    __attribute__((amdgpu_waves_per_eu(2, 2))) void attn_mfma(
        const f16* __restrict__ th_h, const f16* __restrict__ th_l,
        const f16* __restrict__ ph_h, const f16* __restrict__ ph_l,
        const f16* __restrict__ g_h, const f16* __restrict__ g_l,
        f16* __restrict__ y_h, f16* __restrict__ y_l) {
  __shared__ f16 sPhiH[2][8192], sPhiL[2][8192];  // phi [buf][32 j][256 c]
  __shared__ f16 sGH[2][8192], sGL[2][8192];      // g   [buf][256 c][32 j]
  __shared__ f16 sP[2048], sPl[2048];             // P hi / scaled-lo [64][32]
  __shared__ float sPm[2][64], sPs[2][64];        // per-row partial max/sum
  __shared__ float sSc[64], sL[64];
  const int tid = threadIdx.x, w = tid >> 6, l = tid & 63;
  const int b = blockIdx.x & 7;
  const int i0 = (blockIdx.x >> 3) * 64;
  const int gj = w >> 2;        // j-half this wave computes in QK
  const int rw = (w & 3) * 16;  // QK row base

  auto stagePhi = [&](int j0, int buf) {
#pragma unroll
    for (int rep = 0; rep < 2; ++rep) {
      int base = w * 64 + rep * 512;
      int s = inv_swz_r5(base + l);
      int row = s >> 5, kq = s & 31;
      size_t ga = ((size_t)b * TT + j0 + row) * 256 + kq * 8;
      ld_lds16(ph_h + ga, (char*)&sPhiH[buf][0] + base * 16);
      ld_lds16(ph_l + ga, (char*)&sPhiL[buf][0] + base * 16);
    }
  };
  auto stageG = [&](int j0, int buf) {
#pragma unroll
    for (int rep = 0; rep < 2; ++rep) {
      int base = w * 64 + rep * 512;
      int s = inv_swz_r2(base + l);
      int row = s >> 2, kq = s & 3;
      size_t ga = ((size_t)b * 256 + row) * TT + j0 + kq * 8;
      ld_lds16(g_h + ga, (char*)&sGH[buf][0] + base * 16);
      ld_lds16(g_l + ga, (char*)&sGL[buf][0] + base * 16);
    }
  };

  const size_t tbase =
      ((size_t)b * TT + i0 + rw + (l & 15)) * 256 + ((l >> 4) << 3);
  f16x8 qh[8], ql[8];
#pragma unroll
  for (int kf = 0; kf < 8; ++kf) {
    qh[kf] = *(const f16x8*)(th_h + tbase + kf * 32);
    ql[kf] = *(const f16x8*)(th_l + tbase + kf * 32);
  }
  f32x4 yacc[4][2], yaccL[4][2];
#pragma unroll
  for (int i = 0; i < 4; ++i)
#pragma unroll
    for (int j = 0; j < 2; ++j) {
      yacc[i][j] = (f32x4){0.f, 0.f, 0.f, 0.f};
      yaccL[i][j] = (f32x4){0.f, 0.f, 0.f, 0.f};
    }
  float mrow[4], lrow[4];
#pragma unroll
  for (int r = 0; r < 4; ++r) {
    mrow[r] = -3e38f;
    lrow[r] = 0.f;
  }

  stagePhi(0, 0);
  stageG(0, 0);
  __syncthreads();

  for (int jc = 0; jc < 64; ++jc) {
    const int cur = jc & 1, nxt = cur ^ 1;
    if (jc < 63) {
      stagePhi((jc + 1) * 32, nxt);
      stageG((jc + 1) * 32, nxt);
    }
    f32x4 s4 = (f32x4){0.f, 0.f, 0.f, 0.f};
    f32x4 s4L = (f32x4){0.f, 0.f, 0.f, 0.f};
    {
      int prow = gj * 16 + (l & 15);
#pragma unroll
      for (int kf = 0; kf < 8; ++kf) {
        int byte = swz(prow * 512 + kf * 64 + ((l >> 4) << 4), prow);
        f16x8 bh = *(const f16x8*)((char*)&sPhiH[cur][0] + byte);
        f16x8 bl = *(const f16x8*)((char*)&sPhiL[cur][0] + byte);
        s4 = MFMA(qh[kf], bh, s4);
        s4L = MFMA(ql[kf], bh, s4L);
        s4L = MFMA(qh[kf], bl, s4L);
      }
    }
    float sv[4], pm[4];
#pragma unroll
    for (int r = 0; r < 4; ++r) {
      sv[r] = s4[r] + s4L[r] * INV2048;
      float mx = sv[r];
#pragma unroll
      for (int sh = 8; sh >= 1; sh >>= 1) mx = fmaxf(mx, __shfl_xor(mx, sh));
      pm[r] = mx;
    }
    if ((l & 15) == 0) {
#pragma unroll
      for (int r = 0; r < 4; ++r) sPm[gj][rw + ((l >> 4) << 2) + r] = pm[r];
    }
    __syncthreads();  // B: partial maxima visible; staged loads drained
    float scr[4];
#pragma unroll
    for (int r = 0; r < 4; ++r) {
      int row = rw + ((l >> 4) << 2) + r;
      float mx = fmaxf(sPm[0][row], sPm[1][row]);
      float mn = fmaxf(mrow[r], mx);
      scr[r] = __expf(mrow[r] - mn);
      mrow[r] = mn;
      float p = __expf(sv[r] - mn);
      float ls = p;
#pragma unroll
      for (int sh = 8; sh >= 1; sh >>= 1) ls += __shfl_xor(ls, sh);
      int jj = gj * 16 + (l & 15);
      f16 h = (f16)p;
      *(f16*)((char*)sP + swz(row * 64 + jj * 2, row)) = h;
      *(f16*)((char*)sPl + swz(row * 64 + jj * 2, row)) =
          (f16)((p - (float)h) * SC2048);
      if ((l & 15) == 0) {
        sPs[gj][row] = ls;
        if (gj == 0) sSc[row] = scr[r];
      }
    }
    __syncthreads();  // C: P + partial sums + sSc published
#pragma unroll
    for (int r = 0; r < 4; ++r) {
      int row = rw + ((l >> 4) << 2) + r;
      lrow[r] = lrow[r] * scr[r] + (sPs[0][row] + sPs[1][row]);
    }
#pragma unroll
    for (int mf = 0; mf < 4; ++mf)
#pragma unroll
      for (int r = 0; r < 4; ++r) {
        float s0 = sSc[mf * 16 + ((l >> 4) << 2) + r];
#pragma unroll
        for (int cf = 0; cf < 2; ++cf) {
          yacc[mf][cf][r] *= s0;
          yaccL[mf][cf][r] *= s0;
        }
      }
#pragma unroll
    for (int mf = 0; mf < 4; ++mf) {
      int prow = mf * 16 + (l & 15);
      int pb = swz(prow * 64 + ((l >> 4) << 4), prow);
      f16x8 pa = *(const f16x8*)((char*)sP + pb);
      f16x8 paL = *(const f16x8*)((char*)sPl + pb);
#pragma unroll
      for (int cf = 0; cf < 2; ++cf) {
        int crow = w * 32 + cf * 16 + (l & 15);
        int gb2 = swz(crow * 64 + ((l >> 4) << 4), crow);
        f16x8 gh = *(const f16x8*)((char*)&sGH[cur][0] + gb2);
        f16x8 gl = *(const f16x8*)((char*)&sGL[cur][0] + gb2);
        yacc[mf][cf] = MFMA(pa, gh, yacc[mf][cf]);
        yaccL[mf][cf] = MFMA(paL, gh, yaccL[mf][cf]);
        yaccL[mf][cf] = MFMA(pa, gl, yaccL[mf][cf]);
      }
    }
    __syncthreads();  // D: P/g reads done before next softmax/staging reuse
  }

  if (gj == 0 && (l & 15) == 0) {
#pragma unroll
    for (int r = 0; r < 4; ++r) sL[rw + ((l >> 4) << 2) + r] = lrow[r];
  }
  __syncthreads();
  float* sOutF = (float*)&sPhiH[0][0];
  for (int c2 = 0; c2 < 4; ++c2) {
#pragma unroll
    for (int r = 0; r < 4; ++r) {
      int row = c2 * 16 + ((l >> 4) << 2) + r;
      float linv = 1.f / sL[row];
      int rl = row - c2 * 16;
#pragma unroll
      for (int cf = 0; cf < 2; ++cf)
        sOutF[rl * 264 + w * 32 + cf * 16 + (l & 15)] =
            (yacc[c2][cf][r] + yaccL[c2][cf][r] * INV2048) * linv;
    }
    __syncthreads();
    int row = tid >> 5, cc0 = (tid & 31) * 8;
    size_t ob = ((size_t)b * TT + i0 + c2 * 16 + row) * 256 + cc0;
    f16 hv[8], lv[8];
#pragma unroll
    for (int e = 0; e < 8; ++e) {
      float v = sOutF[row * 264 + cc0 + e];
      f16 h = (f16)v;
      hv[e] = h;
      lv[e] = (f16)((v - (float)h) * SC2048);
    }
    *(f16x8*)&y_h[ob] = *(f16x8*)hv;
    *(f16x8*)&y_l[ob] = *(f16x8*)lv;
    __syncthreads();
  }
}

// ---------------------------------------------------------------------------
__global__ void zero_stats(double* s) { s[threadIdx.x] = 0.0; }

__global__ void bn_stats(const double* __restrict__ osum,
                         const double* __restrict__ osumsq,
                         float* __restrict__ mean, float* __restrict__ rstd) {
  int o = threadIdx.x;
  if (o < CC) {
    const double inv = 1.0 / (double)(BB * TT);
    double mu = osum[o] * inv;
    double var = osumsq[o] * inv - mu * mu;
    mean[o] = (float)mu;
    rstd[o] = (float)(1.0 / sqrt(var + (double)EPSV));
  }
}

__global__ __launch_bounds__(256) void bn_apply(
    float* __restrict__ out, const float* __restrict__ x,
    const float* __restrict__ mean, const float* __restrict__ rstd,
    const float* __restrict__ gamma, const float* __restrict__ beta) {
  const size_t n4 = (size_t)BB * CC * TT / 4;
  for (size_t idx = (size_t)blockIdx.x * blockDim.x + threadIdx.x; idx < n4;
       idx += (size_t)gridDim.x * blockDim.x) {
    size_t e = idx * 4;
    int o = (int)((e / TT) % CC);
    float4 wv = ((const float4*)out)[idx];
    float4 xv = ((const float4*)x)[idx];
    float mu = mean[o], rs = rstd[o], ga = gamma[o], be = beta[o];
    float4 r;
    r.x = fmaxf((wv.x - mu) * rs * ga + be, 0.f) + xv.x;
    r.y = fmaxf((wv.y - mu) * rs * ga + be, 0.f) + xv.y;
    r.z = fmaxf((wv.z - mu) * rs * ga + be, 0.f) + xv.z;
    r.w = fmaxf((wv.w - mu) * rs * ga + be, 0.f) + xv.w;
    ((float4*)out)[idx] = r;
  }
}

// ===========================================================================
// Fallback fp32 path (round-3, known-good) — used if ws too small.
// ===========================================================================
template <int M, int K, bool STATS>
__global__ __launch_bounds__(256) void gemm_proj(
    const float* __restrict__ W, const float* __restrict__ bias,
    const float* __restrict__ X, float* __restrict__ Out,
    double* __restrict__ osum, double* __restrict__ osumsq) {
  __shared__ float Ws[16][65];
  __shared__ float Xs[16][65];
  const int bt = blockIdx.x * 64, bm = blockIdx.y * 64, b = blockIdx.z;
  const int tid = threadIdx.x, tx = tid & 15, ty = tid >> 4;
  const float* Xb = X + (size_t)b * K * TT;
  float acc[4][4] = {};
  for (int kb = 0; kb < K; kb += 16) {
#pragma unroll
    for (int r = 0; r < 4; ++r) {
      int idx = tid + r * 256;
      int m = idx >> 4, k = idx & 15;
      Ws[k][m] = W[(size_t)(bm + m) * K + kb + k];
      int kx = idx >> 6, t = idx & 63;
      Xs[kx][t] = Xb[(size_t)(kb + kx) * TT + bt + t];
    }
    __syncthreads();
#pragma unroll
    for (int k = 0; k < 16; ++k) {
      float a[4], bv[4];
#pragma unroll
      for (int i = 0; i < 4; ++i) a[i] = Ws[k][ty * 4 + i];
#pragma unroll
      for (int j = 0; j < 4; ++j) bv[j] = Xs[k][tx * 4 + j];
#pragma unroll
      for (int i = 0; i < 4; ++i)
#pragma unroll
        for (int j = 0; j < 4; ++j) acc[i][j] += a[i] * bv[j];
    }
    __syncthreads();
  }
#pragma unroll
  for (int i = 0; i < 4; ++i) {
    int m = bm + ty * 4 + i;
    float bv = bias[m];
    double rs = 0.0, rq = 0.0;
#pragma unroll
    for (int j = 0; j < 4; ++j) {
      float v = acc[i][j] + bv;
      Out[((size_t)b * M + m) * TT + bt + tx * 4 + j] = v;
      if (STATS) {
        rs += (double)v;
        rq += (double)v * (double)v;
      }
    }
    if (STATS) {
#pragma unroll
      for (int s = 8; s >= 1; s >>= 1) {
        rs += __shfl_xor(rs, s, 16);
        rq += __shfl_xor(rq, s, 16);
      }
      if (tx == 0) {
        atomicAdd(&osum[m], rs);
        atomicAdd(&osumsq[m], rq);
      }
    }
  }
}

__global__ __launch_bounds__(256) void attn_flash(
    const float* __restrict__ th, const float* __restrict__ ph,
    const float* __restrict__ gx, float* __restrict__ y) {
  __shared__ float As[16][65];
  __shared__ float Bs[16][65];
  __shared__ float Ps[64][65];
  __shared__ float Gs[64][65];
  __shared__ float mScale[64];
  __shared__ float lArr[64];
  const int i0 = blockIdx.x * 64, b = blockIdx.y;
  const int tid = threadIdx.x, tx = tid & 15, ty = tid >> 4;
  const float* thb = th + (size_t)b * ICC * TT;
  const float* phb = ph + (size_t)b * ICC * TT;
  const float* gb = gx + (size_t)b * ICC * TT;
  float m[4], l[4];
#pragma unroll
  for (int i = 0; i < 4; ++i) {
    m[i] = -1e30f;
    l[i] = 0.f;
  }
  float acc[4][4][4] = {};
  for (int j0 = 0; j0 < TT; j0 += 64) {
    float S[4][4] = {};
    for (int cb = 0; cb < ICC; cb += 16) {
#pragma unroll
      for (int r = 0; r < 4; ++r) {
        int idx = tid + r * 256;
        int k = idx >> 6, col = idx & 63;
        As[k][col] = thb[(size_t)(cb + k) * TT + i0 + col];
        Bs[k][col] = phb[(size_t)(cb + k) * TT + j0 + col];
      }
      __syncthreads();
#pragma unroll
      for (int k = 0; k < 16; ++k) {
        float a[4], bv[4];
#pragma unroll
        for (int i = 0; i < 4; ++i) a[i] = As[k][ty * 4 + i];
#pragma unroll
        for (int j = 0; j < 4; ++j) bv[j] = Bs[k][tx * 4 + j];
#pragma unroll
        for (int i = 0; i < 4; ++i)
#pragma unroll
          for (int j = 0; j < 4; ++j) S[i][j] += a[i] * bv[j];
      }
      __syncthreads();
    }
    float sc[4];
#pragma unroll
    for (int i = 0; i < 4; ++i) {
      float mc = S[i][0];
#pragma unroll
      for (int j = 1; j < 4; ++j) mc = fmaxf(mc, S[i][j]);
#pragma unroll
      for (int s = 8; s >= 1; s >>= 1) mc = fmaxf(mc, __shfl_xor(mc, s, 16));
      float mn = fmaxf(m[i], mc);
      sc[i] = __expf(m[i] - mn);
      float lsum = 0.f;
#pragma unroll
      for (int j = 0; j < 4; ++j) {
        float p = __expf(S[i][j] - mn);
        S[i][j] = p;
        lsum += p;
      }
#pragma unroll
      for (int s = 8; s >= 1; s >>= 1) lsum += __shfl_xor(lsum, s, 16);
      l[i] = l[i] * sc[i] + lsum;
      m[i] = mn;
#pragma unroll
      for (int j = 0; j < 4; ++j) Ps[ty * 4 + i][tx * 4 + j] = S[i][j];
    }
    if (tx == 0) {
#pragma unroll
      for (int i = 0; i < 4; ++i) mScale[ty * 4 + i] = sc[i];
    }
    __syncthreads();
#pragma unroll
    for (int cq = 0; cq < 4; ++cq) {
#pragma unroll
      for (int r = 0; r < 16; ++r) {
        int idx = tid + r * 256;
        int cpr = idx >> 6, j = idx & 63;
        Gs[cpr][j] = gb[(size_t)(cq * 64 + cpr) * TT + j0 + j];
      }
      __syncthreads();
      float scj[4];
#pragma unroll
      for (int jq = 0; jq < 4; ++jq) scj[jq] = mScale[tx * 4 + jq];
#pragma unroll
      for (int ci = 0; ci < 4; ++ci)
#pragma unroll
        for (int jq = 0; jq < 4; ++jq) acc[cq][ci][jq] *= scj[jq];
      for (int j = 0; j < 64; ++j) {
        float a[4], p[4];
#pragma unroll
        for (int ci = 0; ci < 4; ++ci) a[ci] = Gs[ty * 4 + ci][j];
#pragma unroll
        for (int jq = 0; jq < 4; ++jq) p[jq] = Ps[tx * 4 + jq][j];
#pragma unroll
        for (int ci = 0; ci < 4; ++ci)
#pragma unroll
          for (int jq = 0; jq < 4; ++jq) acc[cq][ci][jq] += a[ci] * p[jq];
      }
      __syncthreads();
    }
  }
  if (tx == 0) {
#pragma unroll
    for (int i = 0; i < 4; ++i) lArr[ty * 4 + i] = l[i];
  }
  __syncthreads();
  float linv[4];
#pragma unroll
  for (int jq = 0; jq < 4; ++jq) linv[jq] = 1.f / lArr[tx * 4 + jq];
#pragma unroll
  for (int cq = 0; cq < 4; ++cq)
#pragma unroll
    for (int ci = 0; ci < 4; ++ci)
#pragma unroll
      for (int jq = 0; jq < 4; ++jq)
        y[((size_t)b * ICC + cq * 64 + ty * 4 + ci) * TT + i0 + tx * 4 + jq] =
            acc[cq][ci][jq] * linv[jq];
}

// ---------------------------------------------------------------------------
extern "C" void kernel_launch(void* const* d_in, const int* in_sizes, int n_in,
                              void* d_out, int out_size, void* d_ws,
                              size_t ws_size, hipStream_t stream) {
  const float* x = (const float*)d_in[0];
  const float* g_w = (const float*)d_in[1];
  const float* g_b = (const float*)d_in[2];
  const float* th_w = (const float*)d_in[3];
  const float* th_b = (const float*)d_in[4];
  const float* ph_w = (const float*)d_in[5];
  const float* ph_b = (const float*)d_in[6];
  const float* W_w = (const float*)d_in[7];
  const float* W_b = (const float*)d_in[8];
  const float* gamma = (const float*)d_in[9];
  const float* beta = (const float*)d_in[10];
  float* out = (float*)d_out;
  dim3 blk(256);

  const size_t NP = (size_t)BB * TT * ICC;  // 4,194,304
  const size_t NW = 131072;                 // 256*512
  const size_t need = (8 * NP + 8 * NW) * sizeof(f16) + 8192 + 4096;

  if (ws_size >= need) {
    // ---------------- fast MFMA path ----------------
    f16* p = (f16*)d_ws;
    f16 *thH = p, *thL = thH + NP, *phH = thL + NP, *phL = phH + NP;
    f16 *gH = phL + NP, *gL = gH + NP, *yH = gL + NP, *yL = yH + NP;
    f16* wp = yL + NP;
    f16 *gwH = wp, *gwL = gwH + NW, *twH = gwL + NW, *twL = twH + NW;
    f16 *pwH = twL + NW, *pwL = pwH + NW, *wwH = pwL + NW, *wwL = wwH + NW;
    double* statd = (double*)(wwL + NW);
    float* meanb = (float*)(statd + 1024);
    float* rstdb = meanb + 512;
    f16* xTh = (f16*)d_out;  // xT hi/lo lives in d_out (dead before W-conv)
    f16* xTl = xTh + (size_t)BB * TT * CC;

    split_transpose_x<<<dim3(TT / 32, CC / 32, BB), dim3(32, 8), 0, stream>>>(
        x, xTh, xTl);
    // fused 4x weight split + full stats zeroing (replay-safe)
    split_w4<<<2049, 256, 0, stream>>>(g_w, gwH, gwL, th_w, twH, twL, ph_w,
                                       pwH, pwL, W_w, wwH, wwL, statd);
    // fused theta/phi/g projections (768 blocks, tails overlap)
    fused_proj<<<768, dim3(512), 0, stream>>>(xTh, xTl, twH, twL, th_b, thH,
                                              thL, pwH, pwL, ph_b, phH, phL,
                                              gwH, gwL, g_b, gH, gL);
    // attention -> y f16 hi/lo directly (r18 exact)
    attn_mfma<<<256, dim3(512), 0, stream>>>(thH, thL, phH, phL, gH, gL, yH,
                                             yL);
    // W conv: D[o][t] -> d_out + BN stats  (M=C, N=T, K=IC, bias on M)
    gemm_nt<CC, TT, ICC, false, true><<<dim3(16, 4, BB), dim3(512), 0,
                                        stream>>>(
        wwH, wwL, 0, yH, yL, (long)TT * ICC, W_b, nullptr, nullptr, out,
        (long)CC * TT, statd, statd + CC);
    bn_stats<<<1, 512, 0, stream>>>(statd, statd + CC, meanb, rstdb);
    bn_apply<<<2048, 256, 0, stream>>>(out, x, meanb, rstdb, gamma, beta);
  } else {
    // ---------------- fallback fp32 path ----------------
    float* ws = (float*)d_ws;
    const size_t np = (size_t)BB * ICC * TT;
    float* thb = ws;
    float* phb = ws + np;
    float* gbuf = ws + 2 * np;
    float* yb = thb;
    double* statd = (double*)(ws + 3 * np);
    float* meanb = (float*)(statd + 1024);
    float* rstdb = meanb + 512;
    gemm_proj<ICC, CC, false><<<dim3(TT / 64, ICC / 64, BB), blk, 0, stream>>>(
        th_w, th_b, x, thb, nullptr, nullptr);
    gemm_proj<ICC, CC, false><<<dim3(TT / 64, ICC / 64, BB), blk, 0, stream>>>(
        ph_w, ph_b, x, phb, nullptr, nullptr);
    gemm_proj<ICC, CC, false><<<dim3(TT / 64, ICC / 64, BB), blk, 0, stream>>>(
        g_w, g_b, x, gbuf, nullptr, nullptr);
    attn_flash<<<dim3(TT / 64, BB), blk, 0, stream>>>(thb, phb, gbuf, yb);
    zero_stats<<<1, 1024, 0, stream>>>(statd);
    gemm_proj<CC, ICC, true><<<dim3(TT / 64, CC / 64, BB), blk, 0, stream>>>(
        W_w, W_b, yb, out, statd, statd + CC);
    bn_stats<<<1, 512, 0, stream>>>(statd, statd + CC, meanb, rstdb);
    bn_apply<<<2048, 256, 0, stream>>>(out, x, meanb, rstdb, gamma, beta);
  }
}

// Round 22
// 403.036 us; speedup vs baseline: 1.2035x; 1.0176x over previous
//
#include <hip/hip_runtime.h>
#include <math.h>

#define BB 8
#define CC 512
#define TT 2048
#define ICC 256
#define EPSV 1e-5f
#define SC2048 2048.0f
#define INV2048 4.8828125e-4f

typedef _Float16 f16;
typedef __attribute__((ext_vector_type(8))) _Float16 f16x8;
typedef __attribute__((ext_vector_type(4))) float f32x4;

#define MFMA(a, b, c) __builtin_amdgcn_mfma_f32_16x16x32_f16(a, b, c, 0, 0, 0)

__device__ __forceinline__ int swz(int byte, int row) {
  return byte ^ ((row & 7) << 4);
}

// global -> LDS direct (16B/lane). LDS dest = wave-uniform base + lane*16.
__device__ __forceinline__ void ld_lds16(const void* g, void* l) {
  __builtin_amdgcn_global_load_lds(
      (const __attribute__((address_space(1))) unsigned int*)g,
      (__attribute__((address_space(3))) unsigned int*)l, 16, 0, 0);
}

// inverse of slot-swizzle o = s ^ ((s>>2)&7)  (row = slot>>2 layouts)
__device__ __forceinline__ int inv_swz_r2(int o) {
  return o ^ (((o >> 2) & 6) | (((o >> 2) ^ (o >> 4)) & 1));
}
// inverse of slot-swizzle o = s ^ ((s>>5)&7)  (row = slot>>5; involution)
__device__ __forceinline__ int inv_swz_r5(int o) { return o ^ ((o >> 5) & 7); }

// ---------------------------------------------------------------------------
// P0: x[b][c][t] f32 -> xT hi / scaled-lo f16 [b][t][c]
// ---------------------------------------------------------------------------
__global__ __launch_bounds__(256) void split_transpose_x(
    const float* __restrict__ x, f16* __restrict__ xh, f16* __restrict__ xl) {
  __shared__ float tile[32][33];
  const int tx = threadIdx.x, ty = threadIdx.y;
  const int t0 = blockIdx.x * 32, c0 = blockIdx.y * 32, b = blockIdx.z;
#pragma unroll
  for (int k = 0; k < 4; ++k)
    tile[ty + 8 * k][tx] = x[((size_t)b * CC + c0 + ty + 8 * k) * TT + t0 + tx];
  __syncthreads();
#pragma unroll
  for (int k = 0; k < 4; ++k) {
    float v = tile[tx][ty + 8 * k];
    size_t o = ((size_t)b * TT + t0 + ty + 8 * k) * CC + c0 + tx;
    f16 h = (f16)v;
    xh[o] = h;
    xl[o] = (f16)((v - (float)h) * SC2048);
  }
}

// fused: 4x weight split (2048 blocks) + stats zeroing (block 2048, strided)
__global__ void split_w4(const float* __restrict__ s0, f16* __restrict__ h0,
                         f16* __restrict__ l0, const float* __restrict__ s1,
                         f16* __restrict__ h1, f16* __restrict__ l1,
                         const float* __restrict__ s2, f16* __restrict__ h2,
                         f16* __restrict__ l2, const float* __restrict__ s3,
                         f16* __restrict__ h3, f16* __restrict__ l3,
                         double* __restrict__ statd) {
  const int NW = 131072;
  int bx = blockIdx.x;
  if (bx == 2048) {
    for (int k = threadIdx.x; k < 1024; k += 256) statd[k] = 0.0;
    return;
  }
  int i = bx * 256 + threadIdx.x;
  int which = i >> 17;
  int j = i & (NW - 1);
  const float* src = which == 0 ? s0 : which == 1 ? s1 : which == 2 ? s2 : s3;
  f16* h = which == 0 ? h0 : which == 1 ? h1 : which == 2 ? h2 : h3;
  f16* lo = which == 0 ? l0 : which == 1 ? l1 : which == 2 ? l2 : l3;
  float v = src[j];
  f16 a = (f16)v;
  h[j] = a;
  lo[j] = (f16)((v - (float)a) * SC2048);
}

// ---------------------------------------------------------------------------
// GEMM body (r19-verified): D = A*B^T + bias, split-f16, dbuf gload_lds,
// one barrier per K-step. 512 threads = 8 waves of 64x32 output.
// ---------------------------------------------------------------------------
template <int M, int N, int K, bool BIAS_N, bool F32OUT>
__device__ __forceinline__ void gemm_body(
    f16 (*sBuf)[4][4096], const f16* __restrict__ Ah,
    const f16* __restrict__ Al, long strideA, const f16* __restrict__ Bh,
    const f16* __restrict__ Bl, long strideB, const float* __restrict__ bias,
    f16* __restrict__ Oh, f16* __restrict__ Ol, float* __restrict__ Of,
    long strideO, double* __restrict__ osum, double* __restrict__ osumsq,
    int bxx, int byy, int bzz) {
  const int tid = threadIdx.x;
  const int w = tid >> 6, l = tid & 63;
  const int bn = bxx * 128, bm = byy * 128;
  const size_t baseA = (size_t)bzz * strideA;
  const size_t baseB = (size_t)bzz * strideB;
  const size_t baseO = (size_t)bzz * strideO;
  const int m0 = (w >> 2) * 64, n0 = (w & 3) * 32;

  auto stage = [&](int kb, int buf) {
    int base = w * 64;
    int s = inv_swz_r2(base + l);
    int row = s >> 2, ks = s & 3;
    size_t ga = baseA + (size_t)(bm + row) * K + kb + ks * 8;
    size_t gb = baseB + (size_t)(bn + row) * K + kb + ks * 8;
    ld_lds16(Ah + ga, (char*)&sBuf[buf][0][0] + base * 16);
    ld_lds16(Al + ga, (char*)&sBuf[buf][1][0] + base * 16);
    ld_lds16(Bh + gb, (char*)&sBuf[buf][2][0] + base * 16);
    ld_lds16(Bl + gb, (char*)&sBuf[buf][3][0] + base * 16);
  };

  f32x4 acc[4][2], accL[4][2];
#pragma unroll
  for (int i = 0; i < 4; ++i)
#pragma unroll
    for (int j = 0; j < 2; ++j) {
      acc[i][j] = (f32x4){0.f, 0.f, 0.f, 0.f};
      accL[i][j] = (f32x4){0.f, 0.f, 0.f, 0.f};
    }

  stage(0, 0);
  __syncthreads();
  const int nsteps = K / 32;
  for (int st = 0; st < nsteps; ++st) {
    const int cur = st & 1, nxt = cur ^ 1;
    if (st + 1 < nsteps) stage((st + 1) * 32, nxt);
    char* cAh = (char*)&sBuf[cur][0][0];
    char* cAl = (char*)&sBuf[cur][1][0];
    char* cBh = (char*)&sBuf[cur][2][0];
    char* cBl = (char*)&sBuf[cur][3][0];
    f16x8 ah[4], al[4];
#pragma unroll
    for (int mf = 0; mf < 4; ++mf) {
      int row = m0 + mf * 16 + (l & 15);
      int byte = swz(row * 64 + ((l >> 4) << 4), row);
      ah[mf] = *(const f16x8*)(cAh + byte);
      al[mf] = *(const f16x8*)(cAl + byte);
    }
#pragma unroll
    for (int nf = 0; nf < 2; ++nf) {
      int row = n0 + nf * 16 + (l & 15);
      int byte = swz(row * 64 + ((l >> 4) << 4), row);
      f16x8 bh = *(const f16x8*)(cBh + byte);
      f16x8 bl = *(const f16x8*)(cBl + byte);
#pragma unroll
      for (int mf = 0; mf < 4; ++mf)
        acc[mf][nf] = MFMA(ah[mf], bh, acc[mf][nf]);
#pragma unroll
      for (int mf = 0; mf < 4; ++mf)
        accL[mf][nf] = MFMA(al[mf], bh, accL[mf][nf]);
#pragma unroll
      for (int mf = 0; mf < 4; ++mf)
        accL[mf][nf] = MFMA(ah[mf], bl, accL[mf][nf]);
    }
    __syncthreads();
  }

  if (F32OUT) {
#pragma unroll
    for (int mf = 0; mf < 4; ++mf)
#pragma unroll
      for (int r = 0; r < 4; ++r) {
        int mrow = bm + m0 + mf * 16 + ((l >> 4) << 2) + r;
        float bv = bias[mrow];
        double s = 0.0, q = 0.0;
#pragma unroll
        for (int nf = 0; nf < 2; ++nf) {
          float v = acc[mf][nf][r] + accL[mf][nf][r] * INV2048 + bv;
          Of[baseO + (size_t)mrow * N + bn + n0 + nf * 16 + (l & 15)] = v;
          s += (double)v;
          q += (double)v * (double)v;
        }
#pragma unroll
        for (int sh = 8; sh >= 1; sh >>= 1) {
          s += __shfl_xor(s, sh);
          q += __shfl_xor(q, sh);
        }
        if ((l & 15) == 0) {
          atomicAdd(&osum[mrow], s);
          atomicAdd(&osumsq[mrow], q);
        }
      }
  } else {
    float* sOut = (float*)&sBuf[0][0][0];
    for (int c = 0; c < 4; ++c) {
      __syncthreads();
      if ((w >> 2) == (c >> 1)) {
#pragma unroll
        for (int mf2 = 0; mf2 < 2; ++mf2) {
          int mf = (c & 1) * 2 + mf2;
          int rl = mf2 * 16 + ((l >> 4) << 2);
#pragma unroll
          for (int nf = 0; nf < 2; ++nf)
#pragma unroll
            for (int r = 0; r < 4; ++r)
              sOut[(rl + r) * 132 + n0 + nf * 16 + (l & 15)] =
                  acc[mf][nf][r] + accL[mf][nf][r] * INV2048;
        }
      }
      __syncthreads();
      int row = tid >> 4, cc0 = (tid & 15) * 8;
      size_t gm = bm + c * 32 + row;
      size_t ob = baseO + gm * (size_t)N + bn + cc0;
      f16 hv[8], lv[8];
#pragma unroll
      for (int e = 0; e < 8; ++e) {
        float v = sOut[row * 132 + cc0 + e];
        v += BIAS_N ? bias[bn + cc0 + e] : bias[gm];
        f16 h = (f16)v;
        hv[e] = h;
        lv[e] = (f16)((v - (float)h) * SC2048);
      }
      *(f16x8*)&Oh[ob] = *(f16x8*)hv;
      *(f16x8*)&Ol[ob] = *(f16x8*)lv;
    }
  }
}

// standalone GEMM kernel (used for W-conv, F32OUT path)
template <int M, int N, int K, bool BIAS_N, bool F32OUT>
__global__ __launch_bounds__(512)
    __attribute__((amdgpu_waves_per_eu(2, 2))) void gemm_nt(
        const f16* __restrict__ Ah, const f16* __restrict__ Al, long strideA,
        const f16* __restrict__ Bh, const f16* __restrict__ Bl, long strideB,
        const float* __restrict__ bias, f16* __restrict__ Oh,
        f16* __restrict__ Ol, float* __restrict__ Of, long strideO,
        double* __restrict__ osum, double* __restrict__ osumsq) {
  __shared__ f16 sBuf[2][4][4096];
  gemm_body<M, N, K, BIAS_N, F32OUT>(sBuf, Ah, Al, strideA, Bh, Bl, strideB,
                                     bias, Oh, Ol, Of, strideO, osum, osumsq,
                                     blockIdx.x, blockIdx.y, blockIdx.z);
}

// ---------------------------------------------------------------------------
// fused projections v2 (r22): blocks 0..255 compute BOTH theta and phi for
// their (t,ic) tile sharing one xT staging (A traffic + A LDS reads halved);
// blocks 256..511 compute g (r21 mapping). 96KB LDS, 1 block/CU.
// ---------------------------------------------------------------------------
__global__ __launch_bounds__(512)
    __attribute__((amdgpu_waves_per_eu(2, 2))) void fused_proj(
        const f16* __restrict__ xTh, const f16* __restrict__ xTl,
        const f16* __restrict__ twH, const f16* __restrict__ twL,
        const float* __restrict__ th_b, f16* __restrict__ thH,
        f16* __restrict__ thL, const f16* __restrict__ pwH,
        const f16* __restrict__ pwL, const float* __restrict__ ph_b,
        f16* __restrict__ phH, f16* __restrict__ phL,
        const f16* __restrict__ gwH, const f16* __restrict__ gwL,
        const float* __restrict__ g_b, f16* __restrict__ gH,
        f16* __restrict__ gL) {
  __shared__ f16 sMem[2][6][4096];  // merged: A hi/lo, tw hi/lo, pw hi/lo
  int bx = blockIdx.x;
  if (bx < 256) {
    // ---- merged theta+phi tile: gx N/128 (2), gy M/128 (16), gz batch (8)
    int gx = bx & 1, gy = (bx >> 1) & 15, gz = bx >> 5;
    const int tid = threadIdx.x, w = tid >> 6, l = tid & 63;
    const int bn = gx * 128, bm = gy * 128;
    const size_t baseA = (size_t)gz * ((size_t)TT * CC);
    const size_t baseO = (size_t)gz * ((size_t)TT * ICC);
    const int m0 = (w >> 2) * 64, n0 = (w & 3) * 32;

    auto stage = [&](int kb, int buf) {
      int base = w * 64;
      int s = inv_swz_r2(base + l);
      int row = s >> 2, ks = s & 3;
      size_t ga = baseA + (size_t)(bm + row) * CC + kb + ks * 8;
      size_t gb = (size_t)(bn + row) * CC + kb + ks * 8;
      ld_lds16(xTh + ga, (char*)&sMem[buf][0][0] + base * 16);
      ld_lds16(xTl + ga, (char*)&sMem[buf][1][0] + base * 16);
      ld_lds16(twH + gb, (char*)&sMem[buf][2][0] + base * 16);
      ld_lds16(twL + gb, (char*)&sMem[buf][3][0] + base * 16);
      ld_lds16(pwH + gb, (char*)&sMem[buf][4][0] + base * 16);
      ld_lds16(pwL + gb, (char*)&sMem[buf][5][0] + base * 16);
    };

    f32x4 a1[4][2], a1L[4][2], a2[4][2], a2L[4][2];
#pragma unroll
    for (int i = 0; i < 4; ++i)
#pragma unroll
      for (int j = 0; j < 2; ++j) {
        a1[i][j] = (f32x4){0.f, 0.f, 0.f, 0.f};
        a1L[i][j] = (f32x4){0.f, 0.f, 0.f, 0.f};
        a2[i][j] = (f32x4){0.f, 0.f, 0.f, 0.f};
        a2L[i][j] = (f32x4){0.f, 0.f, 0.f, 0.f};
      }

    stage(0, 0);
    __syncthreads();
    for (int st = 0; st < 16; ++st) {
      const int cur = st & 1, nxt = cur ^ 1;
      if (st + 1 < 16) stage((st + 1) * 32, nxt);
      char* cAh = (char*)&sMem[cur][0][0];
      char* cAl = (char*)&sMem[cur][1][0];
      char* cB1h = (char*)&sMem[cur][2][0];
      char* cB1l = (char*)&sMem[cur][3][0];
      char* cB2h = (char*)&sMem[cur][4][0];
      char* cB2l = (char*)&sMem[cur][5][0];
      f16x8 ah[4], al[4];
#pragma unroll
      for (int mf = 0; mf < 4; ++mf) {
        int row = m0 + mf * 16 + (l & 15);
        int byte = swz(row * 64 + ((l >> 4) << 4), row);
        ah[mf] = *(const f16x8*)(cAh + byte);
        al[mf] = *(const f16x8*)(cAl + byte);
      }
#pragma unroll
      for (int nf = 0; nf < 2; ++nf) {
        int row = n0 + nf * 16 + (l & 15);
        int byte = swz(row * 64 + ((l >> 4) << 4), row);
        f16x8 b1h = *(const f16x8*)(cB1h + byte);
        f16x8 b1l = *(const f16x8*)(cB1l + byte);
        f16x8 b2h = *(const f16x8*)(cB2h + byte);
        f16x8 b2l = *(const f16x8*)(cB2l + byte);
#pragma unroll
        for (int mf = 0; mf < 4; ++mf)
          a1[mf][nf] = MFMA(ah[mf], b1h, a1[mf][nf]);
#pragma unroll
        for (int mf = 0; mf < 4; ++mf)
          a1L[mf][nf] = MFMA(al[mf], b1h, a1L[mf][nf]);
#pragma unroll
        for (int mf = 0; mf < 4; ++mf)
          a1L[mf][nf] = MFMA(ah[mf], b1l, a1L[mf][nf]);
#pragma unroll
        for (int mf = 0; mf < 4; ++mf)
          a2[mf][nf] = MFMA(ah[mf], b2h, a2[mf][nf]);
#pragma unroll
        for (int mf = 0; mf < 4; ++mf)
          a2L[mf][nf] = MFMA(al[mf], b2h, a2L[mf][nf]);
#pragma unroll
        for (int mf = 0; mf < 4; ++mf)
          a2L[mf][nf] = MFMA(ah[mf], b2l, a2L[mf][nf]);
      }
      __syncthreads();
    }

    // epilogue (f16 hi/lo out), run twice: theta then phi
    float* sOut = (float*)&sMem[0][0][0];
    auto epi = [&](f32x4(*A)[2], f32x4(*AL)[2], const float* bias,
                   f16* Oh, f16* Ol) {
      for (int c = 0; c < 4; ++c) {
        __syncthreads();
        if ((w >> 2) == (c >> 1)) {
#pragma unroll
          for (int mf2 = 0; mf2 < 2; ++mf2) {
            int mf = (c & 1) * 2 + mf2;
            int rl = mf2 * 16 + ((l >> 4) << 2);
#pragma unroll
            for (int nf = 0; nf < 2; ++nf)
#pragma unroll
              for (int r = 0; r < 4; ++r)
                sOut[(rl + r) * 132 + n0 + nf * 16 + (l & 15)] =
                    A[mf][nf][r] + AL[mf][nf][r] * INV2048;
          }
        }
        __syncthreads();
        int row = tid >> 4, cc0 = (tid & 15) * 8;
        size_t gm = bm + c * 32 + row;
        size_t ob = baseO + gm * (size_t)ICC + bn + cc0;
        f16 hv[8], lv[8];
#pragma unroll
        for (int e = 0; e < 8; ++e) {
          float v = sOut[row * 132 + cc0 + e] + bias[bn + cc0 + e];
          f16 h = (f16)v;
          hv[e] = h;
          lv[e] = (f16)((v - (float)h) * SC2048);
        }
        *(f16x8*)&Oh[ob] = *(f16x8*)hv;
        *(f16x8*)&Ol[ob] = *(f16x8*)lv;
      }
    };
    epi(a1, a1L, th_b, thH, thL);
    epi(a2, a2L, ph_b, phH, phL);
  } else {
    // ---- g: D[ic][t] = Wg * xT^T  (r21-verified mapping)
    int sub = bx - 256;
    int gx = sub & 15, gy = (sub >> 4) & 1, gz = sub >> 5;
    f16(*sBuf)[4][4096] = reinterpret_cast<f16(*)[4][4096]>(&sMem[0][0][0]);
    gemm_body<ICC, TT, CC, false, false>(sBuf, gwH, gwL, 0, xTh, xTl,
                                         (long)TT * CC, g_b, gH, gL, nullptr,
                                         (long)ICC * TT, nullptr, nullptr, gx,
                                         gy, gz);
  }
}

// ---------------------------------------------------------------------------
// Fused flash attention (r18 exact, verified 245us): j-split QK, dbuf staging,
// 3 barriers/chunk, waves_per_eu(2,2).
// ---------------------------------------------------------------------------
__global__ __launch_bounds__(512)
    __attribute__((amdgpu_waves_per_eu(2, 2))) void attn_mfma(
        const f16* __restrict__ th_h, const f16* __restrict__ th_l,
        const f16* __restrict__ ph_h, const f16* __restrict__ ph_l,
        const f16* __restrict__ g_h, const f16* __restrict__ g_l,
        f16* __restrict__ y_h, f16* __restrict__ y_l) {
  __shared__ f16 sPhiH[2][8192], sPhiL[2][8192];  // phi [buf][32 j][256 c]
  __shared__ f16 sGH[2][8192], sGL[2][8192];      // g   [buf][256 c][32 j]
  __shared__ f16 sP[2048], sPl[2048];             // P hi / scaled-lo [64][32]
  __shared__ float sPm[2][64], sPs[2][64];        // per-row partial max/sum
  __shared__ float sSc[64], sL[64];
  const int tid = threadIdx.x, w = tid >> 6, l = tid & 63;
  const int b = blockIdx.x & 7;
  const int i0 = (blockIdx.x >> 3) * 64;
  const int gj = w >> 2;        // j-half this wave computes in QK
  const int rw = (w & 3) * 16;  // QK row base

  auto stagePhi = [&](int j0, int buf) {
#pragma unroll
    for (int rep = 0; rep < 2; ++rep) {
      int base = w * 64 + rep * 512;
      int s = inv_swz_r5(base + l);
      int row = s >> 5, kq = s & 31;
      size_t ga = ((size_t)b * TT + j0 + row) * 256 + kq * 8;
      ld_lds16(ph_h + ga, (char*)&sPhiH[buf][0] + base * 16);
      ld_lds16(ph_l + ga, (char*)&sPhiL[buf][0] + base * 16);
    }
  };
  auto stageG = [&](int j0, int buf) {
#pragma unroll
    for (int rep = 0; rep < 2; ++rep) {
      int base = w * 64 + rep * 512;
      int s = inv_swz_r2(base + l);
      int row = s >> 2, kq = s & 3;
      size_t ga = ((size_t)b * 256 + row) * TT + j0 + kq * 8;
      ld_lds16(g_h + ga, (char*)&sGH[buf][0] + base * 16);
      ld_lds16(g_l + ga, (char*)&sGL[buf][0] + base * 16);
    }
  };

  const size_t tbase =
      ((size_t)b * TT + i0 + rw + (l & 15)) * 256 + ((l >> 4) << 3);
  f16x8 qh[8], ql[8];
#pragma unroll
  for (int kf = 0; kf < 8; ++kf) {
    qh[kf] = *(const f16x8*)(th_h + tbase + kf * 32);
    ql[kf] = *(const f16x8*)(th_l + tbase + kf * 32);
  }
  f32x4 yacc[4][2], yaccL[4][2];
#pragma unroll
  for (int i = 0; i < 4; ++i)
#pragma unroll
    for (int j = 0; j < 2; ++j) {
      yacc[i][j] = (f32x4){0.f, 0.f, 0.f, 0.f};
      yaccL[i][j] = (f32x4){0.f, 0.f, 0.f, 0.f};
    }
  float mrow[4], lrow[4];
#pragma unroll
  for (int r = 0; r < 4; ++r) {
    mrow[r] = -3e38f;
    lrow[r] = 0.f;
  }

  stagePhi(0, 0);
  stageG(0, 0);
  __syncthreads();

  for (int jc = 0; jc < 64; ++jc) {
    const int cur = jc & 1, nxt = cur ^ 1;
    if (jc < 63) {
      stagePhi((jc + 1) * 32, nxt);
      stageG((jc + 1) * 32, nxt);
    }
    f32x4 s4 = (f32x4){0.f, 0.f, 0.f, 0.f};
    f32x4 s4L = (f32x4){0.f, 0.f, 0.f, 0.f};
    {
      int prow = gj * 16 + (l & 15);
#pragma unroll
      for (int kf = 0; kf < 8; ++kf) {
        int byte = swz(prow * 512 + kf * 64 + ((l >> 4) << 4), prow);
        f16x8 bh = *(const f16x8*)((char*)&sPhiH[cur][0] + byte);
        f16x8 bl = *(const f16x8*)((char*)&sPhiL[cur][0] + byte);
        s4 = MFMA(qh[kf], bh, s4);
        s4L = MFMA(ql[kf], bh, s4L);
        s4L = MFMA(qh[kf], bl, s4L);
      }
    }
    float sv[4], pm[4];
#pragma unroll
    for (int r = 0; r < 4; ++r) {
      sv[r] = s4[r] + s4L[r] * INV2048;
      float mx = sv[r];
#pragma unroll
      for (int sh = 8; sh >= 1; sh >>= 1) mx = fmaxf(mx, __shfl_xor(mx, sh));
      pm[r] = mx;
    }
    if ((l & 15) == 0) {
#pragma unroll
      for (int r = 0; r < 4; ++r) sPm[gj][rw + ((l >> 4) << 2) + r] = pm[r];
    }
    __syncthreads();  // B: partial maxima visible; staged loads drained
    float scr[4];
#pragma unroll
    for (int r = 0; r < 4; ++r) {
      int row = rw + ((l >> 4) << 2) + r;
      float mx = fmaxf(sPm[0][row], sPm[1][row]);
      float mn = fmaxf(mrow[r], mx);
      scr[r] = __expf(mrow[r] - mn);
      mrow[r] = mn;
      float p = __expf(sv[r] - mn);
      float ls = p;
#pragma unroll
      for (int sh = 8; sh >= 1; sh >>= 1) ls += __shfl_xor(ls, sh);
      int jj = gj * 16 + (l & 15);
      f16 h = (f16)p;
      *(f16*)((char*)sP + swz(row * 64 + jj * 2, row)) = h;
      *(f16*)((char*)sPl + swz(row * 64 + jj * 2, row)) =
          (f16)((p - (float)h) * SC2048);
      if ((l & 15) == 0) {
        sPs[gj][row] = ls;
        if (gj == 0) sSc[row] = scr[r];
      }
    }
    __syncthreads();  // C: P + partial sums + sSc published
#pragma unroll
    for (int r = 0; r < 4; ++r) {
      int row = rw + ((l >> 4) << 2) + r;
      lrow[r] = lrow[r] * scr[r] + (sPs[0][row] + sPs[1][row]);
    }
#pragma unroll
    for (int mf = 0; mf < 4; ++mf)
#pragma unroll
      for (int r = 0; r < 4; ++r) {
        float s0 = sSc[mf * 16 + ((l >> 4) << 2) + r];
#pragma unroll
        for (int cf = 0; cf < 2; ++cf) {
          yacc[mf][cf][r] *= s0;
          yaccL[mf][cf][r] *= s0;
        }
      }
#pragma unroll
    for (int mf = 0; mf < 4; ++mf) {
      int prow = mf * 16 + (l & 15);
      int pb = swz(prow * 64 + ((l >> 4) << 4), prow);
      f16x8 pa = *(const f16x8*)((char*)sP + pb);
      f16x8 paL = *(const f16x8*)((char*)sPl + pb);
#pragma unroll
      for (int cf = 0; cf < 2; ++cf) {
        int crow = w * 32 + cf * 16 + (l & 15);
        int gb2 = swz(crow * 64 + ((l >> 4) << 4), crow);
        f16x8 gh = *(const f16x8*)((char*)&sGH[cur][0] + gb2);
        f16x8 gl = *(const f16x8*)((char*)&sGL[cur][0] + gb2);
        yacc[mf][cf] = MFMA(pa, gh, yacc[mf][cf]);
        yaccL[mf][cf] = MFMA(paL, gh, yaccL[mf][cf]);
        yaccL[mf][cf] = MFMA(pa, gl, yaccL[mf][cf]);
      }
    }
    __syncthreads();  // D: P/g reads done before next softmax/staging reuse
  }

  if (gj == 0 && (l & 15) == 0) {
#pragma unroll
    for (int r = 0; r < 4; ++r) sL[rw + ((l >> 4) << 2) + r] = lrow[r];
  }
  __syncthreads();
  float* sOutF = (float*)&sPhiH[0][0];
  for (int c2 = 0; c2 < 4; ++c2) {
#pragma unroll
    for (int r = 0; r < 4; ++r) {
      int row = c2 * 16 + ((l >> 4) << 2) + r;
      float linv = 1.f / sL[row];
      int rl = row - c2 * 16;
#pragma unroll
      for (int cf = 0; cf < 2; ++cf)
        sOutF[rl * 264 + w * 32 + cf * 16 + (l & 15)] =
            (yacc[c2][cf][r] + yaccL[c2][cf][r] * INV2048) * linv;
    }
    __syncthreads();
    int row = tid >> 5, cc0 = (tid & 31) * 8;
    size_t ob = ((size_t)b * TT + i0 + c2 * 16 + row) * 256 + cc0;
    f16 hv[8], lv[8];
#pragma unroll
    for (int e = 0; e < 8; ++e) {
      float v = sOutF[row * 264 + cc0 + e];
      f16 h = (f16)v;
      hv[e] = h;
      lv[e] = (f16)((v - (float)h) * SC2048);
    }
    *(f16x8*)&y_h[ob] = *(f16x8*)hv;
    *(f16x8*)&y_l[ob] = *(f16x8*)lv;
    __syncthreads();
  }
}

// ---------------------------------------------------------------------------
__global__ void zero_stats(double* s) { s[threadIdx.x] = 0.0; }

__global__ void bn_stats(const double* __restrict__ osum,
                         const double* __restrict__ osumsq,
                         float* __restrict__ mean, float* __restrict__ rstd) {
  int o = threadIdx.x;
  if (o < CC) {
    const double inv = 1.0 / (double)(BB * TT);
    double mu = osum[o] * inv;
    double var = osumsq[o] * inv - mu * mu;
    mean[o] = (float)mu;
    rstd[o] = (float)(1.0 / sqrt(var + (double)EPSV));
  }
}

__global__ __launch_bounds__(256) void bn_apply(
    float* __restrict__ out, const float* __restrict__ x,
    const float* __restrict__ mean, const float* __restrict__ rstd,
    const float* __restrict__ gamma, const float* __restrict__ beta) {
  const size_t n4 = (size_t)BB * CC * TT / 4;
  for (size_t idx = (size_t)blockIdx.x * blockDim.x + threadIdx.x; idx < n4;
       idx += (size_t)gridDim.x * blockDim.x) {
    size_t e = idx * 4;
    int o = (int)((e / TT) % CC);
    float4 wv = ((const float4*)out)[idx];
    float4 xv = ((const float4*)x)[idx];
    float mu = mean[o], rs = rstd[o], ga = gamma[o], be = beta[o];
    float4 r;
    r.x = fmaxf((wv.x - mu) * rs * ga + be, 0.f) + xv.x;
    r.y = fmaxf((wv.y - mu) * rs * ga + be, 0.f) + xv.y;
    r.z = fmaxf((wv.z - mu) * rs * ga + be, 0.f) + xv.z;
    r.w = fmaxf((wv.w - mu) * rs * ga + be, 0.f) + xv.w;
    ((float4*)out)[idx] = r;
  }
}

// ===========================================================================
// Fallback fp32 path (round-3, known-good) — used if ws too small.
// ===========================================================================
template <int M, int K, bool STATS>
__global__ __launch_bounds__(256) void gemm_proj(
    const float* __restrict__ W, const float* __restrict__ bias,
    const float* __restrict__ X, float* __restrict__ Out,
    double* __restrict__ osum, double* __restrict__ osumsq) {
  __shared__ float Ws[16][65];
  __shared__ float Xs[16][65];
  const int bt = blockIdx.x * 64, bm = blockIdx.y * 64, b = blockIdx.z;
  const int tid = threadIdx.x, tx = tid & 15, ty = tid >> 4;
  const float* Xb = X + (size_t)b * K * TT;
  float acc[4][4] = {};
  for (int kb = 0; kb < K; kb += 16) {
#pragma unroll
    for (int r = 0; r < 4; ++r) {
      int idx = tid + r * 256;
      int m = idx >> 4, k = idx & 15;
      Ws[k][m] = W[(size_t)(bm + m) * K + kb + k];
      int kx = idx >> 6, t = idx & 63;
      Xs[kx][t] = Xb[(size_t)(kb + kx) * TT + bt + t];
    }
    __syncthreads();
#pragma unroll
    for (int k = 0; k < 16; ++k) {
      float a[4], bv[4];
#pragma unroll
      for (int i = 0; i < 4; ++i) a[i] = Ws[k][ty * 4 + i];
#pragma unroll
      for (int j = 0; j < 4; ++j) bv[j] = Xs[k][tx * 4 + j];
#pragma unroll
      for (int i = 0; i < 4; ++i)
#pragma unroll
        for (int j = 0; j < 4; ++j) acc[i][j] += a[i] * bv[j];
    }
    __syncthreads();
  }
#pragma unroll
  for (int i = 0; i < 4; ++i) {
    int m = bm + ty * 4 + i;
    float bv = bias[m];
    double rs = 0.0, rq = 0.0;
#pragma unroll
    for (int j = 0; j < 4; ++j) {
      float v = acc[i][j] + bv;
      Out[((size_t)b * M + m) * TT + bt + tx * 4 + j] = v;
      if (STATS) {
        rs += (double)v;
        rq += (double)v * (double)v;
      }
    }
    if (STATS) {
#pragma unroll
      for (int s = 8; s >= 1; s >>= 1) {
        rs += __shfl_xor(rs, s, 16);
        rq += __shfl_xor(rq, s, 16);
      }
      if (tx == 0) {
        atomicAdd(&osum[m], rs);
        atomicAdd(&osumsq[m], rq);
      }
    }
  }
}

__global__ __launch_bounds__(256) void attn_flash(
    const float* __restrict__ th, const float* __restrict__ ph,
    const float* __restrict__ gx, float* __restrict__ y) {
  __shared__ float As[16][65];
  __shared__ float Bs[16][65];
  __shared__ float Ps[64][65];
  __shared__ float Gs[64][65];
  __shared__ float mScale[64];
  __shared__ float lArr[64];
  const int i0 = blockIdx.x * 64, b = blockIdx.y;
  const int tid = threadIdx.x, tx = tid & 15, ty = tid >> 4;
  const float* thb = th + (size_t)b * ICC * TT;
  const float* phb = ph + (size_t)b * ICC * TT;
  const float* gb = gx + (size_t)b * ICC * TT;
  float m[4], l[4];
#pragma unroll
  for (int i = 0; i < 4; ++i) {
    m[i] = -1e30f;
    l[i] = 0.f;
  }
  float acc[4][4][4] = {};
  for (int j0 = 0; j0 < TT; j0 += 64) {
    float S[4][4] = {};
    for (int cb = 0; cb < ICC; cb += 16) {
#pragma unroll
      for (int r = 0; r < 4; ++r) {
        int idx = tid + r * 256;
        int k = idx >> 6, col = idx & 63;
        As[k][col] = thb[(size_t)(cb + k) * TT + i0 + col];
        Bs[k][col] = phb[(size_t)(cb + k) * TT + j0 + col];
      }
      __syncthreads();
#pragma unroll
      for (int k = 0; k < 16; ++k) {
        float a[4], bv[4];
#pragma unroll
        for (int i = 0; i < 4; ++i) a[i] = As[k][ty * 4 + i];
#pragma unroll
        for (int j = 0; j < 4; ++j) bv[j] = Bs[k][tx * 4 + j];
#pragma unroll
        for (int i = 0; i < 4; ++i)
#pragma unroll
          for (int j = 0; j < 4; ++j) S[i][j] += a[i] * bv[j];
      }
      __syncthreads();
    }
    float sc[4];
#pragma unroll
    for (int i = 0; i < 4; ++i) {
      float mc = S[i][0];
#pragma unroll
      for (int j = 1; j < 4; ++j) mc = fmaxf(mc, S[i][j]);
#pragma unroll
      for (int s = 8; s >= 1; s >>= 1) mc = fmaxf(mc, __shfl_xor(mc, s, 16));
      float mn = fmaxf(m[i], mc);
      sc[i] = __expf(m[i] - mn);
      float lsum = 0.f;
#pragma unroll
      for (int j = 0; j < 4; ++j) {
        float p = __expf(S[i][j] - mn);
        S[i][j] = p;
        lsum += p;
      }
#pragma unroll
      for (int s = 8; s >= 1; s >>= 1) lsum += __shfl_xor(lsum, s, 16);
      l[i] = l[i] * sc[i] + lsum;
      m[i] = mn;
#pragma unroll
      for (int j = 0; j < 4; ++j) Ps[ty * 4 + i][tx * 4 + j] = S[i][j];
    }
    if (tx == 0) {
#pragma unroll
      for (int i = 0; i < 4; ++i) mScale[ty * 4 + i] = sc[i];
    }
    __syncthreads();
#pragma unroll
    for (int cq = 0; cq < 4; ++cq) {
#pragma unroll
      for (int r = 0; r < 16; ++r) {
        int idx = tid + r * 256;
        int cpr = idx >> 6, j = idx & 63;
        Gs[cpr][j] = gb[(size_t)(cq * 64 + cpr) * TT + j0 + j];
      }
      __syncthreads();
      float scj[4];
#pragma unroll
      for (int jq = 0; jq < 4; ++jq) scj[jq] = mScale[tx * 4 + jq];
#pragma unroll
      for (int ci = 0; ci < 4; ++ci)
#pragma unroll
        for (int jq = 0; jq < 4; ++jq) acc[cq][ci][jq] *= scj[jq];
      for (int j = 0; j < 64; ++j) {
        float a[4], p[4];
#pragma unroll
        for (int ci = 0; ci < 4; ++ci) a[ci] = Gs[ty * 4 + ci][j];
#pragma unroll
        for (int jq = 0; jq < 4; ++jq) p[jq] = Ps[tx * 4 + jq][j];
#pragma unroll
        for (int ci = 0; ci < 4; ++ci)
#pragma unroll
          for (int jq = 0; jq < 4; ++jq) acc[cq][ci][jq] += a[ci] * p[jq];
      }
      __syncthreads();
    }
  }
  if (tx == 0) {
#pragma unroll
    for (int i = 0; i < 4; ++i) lArr[ty * 4 + i] = l[i];
  }
  __syncthreads();
  float linv[4];
#pragma unroll
  for (int jq = 0; jq < 4; ++jq) linv[jq] = 1.f / lArr[tx * 4 + jq];
#pragma unroll
  for (int cq = 0; cq < 4; ++cq)
#pragma unroll
    for (int ci = 0; ci < 4; ++ci)
#pragma unroll
      for (int jq = 0; jq < 4; ++jq)
        y[((size_t)b * ICC + cq * 64 + ty * 4 + ci) * TT + i0 + tx * 4 + jq] =
            acc[cq][ci][jq] * linv[jq];
}

// ---------------------------------------------------------------------------
extern "C" void kernel_launch(void* const* d_in, const int* in_sizes, int n_in,
                              void* d_out, int out_size, void* d_ws,
                              size_t ws_size, hipStream_t stream) {
  const float* x = (const float*)d_in[0];
  const float* g_w = (const float*)d_in[1];
  const float* g_b = (const float*)d_in[2];
  const float* th_w = (const float*)d_in[3];
  const float* th_b = (const float*)d_in[4];
  const float* ph_w = (const float*)d_in[5];
  const float* ph_b = (const float*)d_in[6];
  const float* W_w = (const float*)d_in[7];
  const float* W_b = (const float*)d_in[8];
  const float* gamma = (const float*)d_in[9];
  const float* beta = (const float*)d_in[10];
  float* out = (float*)d_out;
  dim3 blk(256);

  const size_t NP = (size_t)BB * TT * ICC;  // 4,194,304
  const size_t NW = 131072;                 // 256*512
  const size_t need = (8 * NP + 8 * NW) * sizeof(f16) + 8192 + 4096;

  if (ws_size >= need) {
    // ---------------- fast MFMA path ----------------
    f16* p = (f16*)d_ws;
    f16 *thH = p, *thL = thH + NP, *phH = thL + NP, *phL = phH + NP;
    f16 *gH = phL + NP, *gL = gH + NP, *yH = gL + NP, *yL = yH + NP;
    f16* wp = yL + NP;
    f16 *gwH = wp, *gwL = gwH + NW, *twH = gwL + NW, *twL = twH + NW;
    f16 *pwH = twL + NW, *pwL = pwH + NW, *wwH = pwL + NW, *wwL = wwH + NW;
    double* statd = (double*)(wwL + NW);
    float* meanb = (float*)(statd + 1024);
    float* rstdb = meanb + 512;
    f16* xTh = (f16*)d_out;  // xT hi/lo lives in d_out (dead before W-conv)
    f16* xTl = xTh + (size_t)BB * TT * CC;

    split_transpose_x<<<dim3(TT / 32, CC / 32, BB), dim3(32, 8), 0, stream>>>(
        x, xTh, xTl);
    // fused 4x weight split + full stats zeroing (replay-safe)
    split_w4<<<2049, 256, 0, stream>>>(g_w, gwH, gwL, th_w, twH, twL, ph_w,
                                       pwH, pwL, W_w, wwH, wwL, statd);
    // fused projections: merged theta+phi (256 blocks) + g (256 blocks)
    fused_proj<<<512, dim3(512), 0, stream>>>(xTh, xTl, twH, twL, th_b, thH,
                                              thL, pwH, pwL, ph_b, phH, phL,
                                              gwH, gwL, g_b, gH, gL);
    // attention -> y f16 hi/lo directly (r18 exact)
    attn_mfma<<<256, dim3(512), 0, stream>>>(thH, thL, phH, phL, gH, gL, yH,
                                             yL);
    // W conv: D[o][t] -> d_out + BN stats  (M=C, N=T, K=IC, bias on M)
    gemm_nt<CC, TT, ICC, false, true><<<dim3(16, 4, BB), dim3(512), 0,
                                        stream>>>(
        wwH, wwL, 0, yH, yL, (long)TT * ICC, W_b, nullptr, nullptr, out,
        (long)CC * TT, statd, statd + CC);
    bn_stats<<<1, 512, 0, stream>>>(statd, statd + CC, meanb, rstdb);
    bn_apply<<<2048, 256, 0, stream>>>(out, x, meanb, rstdb, gamma, beta);
  } else {
    // ---------------- fallback fp32 path ----------------
    float* ws = (float*)d_ws;
    const size_t np = (size_t)BB * ICC * TT;
    float* thb = ws;
    float* phb = ws + np;
    float* gbuf = ws + 2 * np;
    float* yb = thb;
    double* statd = (double*)(ws + 3 * np);
    float* meanb = (float*)(statd + 1024);
    float* rstdb = meanb + 512;
    gemm_proj<ICC, CC, false><<<dim3(TT / 64, ICC / 64, BB), blk, 0, stream>>>(
        th_w, th_b, x, thb, nullptr, nullptr);
    gemm_proj<ICC, CC, false><<<dim3(TT / 64, ICC / 64, BB), blk, 0, stream>>>(
        ph_w, ph_b, x, phb, nullptr, nullptr);
    gemm_proj<ICC, CC, false><<<dim3(TT / 64, ICC / 64, BB), blk, 0, stream>>>(
        g_w, g_b, x, gbuf, nullptr, nullptr);
    attn_flash<<<dim3(TT / 64, BB), blk, 0, stream>>>(thb, phb, gbuf, yb);
    zero_stats<<<1, 1024, 0, stream>>>(statd);
    gemm_proj<CC, ICC, true><<<dim3(TT / 64, CC / 64, BB), blk, 0, stream>>>(
        W_w, W_b, yb, out, statd, statd + CC);
    bn_stats<<<1, 512, 0, stream>>>(statd, statd + CC, meanb, rstdb);
    bn_apply<<<2048, 256, 0, stream>>>(out, x, meanb, rstdb, gamma, beta);
  }
}

// Round 23
// 396.546 us; speedup vs baseline: 1.2232x; 1.0164x over previous
//
#include <hip/hip_runtime.h>
#include <math.h>

#define BB 8
#define CC 512
#define TT 2048
#define ICC 256
#define EPSV 1e-5f
#define SC2048 2048.0f
#define INV2048 4.8828125e-4f

typedef _Float16 f16;
typedef __attribute__((ext_vector_type(8))) _Float16 f16x8;
typedef __attribute__((ext_vector_type(4))) float f32x4;

#define MFMA(a, b, c) __builtin_amdgcn_mfma_f32_16x16x32_f16(a, b, c, 0, 0, 0)

__device__ __forceinline__ int swz(int byte, int row) {
  return byte ^ ((row & 7) << 4);
}

// global -> LDS direct (16B/lane). LDS dest = wave-uniform base + lane*16.
__device__ __forceinline__ void ld_lds16(const void* g, void* l) {
  __builtin_amdgcn_global_load_lds(
      (const __attribute__((address_space(1))) unsigned int*)g,
      (__attribute__((address_space(3))) unsigned int*)l, 16, 0, 0);
}

// inverse of slot-swizzle o = s ^ ((s>>2)&7)  (row = slot>>2 layouts)
__device__ __forceinline__ int inv_swz_r2(int o) {
  return o ^ (((o >> 2) & 6) | (((o >> 2) ^ (o >> 4)) & 1));
}
// inverse of slot-swizzle o = s ^ ((s>>5)&7)  (row = slot>>5; involution)
__device__ __forceinline__ int inv_swz_r5(int o) { return o ^ ((o >> 5) & 7); }

// ---------------------------------------------------------------------------
// Fused front-end (r23): blocks 0..2047 split the 4 weight tensors;
// block 2048 zeros stats (strided, replay-safe); blocks 2049..10240 run the
// x transpose+split tiles (r22's split_transpose_x math, flat-tid decode).
// ---------------------------------------------------------------------------
__global__ void front_end(const float* __restrict__ s0, f16* __restrict__ h0,
                          f16* __restrict__ l0, const float* __restrict__ s1,
                          f16* __restrict__ h1, f16* __restrict__ l1,
                          const float* __restrict__ s2, f16* __restrict__ h2,
                          f16* __restrict__ l2, const float* __restrict__ s3,
                          f16* __restrict__ h3, f16* __restrict__ l3,
                          double* __restrict__ statd,
                          const float* __restrict__ x, f16* __restrict__ xh,
                          f16* __restrict__ xl) {
  const int NW = 131072;
  int bx = blockIdx.x;
  int tid = threadIdx.x;
  if (bx < 2048) {
    int i = bx * 256 + tid;
    int which = i >> 17;
    int j = i & (NW - 1);
    const float* src =
        which == 0 ? s0 : which == 1 ? s1 : which == 2 ? s2 : s3;
    f16* h = which == 0 ? h0 : which == 1 ? h1 : which == 2 ? h2 : h3;
    f16* lo = which == 0 ? l0 : which == 1 ? l1 : which == 2 ? l2 : l3;
    float v = src[j];
    f16 a = (f16)v;
    h[j] = a;
    lo[j] = (f16)((v - (float)a) * SC2048);
    return;
  }
  if (bx == 2048) {
    for (int k = tid; k < 1024; k += 256) statd[k] = 0.0;
    return;
  }
  // ---- transpose tiles: sub in [0, 8192)
  int sub = bx - 2049;
  int t0 = (sub & 63) * 32;
  int c0 = ((sub >> 6) & 15) * 32;
  int b = sub >> 10;
  __shared__ float tile[32][33];
  int tx = tid & 31, ty = tid >> 5;  // 32 x 8
#pragma unroll
  for (int k = 0; k < 4; ++k)
    tile[ty + 8 * k][tx] = x[((size_t)b * CC + c0 + ty + 8 * k) * TT + t0 + tx];
  __syncthreads();
#pragma unroll
  for (int k = 0; k < 4; ++k) {
    float v = tile[tx][ty + 8 * k];
    size_t o = ((size_t)b * TT + t0 + ty + 8 * k) * CC + c0 + tx;
    f16 h = (f16)v;
    xh[o] = h;
    xl[o] = (f16)((v - (float)h) * SC2048);
  }
}

// ---------------------------------------------------------------------------
// GEMM body (r19-verified): D = A*B^T + bias, split-f16, dbuf gload_lds,
// one barrier per K-step. 512 threads = 8 waves of 64x32 output.
// ---------------------------------------------------------------------------
template <int M, int N, int K, bool BIAS_N, bool F32OUT>
__device__ __forceinline__ void gemm_body(
    f16 (*sBuf)[4][4096], const f16* __restrict__ Ah,
    const f16* __restrict__ Al, long strideA, const f16* __restrict__ Bh,
    const f16* __restrict__ Bl, long strideB, const float* __restrict__ bias,
    f16* __restrict__ Oh, f16* __restrict__ Ol, float* __restrict__ Of,
    long strideO, double* __restrict__ osum, double* __restrict__ osumsq,
    int bxx, int byy, int bzz) {
  const int tid = threadIdx.x;
  const int w = tid >> 6, l = tid & 63;
  const int bn = bxx * 128, bm = byy * 128;
  const size_t baseA = (size_t)bzz * strideA;
  const size_t baseB = (size_t)bzz * strideB;
  const size_t baseO = (size_t)bzz * strideO;
  const int m0 = (w >> 2) * 64, n0 = (w & 3) * 32;

  auto stage = [&](int kb, int buf) {
    int base = w * 64;
    int s = inv_swz_r2(base + l);
    int row = s >> 2, ks = s & 3;
    size_t ga = baseA + (size_t)(bm + row) * K + kb + ks * 8;
    size_t gb = baseB + (size_t)(bn + row) * K + kb + ks * 8;
    ld_lds16(Ah + ga, (char*)&sBuf[buf][0][0] + base * 16);
    ld_lds16(Al + ga, (char*)&sBuf[buf][1][0] + base * 16);
    ld_lds16(Bh + gb, (char*)&sBuf[buf][2][0] + base * 16);
    ld_lds16(Bl + gb, (char*)&sBuf[buf][3][0] + base * 16);
  };

  f32x4 acc[4][2], accL[4][2];
#pragma unroll
  for (int i = 0; i < 4; ++i)
#pragma unroll
    for (int j = 0; j < 2; ++j) {
      acc[i][j] = (f32x4){0.f, 0.f, 0.f, 0.f};
      accL[i][j] = (f32x4){0.f, 0.f, 0.f, 0.f};
    }

  stage(0, 0);
  __syncthreads();
  const int nsteps = K / 32;
  for (int st = 0; st < nsteps; ++st) {
    const int cur = st & 1, nxt = cur ^ 1;
    if (st + 1 < nsteps) stage((st + 1) * 32, nxt);
    char* cAh = (char*)&sBuf[cur][0][0];
    char* cAl = (char*)&sBuf[cur][1][0];
    char* cBh = (char*)&sBuf[cur][2][0];
    char* cBl = (char*)&sBuf[cur][3][0];
    f16x8 ah[4], al[4];
#pragma unroll
    for (int mf = 0; mf < 4; ++mf) {
      int row = m0 + mf * 16 + (l & 15);
      int byte = swz(row * 64 + ((l >> 4) << 4), row);
      ah[mf] = *(const f16x8*)(cAh + byte);
      al[mf] = *(const f16x8*)(cAl + byte);
    }
#pragma unroll
    for (int nf = 0; nf < 2; ++nf) {
      int row = n0 + nf * 16 + (l & 15);
      int byte = swz(row * 64 + ((l >> 4) << 4), row);
      f16x8 bh = *(const f16x8*)(cBh + byte);
      f16x8 bl = *(const f16x8*)(cBl + byte);
#pragma unroll
      for (int mf = 0; mf < 4; ++mf)
        acc[mf][nf] = MFMA(ah[mf], bh, acc[mf][nf]);
#pragma unroll
      for (int mf = 0; mf < 4; ++mf)
        accL[mf][nf] = MFMA(al[mf], bh, accL[mf][nf]);
#pragma unroll
      for (int mf = 0; mf < 4; ++mf)
        accL[mf][nf] = MFMA(ah[mf], bl, accL[mf][nf]);
    }
    __syncthreads();
  }

  if (F32OUT) {
#pragma unroll
    for (int mf = 0; mf < 4; ++mf)
#pragma unroll
      for (int r = 0; r < 4; ++r) {
        int mrow = bm + m0 + mf * 16 + ((l >> 4) << 2) + r;
        float bv = bias[mrow];
        double s = 0.0, q = 0.0;
#pragma unroll
        for (int nf = 0; nf < 2; ++nf) {
          float v = acc[mf][nf][r] + accL[mf][nf][r] * INV2048 + bv;
          Of[baseO + (size_t)mrow * N + bn + n0 + nf * 16 + (l & 15)] = v;
          s += (double)v;
          q += (double)v * (double)v;
        }
#pragma unroll
        for (int sh = 8; sh >= 1; sh >>= 1) {
          s += __shfl_xor(s, sh);
          q += __shfl_xor(q, sh);
        }
        if ((l & 15) == 0) {
          atomicAdd(&osum[mrow], s);
          atomicAdd(&osumsq[mrow], q);
        }
      }
  } else {
    float* sOut = (float*)&sBuf[0][0][0];
    for (int c = 0; c < 4; ++c) {
      __syncthreads();
      if ((w >> 2) == (c >> 1)) {
#pragma unroll
        for (int mf2 = 0; mf2 < 2; ++mf2) {
          int mf = (c & 1) * 2 + mf2;
          int rl = mf2 * 16 + ((l >> 4) << 2);
#pragma unroll
          for (int nf = 0; nf < 2; ++nf)
#pragma unroll
            for (int r = 0; r < 4; ++r)
              sOut[(rl + r) * 132 + n0 + nf * 16 + (l & 15)] =
                  acc[mf][nf][r] + accL[mf][nf][r] * INV2048;
        }
      }
      __syncthreads();
      int row = tid >> 4, cc0 = (tid & 15) * 8;
      size_t gm = bm + c * 32 + row;
      size_t ob = baseO + gm * (size_t)N + bn + cc0;
      f16 hv[8], lv[8];
#pragma unroll
      for (int e = 0; e < 8; ++e) {
        float v = sOut[row * 132 + cc0 + e];
        v += BIAS_N ? bias[bn + cc0 + e] : bias[gm];
        f16 h = (f16)v;
        hv[e] = h;
        lv[e] = (f16)((v - (float)h) * SC2048);
      }
      *(f16x8*)&Oh[ob] = *(f16x8*)hv;
      *(f16x8*)&Ol[ob] = *(f16x8*)lv;
    }
  }
}

// standalone GEMM kernel (used for W-conv, F32OUT path)
template <int M, int N, int K, bool BIAS_N, bool F32OUT>
__global__ __launch_bounds__(512)
    __attribute__((amdgpu_waves_per_eu(2, 2))) void gemm_nt(
        const f16* __restrict__ Ah, const f16* __restrict__ Al, long strideA,
        const f16* __restrict__ Bh, const f16* __restrict__ Bl, long strideB,
        const float* __restrict__ bias, f16* __restrict__ Oh,
        f16* __restrict__ Ol, float* __restrict__ Of, long strideO,
        double* __restrict__ osum, double* __restrict__ osumsq) {
  __shared__ f16 sBuf[2][4][4096];
  gemm_body<M, N, K, BIAS_N, F32OUT>(sBuf, Ah, Al, strideA, Bh, Bl, strideB,
                                     bias, Oh, Ol, Of, strideO, osum, osumsq,
                                     blockIdx.x, blockIdx.y, blockIdx.z);
}

// ---------------------------------------------------------------------------
// fused projections (r22-verified): blocks 0..255 compute BOTH theta and phi
// sharing one xT staging; blocks 256..511 compute g. 96KB LDS.
// ---------------------------------------------------------------------------
__global__ __launch_bounds__(512)
    __attribute__((amdgpu_waves_per_eu(2, 2))) void fused_proj(
        const f16* __restrict__ xTh, const f16* __restrict__ xTl,
        const f16* __restrict__ twH, const f16* __restrict__ twL,
        const float* __restrict__ th_b, f16* __restrict__ thH,
        f16* __restrict__ thL, const f16* __restrict__ pwH,
        const f16* __restrict__ pwL, const float* __restrict__ ph_b,
        f16* __restrict__ phH, f16* __restrict__ phL,
        const f16* __restrict__ gwH, const f16* __restrict__ gwL,
        const float* __restrict__ g_b, f16* __restrict__ gH,
        f16* __restrict__ gL) {
  __shared__ f16 sMem[2][6][4096];  // merged: A hi/lo, tw hi/lo, pw hi/lo
  int bx = blockIdx.x;
  if (bx < 256) {
    int gx = bx & 1, gy = (bx >> 1) & 15, gz = bx >> 5;
    const int tid = threadIdx.x, w = tid >> 6, l = tid & 63;
    const int bn = gx * 128, bm = gy * 128;
    const size_t baseA = (size_t)gz * ((size_t)TT * CC);
    const size_t baseO = (size_t)gz * ((size_t)TT * ICC);
    const int m0 = (w >> 2) * 64, n0 = (w & 3) * 32;

    auto stage = [&](int kb, int buf) {
      int base = w * 64;
      int s = inv_swz_r2(base + l);
      int row = s >> 2, ks = s & 3;
      size_t ga = baseA + (size_t)(bm + row) * CC + kb + ks * 8;
      size_t gb = (size_t)(bn + row) * CC + kb + ks * 8;
      ld_lds16(xTh + ga, (char*)&sMem[buf][0][0] + base * 16);
      ld_lds16(xTl + ga, (char*)&sMem[buf][1][0] + base * 16);
      ld_lds16(twH + gb, (char*)&sMem[buf][2][0] + base * 16);
      ld_lds16(twL + gb, (char*)&sMem[buf][3][0] + base * 16);
      ld_lds16(pwH + gb, (char*)&sMem[buf][4][0] + base * 16);
      ld_lds16(pwL + gb, (char*)&sMem[buf][5][0] + base * 16);
    };

    f32x4 a1[4][2], a1L[4][2], a2[4][2], a2L[4][2];
#pragma unroll
    for (int i = 0; i < 4; ++i)
#pragma unroll
      for (int j = 0; j < 2; ++j) {
        a1[i][j] = (f32x4){0.f, 0.f, 0.f, 0.f};
        a1L[i][j] = (f32x4){0.f, 0.f, 0.f, 0.f};
        a2[i][j] = (f32x4){0.f, 0.f, 0.f, 0.f};
        a2L[i][j] = (f32x4){0.f, 0.f, 0.f, 0.f};
      }

    stage(0, 0);
    __syncthreads();
    for (int st = 0; st < 16; ++st) {
      const int cur = st & 1, nxt = cur ^ 1;
      if (st + 1 < 16) stage((st + 1) * 32, nxt);
      char* cAh = (char*)&sMem[cur][0][0];
      char* cAl = (char*)&sMem[cur][1][0];
      char* cB1h = (char*)&sMem[cur][2][0];
      char* cB1l = (char*)&sMem[cur][3][0];
      char* cB2h = (char*)&sMem[cur][4][0];
      char* cB2l = (char*)&sMem[cur][5][0];
      f16x8 ah[4], al[4];
#pragma unroll
      for (int mf = 0; mf < 4; ++mf) {
        int row = m0 + mf * 16 + (l & 15);
        int byte = swz(row * 64 + ((l >> 4) << 4), row);
        ah[mf] = *(const f16x8*)(cAh + byte);
        al[mf] = *(const f16x8*)(cAl + byte);
      }
#pragma unroll
      for (int nf = 0; nf < 2; ++nf) {
        int row = n0 + nf * 16 + (l & 15);
        int byte = swz(row * 64 + ((l >> 4) << 4), row);
        f16x8 b1h = *(const f16x8*)(cB1h + byte);
        f16x8 b1l = *(const f16x8*)(cB1l + byte);
        f16x8 b2h = *(const f16x8*)(cB2h + byte);
        f16x8 b2l = *(const f16x8*)(cB2l + byte);
#pragma unroll
        for (int mf = 0; mf < 4; ++mf)
          a1[mf][nf] = MFMA(ah[mf], b1h, a1[mf][nf]);
#pragma unroll
        for (int mf = 0; mf < 4; ++mf)
          a1L[mf][nf] = MFMA(al[mf], b1h, a1L[mf][nf]);
#pragma unroll
        for (int mf = 0; mf < 4; ++mf)
          a1L[mf][nf] = MFMA(ah[mf], b1l, a1L[mf][nf]);
#pragma unroll
        for (int mf = 0; mf < 4; ++mf)
          a2[mf][nf] = MFMA(ah[mf], b2h, a2[mf][nf]);
#pragma unroll
        for (int mf = 0; mf < 4; ++mf)
          a2L[mf][nf] = MFMA(al[mf], b2h, a2L[mf][nf]);
#pragma unroll
        for (int mf = 0; mf < 4; ++mf)
          a2L[mf][nf] = MFMA(ah[mf], b2l, a2L[mf][nf]);
      }
      __syncthreads();
    }

    float* sOut = (float*)&sMem[0][0][0];
    auto epi = [&](f32x4(*A)[2], f32x4(*AL)[2], const float* bias, f16* Oh,
                   f16* Ol) {
      for (int c = 0; c < 4; ++c) {
        __syncthreads();
        if ((w >> 2) == (c >> 1)) {
#pragma unroll
          for (int mf2 = 0; mf2 < 2; ++mf2) {
            int mf = (c & 1) * 2 + mf2;
            int rl = mf2 * 16 + ((l >> 4) << 2);
#pragma unroll
            for (int nf = 0; nf < 2; ++nf)
#pragma unroll
              for (int r = 0; r < 4; ++r)
                sOut[(rl + r) * 132 + n0 + nf * 16 + (l & 15)] =
                    A[mf][nf][r] + AL[mf][nf][r] * INV2048;
          }
        }
        __syncthreads();
        int row = tid >> 4, cc0 = (tid & 15) * 8;
        size_t gm = bm + c * 32 + row;
        size_t ob = baseO + gm * (size_t)ICC + bn + cc0;
        f16 hv[8], lv[8];
#pragma unroll
        for (int e = 0; e < 8; ++e) {
          float v = sOut[row * 132 + cc0 + e] + bias[bn + cc0 + e];
          f16 h = (f16)v;
          hv[e] = h;
          lv[e] = (f16)((v - (float)h) * SC2048);
        }
        *(f16x8*)&Oh[ob] = *(f16x8*)hv;
        *(f16x8*)&Ol[ob] = *(f16x8*)lv;
      }
    };
    epi(a1, a1L, th_b, thH, thL);
    epi(a2, a2L, ph_b, phH, phL);
  } else {
    int sub = bx - 256;
    int gx = sub & 15, gy = (sub >> 4) & 1, gz = sub >> 5;
    f16(*sBuf)[4][4096] = reinterpret_cast<f16(*)[4][4096]>(&sMem[0][0][0]);
    gemm_body<ICC, TT, CC, false, false>(sBuf, gwH, gwL, 0, xTh, xTl,
                                         (long)TT * CC, g_b, gH, gL, nullptr,
                                         (long)ICC * TT, nullptr, nullptr, gx,
                                         gy, gz);
  }
}

// ---------------------------------------------------------------------------
// Fused flash attention (r18 exact, verified 245us): j-split QK, dbuf staging,
// 3 barriers/chunk, waves_per_eu(2,2).
// ---------------------------------------------------------------------------
__global__ __launch_bounds__(512)
    __attribute__((amdgpu_waves_per_eu(2, 2))) void attn_mfma(
        const f16* __restrict__ th_h, const f16* __restrict__ th_l,
        const f16* __restrict__ ph_h, const f16* __restrict__ ph_l,
        const f16* __restrict__ g_h, const f16* __restrict__ g_l,
        f16* __restrict__ y_h, f16* __restrict__ y_l) {
  __shared__ f16 sPhiH[2][8192], sPhiL[2][8192];  // phi [buf][32 j][256 c]
  __shared__ f16 sGH[2][8192], sGL[2][8192];      // g   [buf][256 c][32 j]
  __shared__ f16 sP[2048], sPl[2048];             // P hi / scaled-lo [64][32]
  __shared__ float sPm[2][64], sPs[2][64];        // per-row partial max/sum
  __shared__ float sSc[64], sL[64];
  const int tid = threadIdx.x, w = tid >> 6, l = tid & 63;
  const int b = blockIdx.x & 7;
  const int i0 = (blockIdx.x >> 3) * 64;
  const int gj = w >> 2;        // j-half this wave computes in QK
  const int rw = (w & 3) * 16;  // QK row base

  auto stagePhi = [&](int j0, int buf) {
#pragma unroll
    for (int rep = 0; rep < 2; ++rep) {
      int base = w * 64 + rep * 512;
      int s = inv_swz_r5(base + l);
      int row = s >> 5, kq = s & 31;
      size_t ga = ((size_t)b * TT + j0 + row) * 256 + kq * 8;
      ld_lds16(ph_h + ga, (char*)&sPhiH[buf][0] + base * 16);
      ld_lds16(ph_l + ga, (char*)&sPhiL[buf][0] + base * 16);
    }
  };
  auto stageG = [&](int j0, int buf) {
#pragma unroll
    for (int rep = 0; rep < 2; ++rep) {
      int base = w * 64 + rep * 512;
      int s = inv_swz_r2(base + l);
      int row = s >> 2, kq = s & 3;
      size_t ga = ((size_t)b * 256 + row) * TT + j0 + kq * 8;
      ld_lds16(g_h + ga, (char*)&sGH[buf][0] + base * 16);
      ld_lds16(g_l + ga, (char*)&sGL[buf][0] + base * 16);
    }
  };

  const size_t tbase =
      ((size_t)b * TT + i0 + rw + (l & 15)) * 256 + ((l >> 4) << 3);
  f16x8 qh[8], ql[8];
#pragma unroll
  for (int kf = 0; kf < 8; ++kf) {
    qh[kf] = *(const f16x8*)(th_h + tbase + kf * 32);
    ql[kf] = *(const f16x8*)(th_l + tbase + kf * 32);
  }
  f32x4 yacc[4][2], yaccL[4][2];
#pragma unroll
  for (int i = 0; i < 4; ++i)
#pragma unroll
    for (int j = 0; j < 2; ++j) {
      yacc[i][j] = (f32x4){0.f, 0.f, 0.f, 0.f};
      yaccL[i][j] = (f32x4){0.f, 0.f, 0.f, 0.f};
    }
  float mrow[4], lrow[4];
#pragma unroll
  for (int r = 0; r < 4; ++r) {
    mrow[r] = -3e38f;
    lrow[r] = 0.f;
  }

  stagePhi(0, 0);
  stageG(0, 0);
  __syncthreads();

  for (int jc = 0; jc < 64; ++jc) {
    const int cur = jc & 1, nxt = cur ^ 1;
    if (jc < 63) {
      stagePhi((jc + 1) * 32, nxt);
      stageG((jc + 1) * 32, nxt);
    }
    f32x4 s4 = (f32x4){0.f, 0.f, 0.f, 0.f};
    f32x4 s4L = (f32x4){0.f, 0.f, 0.f, 0.f};
    {
      int prow = gj * 16 + (l & 15);
#pragma unroll
      for (int kf = 0; kf < 8; ++kf) {
        int byte = swz(prow * 512 + kf * 64 + ((l >> 4) << 4), prow);
        f16x8 bh = *(const f16x8*)((char*)&sPhiH[cur][0] + byte);
        f16x8 bl = *(const f16x8*)((char*)&sPhiL[cur][0] + byte);
        s4 = MFMA(qh[kf], bh, s4);
        s4L = MFMA(ql[kf], bh, s4L);
        s4L = MFMA(qh[kf], bl, s4L);
      }
    }
    float sv[4], pm[4];
#pragma unroll
    for (int r = 0; r < 4; ++r) {
      sv[r] = s4[r] + s4L[r] * INV2048;
      float mx = sv[r];
#pragma unroll
      for (int sh = 8; sh >= 1; sh >>= 1) mx = fmaxf(mx, __shfl_xor(mx, sh));
      pm[r] = mx;
    }
    if ((l & 15) == 0) {
#pragma unroll
      for (int r = 0; r < 4; ++r) sPm[gj][rw + ((l >> 4) << 2) + r] = pm[r];
    }
    __syncthreads();  // B: partial maxima visible; staged loads drained
    float scr[4];
#pragma unroll
    for (int r = 0; r < 4; ++r) {
      int row = rw + ((l >> 4) << 2) + r;
      float mx = fmaxf(sPm[0][row], sPm[1][row]);
      float mn = fmaxf(mrow[r], mx);
      scr[r] = __expf(mrow[r] - mn);
      mrow[r] = mn;
      float p = __expf(sv[r] - mn);
      float ls = p;
#pragma unroll
      for (int sh = 8; sh >= 1; sh >>= 1) ls += __shfl_xor(ls, sh);
      int jj = gj * 16 + (l & 15);
      f16 h = (f16)p;
      *(f16*)((char*)sP + swz(row * 64 + jj * 2, row)) = h;
      *(f16*)((char*)sPl + swz(row * 64 + jj * 2, row)) =
          (f16)((p - (float)h) * SC2048);
      if ((l & 15) == 0) {
        sPs[gj][row] = ls;
        if (gj == 0) sSc[row] = scr[r];
      }
    }
    __syncthreads();  // C: P + partial sums + sSc published
#pragma unroll
    for (int r = 0; r < 4; ++r) {
      int row = rw + ((l >> 4) << 2) + r;
      lrow[r] = lrow[r] * scr[r] + (sPs[0][row] + sPs[1][row]);
    }
#pragma unroll
    for (int mf = 0; mf < 4; ++mf)
#pragma unroll
      for (int r = 0; r < 4; ++r) {
        float s0 = sSc[mf * 16 + ((l >> 4) << 2) + r];
#pragma unroll
        for (int cf = 0; cf < 2; ++cf) {
          yacc[mf][cf][r] *= s0;
          yaccL[mf][cf][r] *= s0;
        }
      }
#pragma unroll
    for (int mf = 0; mf < 4; ++mf) {
      int prow = mf * 16 + (l & 15);
      int pb = swz(prow * 64 + ((l >> 4) << 4), prow);
      f16x8 pa = *(const f16x8*)((char*)sP + pb);
      f16x8 paL = *(const f16x8*)((char*)sPl + pb);
#pragma unroll
      for (int cf = 0; cf < 2; ++cf) {
        int crow = w * 32 + cf * 16 + (l & 15);
        int gb2 = swz(crow * 64 + ((l >> 4) << 4), crow);
        f16x8 gh = *(const f16x8*)((char*)&sGH[cur][0] + gb2);
        f16x8 gl = *(const f16x8*)((char*)&sGL[cur][0] + gb2);
        yacc[mf][cf] = MFMA(pa, gh, yacc[mf][cf]);
        yaccL[mf][cf] = MFMA(paL, gh, yaccL[mf][cf]);
        yaccL[mf][cf] = MFMA(pa, gl, yaccL[mf][cf]);
      }
    }
    __syncthreads();  // D: P/g reads done before next softmax/staging reuse
  }

  if (gj == 0 && (l & 15) == 0) {
#pragma unroll
    for (int r = 0; r < 4; ++r) sL[rw + ((l >> 4) << 2) + r] = lrow[r];
  }
  __syncthreads();
  float* sOutF = (float*)&sPhiH[0][0];
  for (int c2 = 0; c2 < 4; ++c2) {
#pragma unroll
    for (int r = 0; r < 4; ++r) {
      int row = c2 * 16 + ((l >> 4) << 2) + r;
      float linv = 1.f / sL[row];
      int rl = row - c2 * 16;
#pragma unroll
      for (int cf = 0; cf < 2; ++cf)
        sOutF[rl * 264 + w * 32 + cf * 16 + (l & 15)] =
            (yacc[c2][cf][r] + yaccL[c2][cf][r] * INV2048) * linv;
    }
    __syncthreads();
    int row = tid >> 5, cc0 = (tid & 31) * 8;
    size_t ob = ((size_t)b * TT + i0 + c2 * 16 + row) * 256 + cc0;
    f16 hv[8], lv[8];
#pragma unroll
    for (int e = 0; e < 8; ++e) {
      float v = sOutF[row * 264 + cc0 + e];
      f16 h = (f16)v;
      hv[e] = h;
      lv[e] = (f16)((v - (float)h) * SC2048);
    }
    *(f16x8*)&y_h[ob] = *(f16x8*)hv;
    *(f16x8*)&y_l[ob] = *(f16x8*)lv;
    __syncthreads();
  }
}

// ---------------------------------------------------------------------------
__global__ void zero_stats(double* s) { s[threadIdx.x] = 0.0; }

__global__ void bn_stats(const double* __restrict__ osum,
                         const double* __restrict__ osumsq,
                         float* __restrict__ mean, float* __restrict__ rstd) {
  int o = threadIdx.x;
  if (o < CC) {
    const double inv = 1.0 / (double)(BB * TT);
    double mu = osum[o] * inv;
    double var = osumsq[o] * inv - mu * mu;
    mean[o] = (float)mu;
    rstd[o] = (float)(1.0 / sqrt(var + (double)EPSV));
  }
}

// r23: folds bn_stats per-block (redundant compute from statd into LDS)
__global__ __launch_bounds__(256) void bn_apply_fused(
    float* __restrict__ out, const float* __restrict__ x,
    const double* __restrict__ statd, const float* __restrict__ gamma,
    const float* __restrict__ beta) {
  __shared__ float sMean[CC], sRstd[CC];
  for (int o = threadIdx.x; o < CC; o += 256) {
    const double inv = 1.0 / (double)(BB * TT);
    double mu = statd[o] * inv;
    double var = statd[CC + o] * inv - mu * mu;
    sMean[o] = (float)mu;
    sRstd[o] = (float)(1.0 / sqrt(var + (double)EPSV));
  }
  __syncthreads();
  const size_t n4 = (size_t)BB * CC * TT / 4;
  for (size_t idx = (size_t)blockIdx.x * blockDim.x + threadIdx.x; idx < n4;
       idx += (size_t)gridDim.x * blockDim.x) {
    size_t e = idx * 4;
    int o = (int)((e / TT) % CC);
    float4 wv = ((const float4*)out)[idx];
    float4 xv = ((const float4*)x)[idx];
    float mu = sMean[o], rs = sRstd[o], ga = gamma[o], be = beta[o];
    float4 r;
    r.x = fmaxf((wv.x - mu) * rs * ga + be, 0.f) + xv.x;
    r.y = fmaxf((wv.y - mu) * rs * ga + be, 0.f) + xv.y;
    r.z = fmaxf((wv.z - mu) * rs * ga + be, 0.f) + xv.z;
    r.w = fmaxf((wv.w - mu) * rs * ga + be, 0.f) + xv.w;
    ((float4*)out)[idx] = r;
  }
}

__global__ __launch_bounds__(256) void bn_apply(
    float* __restrict__ out, const float* __restrict__ x,
    const float* __restrict__ mean, const float* __restrict__ rstd,
    const float* __restrict__ gamma, const float* __restrict__ beta) {
  const size_t n4 = (size_t)BB * CC * TT / 4;
  for (size_t idx = (size_t)blockIdx.x * blockDim.x + threadIdx.x; idx < n4;
       idx += (size_t)gridDim.x * blockDim.x) {
    size_t e = idx * 4;
    int o = (int)((e / TT) % CC);
    float4 wv = ((const float4*)out)[idx];
    float4 xv = ((const float4*)x)[idx];
    float mu = mean[o], rs = rstd[o], ga = gamma[o], be = beta[o];
    float4 r;
    r.x = fmaxf((wv.x - mu) * rs * ga + be, 0.f) + xv.x;
    r.y = fmaxf((wv.y - mu) * rs * ga + be, 0.f) + xv.y;
    r.z = fmaxf((wv.z - mu) * rs * ga + be, 0.f) + xv.z;
    r.w = fmaxf((wv.w - mu) * rs * ga + be, 0.f) + xv.w;
    ((float4*)out)[idx] = r;
  }
}

// ===========================================================================
// Fallback fp32 path (round-3, known-good) — used if ws too small.
// ===========================================================================
template <int M, int K, bool STATS>
__global__ __launch_bounds__(256) void gemm_proj(
    const float* __restrict__ W, const float* __restrict__ bias,
    const float* __restrict__ X, float* __restrict__ Out,
    double* __restrict__ osum, double* __restrict__ osumsq) {
  __shared__ float Ws[16][65];
  __shared__ float Xs[16][65];
  const int bt = blockIdx.x * 64, bm = blockIdx.y * 64, b = blockIdx.z;
  const int tid = threadIdx.x, tx = tid & 15, ty = tid >> 4;
  const float* Xb = X + (size_t)b * K * TT;
  float acc[4][4] = {};
  for (int kb = 0; kb < K; kb += 16) {
#pragma unroll
    for (int r = 0; r < 4; ++r) {
      int idx = tid + r * 256;
      int m = idx >> 4, k = idx & 15;
      Ws[k][m] = W[(size_t)(bm + m) * K + kb + k];
      int kx = idx >> 6, t = idx & 63;
      Xs[kx][t] = Xb[(size_t)(kb + kx) * TT + bt + t];
    }
    __syncthreads();
#pragma unroll
    for (int k = 0; k < 16; ++k) {
      float a[4], bv[4];
#pragma unroll
      for (int i = 0; i < 4; ++i) a[i] = Ws[k][ty * 4 + i];
#pragma unroll
      for (int j = 0; j < 4; ++j) bv[j] = Xs[k][tx * 4 + j];
#pragma unroll
      for (int i = 0; i < 4; ++i)
#pragma unroll
        for (int j = 0; j < 4; ++j) acc[i][j] += a[i] * bv[j];
    }
    __syncthreads();
  }
#pragma unroll
  for (int i = 0; i < 4; ++i) {
    int m = bm + ty * 4 + i;
    float bv = bias[m];
    double rs = 0.0, rq = 0.0;
#pragma unroll
    for (int j = 0; j < 4; ++j) {
      float v = acc[i][j] + bv;
      Out[((size_t)b * M + m) * TT + bt + tx * 4 + j] = v;
      if (STATS) {
        rs += (double)v;
        rq += (double)v * (double)v;
      }
    }
    if (STATS) {
#pragma unroll
      for (int s = 8; s >= 1; s >>= 1) {
        rs += __shfl_xor(rs, s, 16);
        rq += __shfl_xor(rq, s, 16);
      }
      if (tx == 0) {
        atomicAdd(&osum[m], rs);
        atomicAdd(&osumsq[m], rq);
      }
    }
  }
}

__global__ __launch_bounds__(256) void attn_flash(
    const float* __restrict__ th, const float* __restrict__ ph,
    const float* __restrict__ gx, float* __restrict__ y) {
  __shared__ float As[16][65];
  __shared__ float Bs[16][65];
  __shared__ float Ps[64][65];
  __shared__ float Gs[64][65];
  __shared__ float mScale[64];
  __shared__ float lArr[64];
  const int i0 = blockIdx.x * 64, b = blockIdx.y;
  const int tid = threadIdx.x, tx = tid & 15, ty = tid >> 4;
  const float* thb = th + (size_t)b * ICC * TT;
  const float* phb = ph + (size_t)b * ICC * TT;
  const float* gb = gx + (size_t)b * ICC * TT;
  float m[4], l[4];
#pragma unroll
  for (int i = 0; i < 4; ++i) {
    m[i] = -1e30f;
    l[i] = 0.f;
  }
  float acc[4][4][4] = {};
  for (int j0 = 0; j0 < TT; j0 += 64) {
    float S[4][4] = {};
    for (int cb = 0; cb < ICC; cb += 16) {
#pragma unroll
      for (int r = 0; r < 4; ++r) {
        int idx = tid + r * 256;
        int k = idx >> 6, col = idx & 63;
        As[k][col] = thb[(size_t)(cb + k) * TT + i0 + col];
        Bs[k][col] = phb[(size_t)(cb + k) * TT + j0 + col];
      }
      __syncthreads();
#pragma unroll
      for (int k = 0; k < 16; ++k) {
        float a[4], bv[4];
#pragma unroll
        for (int i = 0; i < 4; ++i) a[i] = As[k][ty * 4 + i];
#pragma unroll
        for (int j = 0; j < 4; ++j) bv[j] = Bs[k][tx * 4 + j];
#pragma unroll
        for (int i = 0; i < 4; ++i)
#pragma unroll
          for (int j = 0; j < 4; ++j) S[i][j] += a[i] * bv[j];
      }
      __syncthreads();
    }
    float sc[4];
#pragma unroll
    for (int i = 0; i < 4; ++i) {
      float mc = S[i][0];
#pragma unroll
      for (int j = 1; j < 4; ++j) mc = fmaxf(mc, S[i][j]);
#pragma unroll
      for (int s = 8; s >= 1; s >>= 1) mc = fmaxf(mc, __shfl_xor(mc, s, 16));
      float mn = fmaxf(m[i], mc);
      sc[i] = __expf(m[i] - mn);
      float lsum = 0.f;
#pragma unroll
      for (int j = 0; j < 4; ++j) {
        float p = __expf(S[i][j] - mn);
        S[i][j] = p;
        lsum += p;
      }
#pragma unroll
      for (int s = 8; s >= 1; s >>= 1) lsum += __shfl_xor(lsum, s, 16);
      l[i] = l[i] * sc[i] + lsum;
      m[i] = mn;
#pragma unroll
      for (int j = 0; j < 4; ++j) Ps[ty * 4 + i][tx * 4 + j] = S[i][j];
    }
    if (tx == 0) {
#pragma unroll
      for (int i = 0; i < 4; ++i) mScale[ty * 4 + i] = sc[i];
    }
    __syncthreads();
#pragma unroll
    for (int cq = 0; cq < 4; ++cq) {
#pragma unroll
      for (int r = 0; r < 16; ++r) {
        int idx = tid + r * 256;
        int cpr = idx >> 6, j = idx & 63;
        Gs[cpr][j] = gb[(size_t)(cq * 64 + cpr) * TT + j0 + j];
      }
      __syncthreads();
      float scj[4];
#pragma unroll
      for (int jq = 0; jq < 4; ++jq) scj[jq] = mScale[tx * 4 + jq];
#pragma unroll
      for (int ci = 0; ci < 4; ++ci)
#pragma unroll
        for (int jq = 0; jq < 4; ++jq) acc[cq][ci][jq] *= scj[jq];
      for (int j = 0; j < 64; ++j) {
        float a[4], p[4];
#pragma unroll
        for (int ci = 0; ci < 4; ++ci) a[ci] = Gs[ty * 4 + ci][j];
#pragma unroll
        for (int jq = 0; jq < 4; ++jq) p[jq] = Ps[tx * 4 + jq][j];
#pragma unroll
        for (int ci = 0; ci < 4; ++ci)
#pragma unroll
          for (int jq = 0; jq < 4; ++jq) acc[cq][ci][jq] += a[ci] * p[jq];
      }
      __syncthreads();
    }
  }
  if (tx == 0) {
#pragma unroll
    for (int i = 0; i < 4; ++i) lArr[ty * 4 + i] = l[i];
  }
  __syncthreads();
  float linv[4];
#pragma unroll
  for (int jq = 0; jq < 4; ++jq) linv[jq] = 1.f / lArr[tx * 4 + jq];
#pragma unroll
  for (int cq = 0; cq < 4; ++cq)
#pragma unroll
    for (int ci = 0; ci < 4; ++ci)
#pragma unroll
      for (int jq = 0; jq < 4; ++jq)
        y[((size_t)b * ICC + cq * 64 + ty * 4 + ci) * TT + i0 + tx * 4 + jq] =
            acc[cq][ci][jq] * linv[jq];
}

// ---------------------------------------------------------------------------
extern "C" void kernel_launch(void* const* d_in, const int* in_sizes, int n_in,
                              void* d_out, int out_size, void* d_ws,
                              size_t ws_size, hipStream_t stream) {
  const float* x = (const float*)d_in[0];
  const float* g_w = (const float*)d_in[1];
  const float* g_b = (const float*)d_in[2];
  const float* th_w = (const float*)d_in[3];
  const float* th_b = (const float*)d_in[4];
  const float* ph_w = (const float*)d_in[5];
  const float* ph_b = (const float*)d_in[6];
  const float* W_w = (const float*)d_in[7];
  const float* W_b = (const float*)d_in[8];
  const float* gamma = (const float*)d_in[9];
  const float* beta = (const float*)d_in[10];
  float* out = (float*)d_out;
  dim3 blk(256);

  const size_t NP = (size_t)BB * TT * ICC;  // 4,194,304
  const size_t NW = 131072;                 // 256*512
  const size_t need = (8 * NP + 8 * NW) * sizeof(f16) + 8192 + 4096;

  if (ws_size >= need) {
    // ---------------- fast MFMA path ----------------
    f16* p = (f16*)d_ws;
    f16 *thH = p, *thL = thH + NP, *phH = thL + NP, *phL = phH + NP;
    f16 *gH = phL + NP, *gL = gH + NP, *yH = gL + NP, *yL = yH + NP;
    f16* wp = yL + NP;
    f16 *gwH = wp, *gwL = gwH + NW, *twH = gwL + NW, *twL = twH + NW;
    f16 *pwH = twL + NW, *pwL = pwH + NW, *wwH = pwL + NW, *wwL = wwH + NW;
    double* statd = (double*)(wwL + NW);
    f16* xTh = (f16*)d_out;  // xT hi/lo lives in d_out (dead before W-conv)
    f16* xTl = xTh + (size_t)BB * TT * CC;

    // fused front-end: weight splits + stats zero + x transpose/split
    front_end<<<10241, 256, 0, stream>>>(g_w, gwH, gwL, th_w, twH, twL, ph_w,
                                         pwH, pwL, W_w, wwH, wwL, statd, x,
                                         xTh, xTl);
    // fused projections: merged theta+phi (256 blocks) + g (256 blocks)
    fused_proj<<<512, dim3(512), 0, stream>>>(xTh, xTl, twH, twL, th_b, thH,
                                              thL, pwH, pwL, ph_b, phH, phL,
                                              gwH, gwL, g_b, gH, gL);
    // attention -> y f16 hi/lo directly (r18 exact)
    attn_mfma<<<256, dim3(512), 0, stream>>>(thH, thL, phH, phL, gH, gL, yH,
                                             yL);
    // W conv: D[o][t] -> d_out + BN stats  (M=C, N=T, K=IC, bias on M)
    gemm_nt<CC, TT, ICC, false, true><<<dim3(16, 4, BB), dim3(512), 0,
                                        stream>>>(
        wwH, wwL, 0, yH, yL, (long)TT * ICC, W_b, nullptr, nullptr, out,
        (long)CC * TT, statd, statd + CC);
    // BN stats folded into apply (per-block redundant finalize from statd)
    bn_apply_fused<<<2048, 256, 0, stream>>>(out, x, statd, gamma, beta);
  } else {
    // ---------------- fallback fp32 path ----------------
    float* ws = (float*)d_ws;
    const size_t np = (size_t)BB * ICC * TT;
    float* thb = ws;
    float* phb = ws + np;
    float* gbuf = ws + 2 * np;
    float* yb = thb;
    double* statd = (double*)(ws + 3 * np);
    float* meanb = (float*)(statd + 1024);
    float* rstdb = meanb + 512;
    gemm_proj<ICC, CC, false><<<dim3(TT / 64, ICC / 64, BB), blk, 0, stream>>>(
        th_w, th_b, x, thb, nullptr, nullptr);
    gemm_proj<ICC, CC, false><<<dim3(TT / 64, ICC / 64, BB), blk, 0, stream>>>(
        ph_w, ph_b, x, phb, nullptr, nullptr);
    gemm_proj<ICC, CC, false><<<dim3(TT / 64, ICC / 64, BB), blk, 0, stream>>>(
        g_w, g_b, x, gbuf, nullptr, nullptr);
    attn_flash<<<dim3(TT / 64, BB), blk, 0, stream>>>(thb, phb, gbuf, yb);
    zero_stats<<<1, 1024, 0, stream>>>(statd);
    gemm_proj<CC, ICC, true><<<dim3(TT / 64, CC / 64, BB), blk, 0, stream>>>(
        W_w, W_b, yb, out, statd, statd + CC);
    bn_stats<<<1, 512, 0, stream>>>(statd, statd + CC, meanb, rstdb);
    bn_apply<<<2048, 256, 0, stream>>>(out, x, meanb, rstdb, gamma, beta);
  }
}